// Round 1
// baseline (1536.155 us; speedup 1.0000x reference)
//
#include <hip/hip_runtime.h>
#include <hip/hip_bf16.h>

// Problem constants (from reference)
constexpr int NPT    = 50000;    // nodes per type
constexpr int NN     = 100000;   // total nodes
constexpr int NE     = 1000000;  // edges
constexpr int HID    = 128;
constexpr int OUTF   = 64;
constexpr int INF    = 256;
constexpr int NREL   = 5;
constexpr int NSEG   = NN * NREL; // 500000

// ---------------------------------------------------------------------------
// Wstack[(r*128+i)*FOUT + f] = sum_b comp[r,b]*basis[b,i,f];  rows 640..767 = root
__global__ void build_wstack(const float* __restrict__ comp,
                             const float* __restrict__ basis,
                             const float* __restrict__ root,
                             float* __restrict__ wstack, int fout) {
    int idx = blockIdx.x * blockDim.x + threadIdx.x;
    int total = 768 * fout;
    if (idx >= total) return;
    int k = idx / fout, f = idx - k * fout;
    float v;
    if (k < 640) {
        int r = k >> 7, i = k & 127;
        v = 0.f;
#pragma unroll
        for (int b = 0; b < 8; b++)
            v += comp[r * 8 + b] * basis[(b * 128 + i) * fout + f];
    } else {
        int i = k - 640;
        v = root[i * fout + f];
    }
    wstack[idx] = v;
}

// ---------------------------------------------------------------------------
// x0[n,f] = relu( concat(x_author,x_paper)[n,:] @ W_type + b_type )
// 8 nodes per block (50000 % 8 == 0 so tiles never straddle node types)
__global__ void proj_kernel(const float* __restrict__ xa, const float* __restrict__ xp,
                            const float* __restrict__ wa, const float* __restrict__ ba,
                            const float* __restrict__ wp, const float* __restrict__ bp,
                            float* __restrict__ x0) {
    __shared__ float sx[8][INF];
    const int tid = threadIdx.x;      // 256
    const int n0 = blockIdx.x * 8;
    for (int r = 0; r < 8; r++) {
        int n = n0 + r;
        float v = (n < NPT) ? xa[(size_t)n * INF + tid]
                            : xp[(size_t)(n - NPT) * INF + tid];
        sx[r][tid] = v;
    }
    __syncthreads();
    const int f = tid & 127;
    const int half = tid >> 7;        // nodes 0-3 / 4-7
    const float* w = (n0 < NPT) ? wa : wp;
    const float* bb = (n0 < NPT) ? ba : bp;
    float acc[4];
    float bv = bb[f];
#pragma unroll
    for (int i = 0; i < 4; i++) acc[i] = bv;
    for (int k = 0; k < INF; k++) {
        float wv = w[k * 128 + f];
#pragma unroll
        for (int i = 0; i < 4; i++) acc[i] += sx[half * 4 + i][k] * wv;
    }
#pragma unroll
    for (int i = 0; i < 4; i++) {
        int n = n0 + half * 4 + i;
        x0[(size_t)n * 128 + f] = fmaxf(acc[i], 0.f);
    }
}

// ---------------------------------------------------------------------------
__global__ void hist_kernel(const int* __restrict__ ei, const int* __restrict__ et,
                            int* __restrict__ cnt) {
    int e = blockIdx.x * blockDim.x + threadIdx.x;
    if (e < NE) {
        int dst = ei[NE + e];
        int r = et[e];
        atomicAdd(&cnt[dst * NREL + r], 1);
    }
}

// exclusive scan over NSEG ints; 2048 elements per block
__global__ void scan1(const int* __restrict__ cnt, int* __restrict__ offs,
                      int* __restrict__ bsums, int n) {
    __shared__ int lds[256];
    const int t = threadIdx.x;
    const int base = blockIdx.x * 2048 + t * 8;
    int vals[8];
    int s = 0;
#pragma unroll
    for (int v = 0; v < 8; v++) {
        int idx = base + v;
        vals[v] = (idx < n) ? cnt[idx] : 0;
        s += vals[v];
    }
    lds[t] = s;
    __syncthreads();
    for (int off = 1; off < 256; off <<= 1) {
        int x = lds[t];
        int y = (t >= off) ? lds[t - off] : 0;
        __syncthreads();
        lds[t] = x + y;
        __syncthreads();
    }
    int run = (t > 0) ? lds[t - 1] : 0;
    if (t == 255) bsums[blockIdx.x] = lds[255];
#pragma unroll
    for (int v = 0; v < 8; v++) {
        int idx = base + v;
        if (idx < n) offs[idx] = run;
        run += vals[v];
    }
}

__global__ void scan2(const int* __restrict__ bsums, int* __restrict__ bsums2, int nb) {
    __shared__ int lds[256];
    const int t = threadIdx.x;
    lds[t] = (t < nb) ? bsums[t] : 0;
    __syncthreads();
    for (int off = 1; off < 256; off <<= 1) {
        int x = lds[t];
        int y = (t >= off) ? lds[t - off] : 0;
        __syncthreads();
        lds[t] = x + y;
        __syncthreads();
    }
    if (t < nb) bsums2[t] = (t > 0) ? lds[t - 1] : 0;
}

__global__ void scan3(int* __restrict__ offs, const int* __restrict__ bsums2,
                      int* __restrict__ cursor, int n) {
    int i = blockIdx.x * blockDim.x + threadIdx.x;
    if (i < n) {
        int v = offs[i] + bsums2[i >> 11];
        offs[i] = v;
        cursor[i] = v;
    }
}

__global__ void scatter_kernel(const int* __restrict__ ei, const int* __restrict__ et,
                               int* __restrict__ cursor, int* __restrict__ ssrc) {
    int e = blockIdx.x * blockDim.x + threadIdx.x;
    if (e < NE) {
        int src = ei[e];
        int dst = ei[NE + e];
        int r = et[e];
        int pos = atomicAdd(&cursor[dst * NREL + r], 1);
        ssrc[pos] = src;
    }
}

// ---------------------------------------------------------------------------
// Fused: per node build [5 relation means | x row] (768 f32) in LDS, then
// out[n,:] = A_row @ Wstack.  16 nodes per block, 256 threads.
template <int FOUT, bool RELU>
__global__ void combine_kernel(const float* __restrict__ xin,
                               const int* __restrict__ ssrc,
                               const int* __restrict__ offs,
                               const int* __restrict__ cnt,
                               const float* __restrict__ wstack,
                               float* __restrict__ out) {
    __shared__ float sm[16][768];
    const int tid = threadIdx.x;
    const int g = tid >> 5;   // 8 groups of 32 lanes
    const int lane = tid & 31;
    const int n0 = blockIdx.x * 16;

    for (int rep = 0; rep < 2; rep++) {
        int node = g * 2 + rep;      // 0..15
        int n = n0 + node;
        // x part (rows 640..767)
        float4 xv = *(const float4*)&xin[(size_t)n * 128 + lane * 4];
        *(float4*)&sm[node][640 + lane * 4] = xv;
        for (int r = 0; r < NREL; r++) {
            int sgi = n * NREL + r;
            int off = offs[sgi];
            int c = cnt[sgi];
            float4 acc = {0.f, 0.f, 0.f, 0.f};
            for (int j = 0; j < c; j++) {
                int row = ssrc[off + j];
                float4 v = *(const float4*)&xin[(size_t)row * 128 + lane * 4];
                acc.x += v.x; acc.y += v.y; acc.z += v.z; acc.w += v.w;
            }
            float inv = 1.f / (float)((c > 1) ? c : 1);
            acc.x *= inv; acc.y *= inv; acc.z *= inv; acc.w *= inv;
            *(float4*)&sm[node][r * 128 + lane * 4] = acc;
        }
    }
    __syncthreads();

    const int f = tid & (FOUT - 1);
    const int nsub = tid / FOUT;          // 256/FOUT sub-groups
    constexpr int NSUB = 256 / FOUT;
    constexpr int NPER = 16 / NSUB;
    float acc[NPER];
#pragma unroll
    for (int i = 0; i < NPER; i++) acc[i] = 0.f;
#pragma unroll 4
    for (int k = 0; k < 768; k++) {
        float wv = wstack[k * FOUT + f];
#pragma unroll
        for (int i = 0; i < NPER; i++) acc[i] += sm[nsub * NPER + i][k] * wv;
    }
#pragma unroll
    for (int i = 0; i < NPER; i++) {
        int n = n0 + nsub * NPER + i;
        float v = acc[i];
        if (RELU) v = fmaxf(v, 0.f);
        out[(size_t)n * FOUT + f] = v;
    }
}

// ---------------------------------------------------------------------------
// PairNorm stats: colsum[f] = sum_n x[n,f];  sumsq = sum x^2
template <int F>
__global__ void stats_kernel(const float* __restrict__ x, float* __restrict__ colsum,
                             float* __restrict__ sumsq) {
    constexpr int NSUB = 256 / F;
    const int f = threadIdx.x & (F - 1);
    const int sub = threadIdx.x / F;
    float cs = 0.f, ss = 0.f;
    const int stride = gridDim.x * NSUB;
    for (int n = blockIdx.x * NSUB + sub; n < NN; n += stride) {
        float v = x[(size_t)n * F + f];
        cs += v;
        ss += v * v;
    }
    __shared__ float sred[256];
    sred[threadIdx.x] = cs;
    __syncthreads();
    if (sub == 0) {
        float t = cs;
#pragma unroll
        for (int s2 = 1; s2 < NSUB; s2++) t += sred[s2 * F + f];
        atomicAdd(&colsum[f], t);
    }
    __syncthreads();
    sred[threadIdx.x] = ss;
    __syncthreads();
    for (int h = 128; h > 0; h >>= 1) {
        if (threadIdx.x < h) sred[threadIdx.x] += sred[threadIdx.x + h];
        __syncthreads();
    }
    if (threadIdx.x == 0) atomicAdd(sumsq, sred[0]);
}

// mu_inv[0..F-1] = colmean; mu_inv[F] = 1/sqrt(eps + S2/N - sum mu^2)
template <int F>
__global__ void finalize_kernel(const float* __restrict__ colsum,
                                const float* __restrict__ sumsq,
                                float* __restrict__ mu_inv) {
    __shared__ float sred[128];
    const int f = threadIdx.x;  // F threads
    float mu = colsum[f] / (float)NN;
    mu_inv[f] = mu;
    sred[f] = mu * mu;
    __syncthreads();
    for (int h = F / 2; h > 0; h >>= 1) {
        if (f < h) sred[f] += sred[f + h];
        __syncthreads();
    }
    if (f == 0) {
        float var = sumsq[0] / (float)NN - sred[0];
        mu_inv[F] = rsqrtf(1e-5f + var);
    }
}

template <int F>
__global__ void normalize_kernel(const float* __restrict__ x,
                                 const float* __restrict__ mu_inv,
                                 float* __restrict__ out, int total) {
    int i = blockIdx.x * blockDim.x + threadIdx.x;
    if (i < total) {
        int f = i & (F - 1);
        out[i] = (x[i] - mu_inv[f]) * mu_inv[F];
    }
}

// ---------------------------------------------------------------------------
extern "C" void kernel_launch(void* const* d_in, const int* in_sizes, int n_in,
                              void* d_out, int out_size, void* d_ws, size_t ws_size,
                              hipStream_t stream) {
    const float* xa    = (const float*)d_in[0];
    const float* xp    = (const float*)d_in[1];
    const int*   ei    = (const int*)d_in[2];
    const int*   et    = (const int*)d_in[3];
    const float* paw   = (const float*)d_in[4];
    const float* pab   = (const float*)d_in[5];
    const float* ppw   = (const float*)d_in[6];
    const float* ppb   = (const float*)d_in[7];
    const float* comp0 = (const float*)d_in[8];
    const float* basis0= (const float*)d_in[9];
    const float* root0 = (const float*)d_in[10];
    const float* comp1 = (const float*)d_in[11];
    const float* basis1= (const float*)d_in[12];
    const float* root1 = (const float*)d_in[13];
    float* out = (float*)d_out;

    char* ws = (char*)d_ws;
    size_t o = 0;
    auto alloc = [&](size_t b) { size_t p = o; o += (b + 255) & ~(size_t)255; return p; };
    float* x0     = (float*)(ws + alloc((size_t)NN * HID * 4));   // 51.2 MB
    float* h0     = (float*)(ws + alloc((size_t)NN * HID * 4));   // 51.2 MB
    float* h1     = (float*)(ws + alloc((size_t)NN * OUTF * 4));  // 25.6 MB
    int*   cnt    = (int*)(ws + alloc((size_t)NSEG * 4));
    int*   offs   = (int*)(ws + alloc((size_t)NSEG * 4));
    int*   cursor = (int*)(ws + alloc((size_t)NSEG * 4));
    int*   ssrc   = (int*)(ws + alloc((size_t)NE * 4));
    int*   bsums  = (int*)(ws + alloc(1024 * 4));
    int*   bsums2 = (int*)(ws + alloc(1024 * 4));
    float* w0s    = (float*)(ws + alloc(768 * HID * 4));
    float* w1s    = (float*)(ws + alloc(768 * OUTF * 4));
    float* pnscr  = (float*)(ws + alloc(512 * 4));   // cs0[0..127] ss0[128] cs1[192..255] ss1[256]
    float* mu0    = (float*)(ws + alloc(129 * 4));
    float* mu1    = (float*)(ws + alloc(65 * 4));
    float* cs0 = pnscr, *ss0 = pnscr + 128, *cs1 = pnscr + 192, *ss1 = pnscr + 256;

    // weight stacks + projection
    build_wstack<<<(768 * HID + 255) / 256, 256, 0, stream>>>(comp0, basis0, root0, w0s, HID);
    build_wstack<<<(768 * OUTF + 255) / 256, 256, 0, stream>>>(comp1, basis1, root1, w1s, OUTF);
    proj_kernel<<<NN / 8, 256, 0, stream>>>(xa, xp, paw, pab, ppw, ppb, x0);

    // segment index (shared by both layers)
    hipMemsetAsync(cnt, 0, (size_t)NSEG * 4, stream);
    hipMemsetAsync(pnscr, 0, 512 * 4, stream);
    hist_kernel<<<(NE + 255) / 256, 256, 0, stream>>>(ei, et, cnt);
    const int nb = (NSEG + 2047) / 2048;
    scan1<<<nb, 256, 0, stream>>>(cnt, offs, bsums, NSEG);
    scan2<<<1, 256, 0, stream>>>(bsums, bsums2, nb);
    scan3<<<(NSEG + 255) / 256, 256, 0, stream>>>(offs, bsums2, cursor, NSEG);
    scatter_kernel<<<(NE + 255) / 256, 256, 0, stream>>>(ei, et, cursor, ssrc);

    // layer 0
    combine_kernel<HID, true><<<NN / 16, 256, 0, stream>>>(x0, ssrc, offs, cnt, w0s, h0);
    stats_kernel<HID><<<512, 256, 0, stream>>>(h0, cs0, ss0);
    finalize_kernel<HID><<<1, HID, 0, stream>>>(cs0, ss0, mu0);
    float* xlat = out + (size_t)NN * OUTF;
    normalize_kernel<HID><<<(NN * HID + 255) / 256, 256, 0, stream>>>(h0, mu0, xlat, NN * HID);

    // layer 1 (reads x_latent from d_out)
    combine_kernel<OUTF, false><<<NN / 16, 256, 0, stream>>>(xlat, ssrc, offs, cnt, w1s, h1);
    stats_kernel<OUTF><<<512, 256, 0, stream>>>(h1, cs1, ss1);
    finalize_kernel<OUTF><<<1, OUTF, 0, stream>>>(cs1, ss1, mu1);
    normalize_kernel<OUTF><<<(NN * OUTF + 255) / 256, 256, 0, stream>>>(h1, mu1, out, NN * OUTF);
}

// Round 2
// 764.538 us; speedup vs baseline: 2.0093x; 2.0093x over previous
//
#include <hip/hip_runtime.h>
#include <hip/hip_bf16.h>

constexpr int NPT    = 50000;
constexpr int NN     = 100000;
constexpr int NE     = 1000000;
constexpr int HID    = 128;
constexpr int OUTF   = 64;
constexpr int INF    = 256;
constexpr int NREL   = 5;
constexpr int NSEG   = NN * NREL;

typedef __attribute__((ext_vector_type(8))) short short8v;
typedef __attribute__((ext_vector_type(4))) float f32x4;

__device__ __forceinline__ ushort f2bf(float x) {
    uint u = __builtin_bit_cast(uint, x);
    uint r = (u + 0x7FFFu + ((u >> 16) & 1u)) >> 16;
    return (ushort)r;
}

// ---------------------------------------------------------------------------
// wT[f][k] (bf16), k in 0..767: rows 0..639 = comp x basis (rel-major), 640..767 = root
__global__ void build_wstackT(const float* __restrict__ comp,
                              const float* __restrict__ basis,
                              const float* __restrict__ root,
                              ushort* __restrict__ wT, int fout) {
    int idx = blockIdx.x * blockDim.x + threadIdx.x;
    if (idx >= 768 * fout) return;
    int k = idx / fout, f = idx - k * fout;
    float v;
    if (k < 640) {
        int r = k >> 7, i = k & 127;
        v = 0.f;
#pragma unroll
        for (int b = 0; b < 8; b++)
            v += comp[r * 8 + b] * basis[(b * 128 + i) * fout + f];
    } else {
        v = root[(k - 640) * fout + f];
    }
    wT[(size_t)f * 768 + k] = f2bf(v);
}

// w[256][128] f32 -> wT[128][256] bf16
__global__ void build_wprojT(const float* __restrict__ w, ushort* __restrict__ wT) {
    int idx = blockIdx.x * blockDim.x + threadIdx.x;
    if (idx >= 256 * 128) return;
    int k = idx >> 7, f = idx & 127;
    wT[(size_t)f * 256 + k] = f2bf(w[idx]);
}

// ---------------------------------------------------------------------------
// proj via MFMA: 16 nodes/block, K=256, N=128. x0b bf16 output.
__launch_bounds__(256, 6)
__global__ void proj_mfma(const float* __restrict__ xa, const float* __restrict__ xp,
                          const ushort* __restrict__ wTa, const ushort* __restrict__ wTp,
                          const float* __restrict__ ba, const float* __restrict__ bp,
                          ushort* __restrict__ x0b) {
    __shared__ ushort sx[16][264];   // pad to 264 for bank spread
    const int tid = threadIdx.x;
    const int n0 = blockIdx.x * 16;
    const bool author = n0 < NPT;
    const float* x = author ? xa : xp;
    const ushort* wT = author ? wTa : wTp;
    const float* bias = author ? ba : bp;

    {   // stage 16 x 256 f32 -> bf16 LDS
        int r = tid >> 4, part = tid & 15;
        size_t rowoff = (size_t)(n0 - (author ? 0 : NPT) + r) * INF + part * 16;
#pragma unroll
        for (int ii = 0; ii < 4; ii++) {
            float4 v = *(const float4*)&x[rowoff + ii * 4];
            ushort4 h = {f2bf(v.x), f2bf(v.y), f2bf(v.z), f2bf(v.w)};
            *(ushort4*)&sx[r][part * 16 + ii * 4] = h;
        }
    }
    __syncthreads();

    const int wave = tid >> 6, lane = tid & 63;
    const int row = lane & 15, g = lane >> 4;
#pragma unroll
    for (int t = 0; t < 2; t++) {
        int ntile = wave * 2 + t;
        int fcol = ntile * 16 + row;
        f32x4 acc = {0.f, 0.f, 0.f, 0.f};
#pragma unroll
        for (int kk = 0; kk < 8; kk++) {
            short8v a = *(const short8v*)&sx[row][kk * 32 + g * 8];
            short8v b = *(const short8v*)&wT[(size_t)fcol * 256 + kk * 32 + g * 8];
            acc = __builtin_amdgcn_mfma_f32_16x16x32_bf16(a, b, acc, 0, 0, 0);
        }
        float bv = bias[fcol];
#pragma unroll
        for (int q = 0; q < 4; q++) {
            int node = g * 4 + q;
            float v = fmaxf(acc[q] + bv, 0.f);
            x0b[(size_t)(n0 + node) * HID + fcol] = f2bf(v);
        }
    }
}

// ---------------------------------------------------------------------------
__global__ void hist_kernel(const int* __restrict__ ei, const int* __restrict__ et,
                            int* __restrict__ cnt) {
    int e = blockIdx.x * blockDim.x + threadIdx.x;
    if (e < NE) {
        int dst = ei[NE + e];
        int r = et[e];
        atomicAdd(&cnt[dst * NREL + r], 1);
    }
}

__global__ void scan1(const int* __restrict__ cnt, int* __restrict__ offs,
                      int* __restrict__ bsums, int n) {
    __shared__ int lds[256];
    const int t = threadIdx.x;
    const int base = blockIdx.x * 2048 + t * 8;
    int vals[8];
    int s = 0;
#pragma unroll
    for (int v = 0; v < 8; v++) {
        int idx = base + v;
        vals[v] = (idx < n) ? cnt[idx] : 0;
        s += vals[v];
    }
    lds[t] = s;
    __syncthreads();
    for (int off = 1; off < 256; off <<= 1) {
        int x = lds[t];
        int y = (t >= off) ? lds[t - off] : 0;
        __syncthreads();
        lds[t] = x + y;
        __syncthreads();
    }
    int run = (t > 0) ? lds[t - 1] : 0;
    if (t == 255) bsums[blockIdx.x] = lds[255];
#pragma unroll
    for (int v = 0; v < 8; v++) {
        int idx = base + v;
        if (idx < n) offs[idx] = run;
        run += vals[v];
    }
}

__global__ void scan2(const int* __restrict__ bsums, int* __restrict__ bsums2, int nb) {
    __shared__ int lds[256];
    const int t = threadIdx.x;
    lds[t] = (t < nb) ? bsums[t] : 0;
    __syncthreads();
    for (int off = 1; off < 256; off <<= 1) {
        int x = lds[t];
        int y = (t >= off) ? lds[t - off] : 0;
        __syncthreads();
        lds[t] = x + y;
        __syncthreads();
    }
    if (t < nb) bsums2[t] = (t > 0) ? lds[t - 1] : 0;
}

__global__ void scan3(int* __restrict__ offs, const int* __restrict__ bsums2,
                      int* __restrict__ cursor, int n) {
    int i = blockIdx.x * blockDim.x + threadIdx.x;
    if (i < n) {
        int v = offs[i] + bsums2[i >> 11];
        offs[i] = v;
        cursor[i] = v;
    }
}

// pack relation into high bits of src index
__global__ void scatter_kernel(const int* __restrict__ ei, const int* __restrict__ et,
                               int* __restrict__ cursor, int* __restrict__ ssrc) {
    int e = blockIdx.x * blockDim.x + threadIdx.x;
    if (e < NE) {
        int src = ei[e];
        int dst = ei[NE + e];
        int r = et[e];
        int pos = atomicAdd(&cursor[dst * NREL + r], 1);
        ssrc[pos] = (r << 20) | src;
    }
}

// ---------------------------------------------------------------------------
// Fused RGCN layer: gather means (bf16 rows) -> LDS A tile -> MFMA with wT.
// 16 nodes/block, 256 threads (4 waves), 1 wave per node in gather phase.
template <int FOUT, bool RELU>
__launch_bounds__(256, 6)
__global__ void combine_mfma(const ushort* __restrict__ xb,
                             const int* __restrict__ ssrc,
                             const int* __restrict__ offs,
                             const int* __restrict__ cnt,
                             const ushort* __restrict__ wT,
                             float* __restrict__ out) {
    __shared__ ushort sm[16][776];   // 768 + 8 pad -> 2-way max bank aliasing
    const int tid = threadIdx.x;
    const int wave = tid >> 6, lane = tid & 63;
    const int n0 = blockIdx.x * 16;

    for (int rep = 0; rep < 4; rep++) {
        const int node = wave * 4 + rep;
        const int n = n0 + node;
        // root/x row (bf16 copy), cols 640..767
        uint xr = *(const uint*)&xb[(size_t)n * HID + lane * 2];
        *(uint*)&sm[node][640 + lane * 2] = xr;

        const int s5 = n * NREL;
        const int base = offs[s5];
        const int c0 = cnt[s5 + 0], c1 = cnt[s5 + 1], c2 = cnt[s5 + 2],
                  c3 = cnt[s5 + 3], c4 = cnt[s5 + 4];
        const int total = c0 + c1 + c2 + c3 + c4;
        float2 a0 = {0.f, 0.f}, a1 = {0.f, 0.f}, a2 = {0.f, 0.f},
               a3 = {0.f, 0.f}, a4 = {0.f, 0.f};
        for (int j = 0; j < total; j++) {
            int p = ssrc[base + j];           // wave-uniform
            int rel = p >> 20;
            uint raw = *(const uint*)&xb[(size_t)(p & 0xFFFFF) * HID + lane * 2];
            float fx = __builtin_bit_cast(float, raw << 16);
            float fy = __builtin_bit_cast(float, raw & 0xFFFF0000u);
            if (rel == 0)      { a0.x += fx; a0.y += fy; }
            else if (rel == 1) { a1.x += fx; a1.y += fy; }
            else if (rel == 2) { a2.x += fx; a2.y += fy; }
            else if (rel == 3) { a3.x += fx; a3.y += fy; }
            else               { a4.x += fx; a4.y += fy; }
        }
        {
            float2 av[5] = {a0, a1, a2, a3, a4};
            int cv[5] = {c0, c1, c2, c3, c4};
#pragma unroll
            for (int r = 0; r < NREL; r++) {
                float inv = 1.f / (float)((cv[r] > 1) ? cv[r] : 1);
                uint packed = (uint)f2bf(av[r].x * inv) | ((uint)f2bf(av[r].y * inv) << 16);
                *(uint*)&sm[node][r * 128 + lane * 2] = packed;
            }
        }
    }
    __syncthreads();

    constexpr int NTILES = FOUT / 16;
    constexpr int TPW = (NTILES + 3) / 4;
    const int row = lane & 15, g = lane >> 4;
#pragma unroll
    for (int t = 0; t < TPW; t++) {
        const int ntile = wave * TPW + t;
        if (NTILES < 4 && ntile >= NTILES) break;
        const int fcol = ntile * 16 + row;
        f32x4 acc = {0.f, 0.f, 0.f, 0.f};
#pragma unroll 6
        for (int kk = 0; kk < 24; kk++) {
            short8v a = *(const short8v*)&sm[row][kk * 32 + g * 8];
            short8v b = *(const short8v*)&wT[(size_t)fcol * 768 + kk * 32 + g * 8];
            acc = __builtin_amdgcn_mfma_f32_16x16x32_bf16(a, b, acc, 0, 0, 0);
        }
#pragma unroll
        for (int q = 0; q < 4; q++) {
            const int node = g * 4 + q;
            float v = acc[q];
            if (RELU) v = fmaxf(v, 0.f);
            out[(size_t)(n0 + node) * FOUT + fcol] = v;
        }
    }
}

// ---------------------------------------------------------------------------
template <int F>
__global__ void stats_kernel(const float* __restrict__ x, float* __restrict__ colsum,
                             float* __restrict__ sumsq) {
    constexpr int NSUB = 256 / F;
    const int f = threadIdx.x & (F - 1);
    const int sub = threadIdx.x / F;
    float cs = 0.f, ss = 0.f;
    const int stride = gridDim.x * NSUB;
    for (int n = blockIdx.x * NSUB + sub; n < NN; n += stride) {
        float v = x[(size_t)n * F + f];
        cs += v;
        ss += v * v;
    }
    __shared__ float sred[256];
    sred[threadIdx.x] = cs;
    __syncthreads();
    if (sub == 0) {
        float t = cs;
#pragma unroll
        for (int s2 = 1; s2 < NSUB; s2++) t += sred[s2 * F + f];
        atomicAdd(&colsum[f], t);
    }
    __syncthreads();
    sred[threadIdx.x] = ss;
    __syncthreads();
    for (int h = 128; h > 0; h >>= 1) {
        if (threadIdx.x < h) sred[threadIdx.x] += sred[threadIdx.x + h];
        __syncthreads();
    }
    if (threadIdx.x == 0) atomicAdd(sumsq, sred[0]);
}

template <int F>
__global__ void finalize_kernel(const float* __restrict__ colsum,
                                const float* __restrict__ sumsq,
                                float* __restrict__ mu_inv) {
    __shared__ float sred[128];
    const int f = threadIdx.x;
    float mu = colsum[f] / (float)NN;
    mu_inv[f] = mu;
    sred[f] = mu * mu;
    __syncthreads();
    for (int h = F / 2; h > 0; h >>= 1) {
        if (f < h) sred[f] += sred[f + h];
        __syncthreads();
    }
    if (f == 0) {
        float var = sumsq[0] / (float)NN - sred[0];
        mu_inv[F] = rsqrtf(1e-5f + var);
    }
}

// layer-0 normalize: write f32 x_latent (d_out) AND bf16 copy for layer-1 input
__global__ void normalize_dual(const float* __restrict__ x,
                               const float* __restrict__ mu_inv,
                               float* __restrict__ outf, ushort* __restrict__ outb,
                               int total) {
    int i = blockIdx.x * blockDim.x + threadIdx.x;
    if (i < total) {
        int f = i & 127;
        float v = (x[i] - mu_inv[f]) * mu_inv[128];
        outf[i] = v;
        outb[i] = f2bf(v);
    }
}

template <int F>
__global__ void normalize_kernel(const float* __restrict__ x,
                                 const float* __restrict__ mu_inv,
                                 float* __restrict__ out, int total) {
    int i = blockIdx.x * blockDim.x + threadIdx.x;
    if (i < total) {
        int f = i & (F - 1);
        out[i] = (x[i] - mu_inv[f]) * mu_inv[F];
    }
}

// ---------------------------------------------------------------------------
extern "C" void kernel_launch(void* const* d_in, const int* in_sizes, int n_in,
                              void* d_out, int out_size, void* d_ws, size_t ws_size,
                              hipStream_t stream) {
    const float* xa    = (const float*)d_in[0];
    const float* xp    = (const float*)d_in[1];
    const int*   ei    = (const int*)d_in[2];
    const int*   et    = (const int*)d_in[3];
    const float* paw   = (const float*)d_in[4];
    const float* pab   = (const float*)d_in[5];
    const float* ppw   = (const float*)d_in[6];
    const float* ppb   = (const float*)d_in[7];
    const float* comp0 = (const float*)d_in[8];
    const float* basis0= (const float*)d_in[9];
    const float* root0 = (const float*)d_in[10];
    const float* comp1 = (const float*)d_in[11];
    const float* basis1= (const float*)d_in[12];
    const float* root1 = (const float*)d_in[13];
    float* out = (float*)d_out;

    char* ws = (char*)d_ws;
    size_t o = 0;
    auto alloc = [&](size_t b) { size_t p = o; o += (b + 255) & ~(size_t)255; return p; };
    ushort* x0b   = (ushort*)(ws + alloc((size_t)NN * HID * 2));   // 25.6 MB
    ushort* xlatb = (ushort*)(ws + alloc((size_t)NN * HID * 2));   // 25.6 MB
    float*  h0    = (float*)(ws + alloc((size_t)NN * HID * 4));    // 51.2 MB
    float*  h1    = (float*)(ws + alloc((size_t)NN * OUTF * 4));   // 25.6 MB
    int*    cnt   = (int*)(ws + alloc((size_t)NSEG * 4));
    int*    offs  = (int*)(ws + alloc((size_t)NSEG * 4));
    int*    cursor= (int*)(ws + alloc((size_t)NSEG * 4));
    int*    ssrc  = (int*)(ws + alloc((size_t)NE * 4));
    int*    bsums = (int*)(ws + alloc(1024 * 4));
    int*    bsums2= (int*)(ws + alloc(1024 * 4));
    ushort* w0T   = (ushort*)(ws + alloc(768 * HID * 2));
    ushort* w1T   = (ushort*)(ws + alloc(768 * OUTF * 2));
    ushort* wpa   = (ushort*)(ws + alloc(128 * 256 * 2));
    ushort* wpp   = (ushort*)(ws + alloc(128 * 256 * 2));
    float*  pnscr = (float*)(ws + alloc(512 * 4));
    float*  mu0   = (float*)(ws + alloc(129 * 4));
    float*  mu1   = (float*)(ws + alloc(65 * 4));
    float *cs0 = pnscr, *ss0 = pnscr + 128, *cs1 = pnscr + 192, *ss1 = pnscr + 256;

    // prep
    build_wstackT<<<(768 * HID + 255) / 256, 256, 0, stream>>>(comp0, basis0, root0, w0T, HID);
    build_wstackT<<<(768 * OUTF + 255) / 256, 256, 0, stream>>>(comp1, basis1, root1, w1T, OUTF);
    build_wprojT<<<(256 * 128 + 255) / 256, 256, 0, stream>>>(paw, wpa);
    build_wprojT<<<(256 * 128 + 255) / 256, 256, 0, stream>>>(ppw, wpp);
    proj_mfma<<<NN / 16, 256, 0, stream>>>(xa, xp, wpa, wpp, pab, ppb, x0b);

    // segment index (shared by both layers)
    hipMemsetAsync(cnt, 0, (size_t)NSEG * 4, stream);
    hipMemsetAsync(pnscr, 0, 512 * 4, stream);
    hist_kernel<<<(NE + 255) / 256, 256, 0, stream>>>(ei, et, cnt);
    const int nb = (NSEG + 2047) / 2048;
    scan1<<<nb, 256, 0, stream>>>(cnt, offs, bsums, NSEG);
    scan2<<<1, 256, 0, stream>>>(bsums, bsums2, nb);
    scan3<<<(NSEG + 255) / 256, 256, 0, stream>>>(offs, bsums2, cursor, NSEG);
    scatter_kernel<<<(NE + 255) / 256, 256, 0, stream>>>(ei, et, cursor, ssrc);

    // layer 0
    combine_mfma<HID, true><<<NN / 16, 256, 0, stream>>>(x0b, ssrc, offs, cnt, w0T, h0);
    stats_kernel<HID><<<512, 256, 0, stream>>>(h0, cs0, ss0);
    finalize_kernel<HID><<<1, HID, 0, stream>>>(cs0, ss0, mu0);
    float* xlat = out + (size_t)NN * OUTF;
    normalize_dual<<<(NN * HID + 255) / 256, 256, 0, stream>>>(h0, mu0, xlat, xlatb, NN * HID);

    // layer 1
    combine_mfma<OUTF, false><<<NN / 16, 256, 0, stream>>>(xlatb, ssrc, offs, cnt, w1T, h1);
    stats_kernel<OUTF><<<512, 256, 0, stream>>>(h1, cs1, ss1);
    finalize_kernel<OUTF><<<1, OUTF, 0, stream>>>(cs1, ss1, mu1);
    normalize_kernel<OUTF><<<(NN * OUTF + 255) / 256, 256, 0, stream>>>(h1, mu1, out, NN * OUTF);
}

// Round 3
// 678.452 us; speedup vs baseline: 2.2642x; 1.1269x over previous
//
#include <hip/hip_runtime.h>
#include <hip/hip_bf16.h>

constexpr int NPT    = 50000;
constexpr int NN     = 100000;
constexpr int NE     = 1000000;
constexpr int HID    = 128;
constexpr int OUTF   = 64;
constexpr int INF    = 256;
constexpr int NREL   = 5;
constexpr int NSEG   = NN * NREL;

typedef __attribute__((ext_vector_type(8))) short short8v;
typedef __attribute__((ext_vector_type(4))) float f32x4;

__device__ __forceinline__ ushort f2bf(float x) {
    uint u = __builtin_bit_cast(uint, x);
    uint r = (u + 0x7FFFu + ((u >> 16) & 1u)) >> 16;
    return (ushort)r;
}

// ---------------------------------------------------------------------------
// wbT[col][k] bf16, col in [0,384), k in [0,128):
//   col < 320 : rel = col>>6, f = (col&63)+passOff : sum_b comp[r,b]*basis[b,k,f]
//   col >= 320: root[k, (col-320)+passOff]
__global__ void build_wbT(const float* __restrict__ comp,
                          const float* __restrict__ basis,
                          const float* __restrict__ root,
                          ushort* __restrict__ wbT, int fout, int passOff) {
    int idx = blockIdx.x * blockDim.x + threadIdx.x;
    if (idx >= 384 * 128) return;
    int col = idx >> 7, k = idx & 127;
    float v;
    if (col < 320) {
        int r = col >> 6, f = (col & 63) + passOff;
        v = 0.f;
#pragma unroll
        for (int b = 0; b < 8; b++)
            v += comp[r * 8 + b] * basis[(b * 128 + k) * fout + f];
    } else {
        v = root[k * fout + (col - 320) + passOff];
    }
    wbT[col * 128 + k] = f2bf(v);
}

// w[256][128] f32 -> wT[128][256] bf16
__global__ void build_wprojT(const float* __restrict__ w, ushort* __restrict__ wT) {
    int idx = blockIdx.x * blockDim.x + threadIdx.x;
    if (idx >= 256 * 128) return;
    int k = idx >> 7, f = idx & 127;
    wT[(size_t)f * 256 + k] = f2bf(w[idx]);
}

// ---------------------------------------------------------------------------
// proj via MFMA: 16 nodes/block, K=256, N=128. x0b bf16 output.
__launch_bounds__(256, 6)
__global__ void proj_mfma(const float* __restrict__ xa, const float* __restrict__ xp,
                          const ushort* __restrict__ wTa, const ushort* __restrict__ wTp,
                          const float* __restrict__ ba, const float* __restrict__ bp,
                          ushort* __restrict__ x0b) {
    __shared__ ushort sx[16][264];
    const int tid = threadIdx.x;
    const int n0 = blockIdx.x * 16;
    const bool author = n0 < NPT;
    const float* x = author ? xa : xp;
    const ushort* wT = author ? wTa : wTp;
    const float* bias = author ? ba : bp;
    {
        int r = tid >> 4, part = tid & 15;
        size_t rowoff = (size_t)(n0 - (author ? 0 : NPT) + r) * INF + part * 16;
#pragma unroll
        for (int ii = 0; ii < 4; ii++) {
            float4 v = *(const float4*)&x[rowoff + ii * 4];
            ushort4 h = {f2bf(v.x), f2bf(v.y), f2bf(v.z), f2bf(v.w)};
            *(ushort4*)&sx[r][part * 16 + ii * 4] = h;
        }
    }
    __syncthreads();
    const int wave = tid >> 6, lane = tid & 63;
    const int row = lane & 15, g = lane >> 4;
#pragma unroll
    for (int t = 0; t < 2; t++) {
        int ntile = wave * 2 + t;
        int fcol = ntile * 16 + row;
        f32x4 acc = {0.f, 0.f, 0.f, 0.f};
#pragma unroll
        for (int kk = 0; kk < 8; kk++) {
            short8v a = *(const short8v*)&sx[row][kk * 32 + g * 8];
            short8v b = *(const short8v*)&wT[(size_t)fcol * 256 + kk * 32 + g * 8];
            acc = __builtin_amdgcn_mfma_f32_16x16x32_bf16(a, b, acc, 0, 0, 0);
        }
        float bv = bias[fcol];
#pragma unroll
        for (int q = 0; q < 4; q++) {
            int node = g * 4 + q;
            float v = fmaxf(acc[q] + bv, 0.f);
            x0b[(size_t)(n0 + node) * HID + fcol] = f2bf(v);
        }
    }
}

// ---------------------------------------------------------------------------
__global__ void hist_kernel(const int* __restrict__ ei, const int* __restrict__ et,
                            int* __restrict__ cnt) {
    int e = blockIdx.x * blockDim.x + threadIdx.x;
    if (e < NE) {
        int dst = ei[NE + e];
        int r = et[e];
        atomicAdd(&cnt[dst * NREL + r], 1);
    }
}

__global__ void scan1(const int* __restrict__ cnt, int* __restrict__ offs,
                      int* __restrict__ bsums, int n) {
    __shared__ int lds[256];
    const int t = threadIdx.x;
    const int base = blockIdx.x * 2048 + t * 8;
    int vals[8];
    int s = 0;
#pragma unroll
    for (int v = 0; v < 8; v++) {
        int idx = base + v;
        vals[v] = (idx < n) ? cnt[idx] : 0;
        s += vals[v];
    }
    lds[t] = s;
    __syncthreads();
    for (int off = 1; off < 256; off <<= 1) {
        int x = lds[t];
        int y = (t >= off) ? lds[t - off] : 0;
        __syncthreads();
        lds[t] = x + y;
        __syncthreads();
    }
    int run = (t > 0) ? lds[t - 1] : 0;
    if (t == 255) bsums[blockIdx.x] = lds[255];
#pragma unroll
    for (int v = 0; v < 8; v++) {
        int idx = base + v;
        if (idx < n) offs[idx] = run;
        run += vals[v];
    }
}

__global__ void scan2(const int* __restrict__ bsums, int* __restrict__ bsums2, int nb) {
    __shared__ int lds[256];
    const int t = threadIdx.x;
    lds[t] = (t < nb) ? bsums[t] : 0;
    __syncthreads();
    for (int off = 1; off < 256; off <<= 1) {
        int x = lds[t];
        int y = (t >= off) ? lds[t - off] : 0;
        __syncthreads();
        lds[t] = x + y;
        __syncthreads();
    }
    if (t < nb) bsums2[t] = (t > 0) ? lds[t - 1] : 0;
}

__global__ void scan3(int* __restrict__ offs, const int* __restrict__ bsums2,
                      int* __restrict__ cursor, int n) {
    int i = blockIdx.x * blockDim.x + threadIdx.x;
    if (i < n) {
        int v = offs[i] + bsums2[i >> 11];
        offs[i] = v;
        cursor[i] = v;
    }
}

// rows[pos] = rel*NN + src (direct y-table row); escale[pos] = 1/max(cnt,1)
__global__ void scatter_kernel(const int* __restrict__ ei, const int* __restrict__ et,
                               const int* __restrict__ cnt,
                               int* __restrict__ cursor, int* __restrict__ rows,
                               float* __restrict__ escale) {
    int e = blockIdx.x * blockDim.x + threadIdx.x;
    if (e < NE) {
        int src = ei[e];
        int dst = ei[NE + e];
        int r = et[e];
        int seg = dst * NREL + r;
        int pos = atomicAdd(&cursor[seg], 1);
        rows[pos] = r * NN + src;
        int c = cnt[seg];
        escale[pos] = 1.f / (float)((c > 1) ? c : 1);
    }
}

// ---------------------------------------------------------------------------
// Dense GEMM: X[NN x 128] bf16 @ WbigT -> ytab (5 x NN x 64 bf16) + hout root f32.
__launch_bounds__(256)
__global__ void ytab_gemm(const ushort* __restrict__ xin, const ushort* __restrict__ wbT,
                          ushort* __restrict__ ytab, float* __restrict__ hout,
                          int outStride, int outOff) {
    __shared__ ushort sx[16][136];
    const int tid = threadIdx.x;
    const int n0 = blockIdx.x * 16;
    {
        int r = tid >> 4, c = tid & 15;
        *(short8v*)&sx[r][c * 8] = *(const short8v*)&xin[(size_t)(n0 + r) * 128 + c * 8];
    }
    __syncthreads();
    const int wave = tid >> 6, lane = tid & 63;
    const int row = lane & 15, g = lane >> 4;
    short8v a[4];
#pragma unroll
    for (int kk = 0; kk < 4; kk++) a[kk] = *(const short8v*)&sx[row][kk * 32 + g * 8];
    const int colbase = wave * 96;
#pragma unroll
    for (int t = 0; t < 6; t++) {
        const int col = colbase + t * 16 + row;
        f32x4 acc = {0.f, 0.f, 0.f, 0.f};
#pragma unroll
        for (int kk = 0; kk < 4; kk++) {
            short8v b = *(const short8v*)&wbT[(size_t)col * 128 + kk * 32 + g * 8];
            acc = __builtin_amdgcn_mfma_f32_16x16x32_bf16(a[kk], b, acc, 0, 0, 0);
        }
        if (col < 320) {
            const int rel = col >> 6, f = col & 63;
            const size_t base = (size_t)rel * NN * 64 + f;
#pragma unroll
            for (int q = 0; q < 4; q++) {
                int node = n0 + g * 4 + q;
                ytab[base + (size_t)node * 64] = f2bf(acc[q]);
            }
        } else {
            const int f = col - 320;
#pragma unroll
            for (int q = 0; q < 4; q++) {
                int node = n0 + g * 4 + q;
                hout[(size_t)node * outStride + outOff + f] = acc[q];
            }
        }
    }
}

// ---------------------------------------------------------------------------
// Aggregation: hout[n, outOff..outOff+63] += sum_e scale_e * ytab[rows_e].
// 2 edges per wave-iteration (half-wave per edge, 32 lanes x 2 feats each).
__launch_bounds__(256)
__global__ void agg_kernel(const ushort* __restrict__ ytab,
                           const int* __restrict__ rows, const float* __restrict__ escale,
                           const int* __restrict__ offs, const int* __restrict__ cursor,
                           float* __restrict__ hout, int outStride, int outOff) {
    const int tid = threadIdx.x;
    const int wave = tid >> 6, lane = tid & 63;
    const int half = lane >> 5, fl = lane & 31;
    const int n0 = blockIdx.x * 16 + wave * 4;
    for (int rep = 0; rep < 4; rep++) {
        const int n = n0 + rep;
        const int s5 = n * NREL;
        const int start = offs[s5];
        const int end = cursor[s5 + 4];
        const int total = end - start;
        if (total <= 0) continue;
        const size_t hbase = (size_t)n * outStride + outOff + fl * 2;
        float2 hpre = *(const float2*)&hout[hbase];      // RMW load, issued early
        int idxv = rows[start + lane];                   // stage up to 64 idx/scale
        float sclv = escale[start + lane];
        float accx = 0.f, accy = 0.f;
        const int lim = (total > 64) ? 64 : total;
#pragma unroll 2
        for (int j2 = half; j2 < lim; j2 += 2) {
            int rw = __shfl(idxv, j2);
            float sc = __shfl(sclv, j2);
            uint raw = *(const uint*)&ytab[(size_t)rw * 64 + fl * 2];
            float fx = __builtin_bit_cast(float, raw << 16);
            float fy = __builtin_bit_cast(float, raw & 0xFFFF0000u);
            accx += sc * fx;
            accy += sc * fy;
        }
        if (total > 64) {                                // rare fallback
            for (int j = 64 + half; j < total; j += 2) {
                int rw = rows[start + j];
                float sc = escale[start + j];
                uint raw = *(const uint*)&ytab[(size_t)rw * 64 + fl * 2];
                float fx = __builtin_bit_cast(float, raw << 16);
                float fy = __builtin_bit_cast(float, raw & 0xFFFF0000u);
                accx += sc * fx;
                accy += sc * fy;
            }
        }
        accx += __shfl_xor(accx, 32);
        accy += __shfl_xor(accy, 32);
        if (half == 0) {
            float2 o = {hpre.x + accx, hpre.y + accy};
            *(float2*)&hout[hbase] = o;
        }
    }
}

// ---------------------------------------------------------------------------
template <int F, bool RELU>
__global__ void stats_kernel(const float* __restrict__ x, float* __restrict__ colsum,
                             float* __restrict__ sumsq) {
    constexpr int NSUB = 256 / F;
    const int f = threadIdx.x & (F - 1);
    const int sub = threadIdx.x / F;
    float cs = 0.f, ss = 0.f;
    const int stride = gridDim.x * NSUB;
    for (int n = blockIdx.x * NSUB + sub; n < NN; n += stride) {
        float v = x[(size_t)n * F + f];
        if (RELU) v = fmaxf(v, 0.f);
        cs += v;
        ss += v * v;
    }
    __shared__ float sred[256];
    sred[threadIdx.x] = cs;
    __syncthreads();
    if (sub == 0) {
        float t = cs;
#pragma unroll
        for (int s2 = 1; s2 < NSUB; s2++) t += sred[s2 * F + f];
        atomicAdd(&colsum[f], t);
    }
    __syncthreads();
    sred[threadIdx.x] = ss;
    __syncthreads();
    for (int h = 128; h > 0; h >>= 1) {
        if (threadIdx.x < h) sred[threadIdx.x] += sred[threadIdx.x + h];
        __syncthreads();
    }
    if (threadIdx.x == 0) atomicAdd(sumsq, sred[0]);
}

template <int F>
__global__ void finalize_kernel(const float* __restrict__ colsum,
                                const float* __restrict__ sumsq,
                                float* __restrict__ mu_inv) {
    __shared__ float sred[128];
    const int f = threadIdx.x;
    float mu = colsum[f] / (float)NN;
    mu_inv[f] = mu;
    sred[f] = mu * mu;
    __syncthreads();
    for (int h = F / 2; h > 0; h >>= 1) {
        if (f < h) sred[f] += sred[f + h];
        __syncthreads();
    }
    if (f == 0) {
        float var = sumsq[0] / (float)NN - sred[0];
        mu_inv[F] = rsqrtf(1e-5f + var);
    }
}

// layer-0 normalize (in-place over h0==xlat region) + bf16 copy; ReLU on read
__global__ void normalize_dual(const float* __restrict__ x,
                               const float* __restrict__ mu_inv,
                               float* __restrict__ outf, ushort* __restrict__ outb,
                               int total) {
    int i = blockIdx.x * blockDim.x + threadIdx.x;
    if (i < total) {
        int f = i & 127;
        float v = (fmaxf(x[i], 0.f) - mu_inv[f]) * mu_inv[128];
        outf[i] = v;
        outb[i] = f2bf(v);
    }
}

template <int F>
__global__ void normalize_kernel(const float* __restrict__ x,
                                 const float* __restrict__ mu_inv,
                                 float* __restrict__ out, int total) {
    int i = blockIdx.x * blockDim.x + threadIdx.x;
    if (i < total) {
        int f = i & (F - 1);
        out[i] = (x[i] - mu_inv[f]) * mu_inv[F];
    }
}

// ---------------------------------------------------------------------------
extern "C" void kernel_launch(void* const* d_in, const int* in_sizes, int n_in,
                              void* d_out, int out_size, void* d_ws, size_t ws_size,
                              hipStream_t stream) {
    const float* xa    = (const float*)d_in[0];
    const float* xp    = (const float*)d_in[1];
    const int*   ei    = (const int*)d_in[2];
    const int*   et    = (const int*)d_in[3];
    const float* paw   = (const float*)d_in[4];
    const float* pab   = (const float*)d_in[5];
    const float* ppw   = (const float*)d_in[6];
    const float* ppb   = (const float*)d_in[7];
    const float* comp0 = (const float*)d_in[8];
    const float* basis0= (const float*)d_in[9];
    const float* root0 = (const float*)d_in[10];
    const float* comp1 = (const float*)d_in[11];
    const float* basis1= (const float*)d_in[12];
    const float* root1 = (const float*)d_in[13];
    float* out = (float*)d_out;

    char* ws = (char*)d_ws;
    size_t o = 0;
    auto alloc = [&](size_t b) { size_t p = o; o += (b + 255) & ~(size_t)255; return p; };
    ushort* x0b   = (ushort*)(ws + alloc((size_t)NN * HID * 2));        // 25.6 MB
    ushort* xlatb = (ushort*)(ws + alloc((size_t)NN * HID * 2));        // 25.6 MB
    ushort* ytab  = (ushort*)(ws + alloc((size_t)NREL * NN * 64 * 2));  // 64 MB
    int*    cnt   = (int*)(ws + alloc((size_t)NSEG * 4));
    int*    offs  = (int*)(ws + alloc((size_t)NSEG * 4));
    int*    cursor= (int*)(ws + alloc((size_t)NSEG * 4));
    int*    rows  = (int*)(ws + alloc((size_t)(NE + 64) * 4));          // +64 pad
    float*  escal = (float*)(ws + alloc((size_t)(NE + 64) * 4));        // +64 pad
    int*    bsums = (int*)(ws + alloc(1024 * 4));
    int*    bsums2= (int*)(ws + alloc(1024 * 4));
    ushort* wbT0a = (ushort*)(ws + alloc(384 * 128 * 2));
    ushort* wbT0b = (ushort*)(ws + alloc(384 * 128 * 2));
    ushort* wbT1  = (ushort*)(ws + alloc(384 * 128 * 2));
    ushort* wpa   = (ushort*)(ws + alloc(128 * 256 * 2));
    ushort* wpp   = (ushort*)(ws + alloc(128 * 256 * 2));
    float*  pnscr = (float*)(ws + alloc(512 * 4));
    float*  mu0   = (float*)(ws + alloc(129 * 4));
    float*  mu1   = (float*)(ws + alloc(65 * 4));
    float *cs0 = pnscr, *ss0 = pnscr + 128, *cs1 = pnscr + 192, *ss1 = pnscr + 256;

    // h0 lives in d_out's x_latent slice; h1 in d_out's first slice (both
    // fully rewritten every call; normalize passes are elementwise in-place).
    float* h0 = out + (size_t)NN * OUTF;   // [NN][128] f32
    float* h1 = out;                       // [NN][64]  f32
    float* xlat = h0;

    // prep: weights + projection
    build_wbT<<<192, 256, 0, stream>>>(comp0, basis0, root0, wbT0a, HID, 0);
    build_wbT<<<192, 256, 0, stream>>>(comp0, basis0, root0, wbT0b, HID, 64);
    build_wbT<<<192, 256, 0, stream>>>(comp1, basis1, root1, wbT1, OUTF, 0);
    build_wprojT<<<128, 256, 0, stream>>>(paw, wpa);
    build_wprojT<<<128, 256, 0, stream>>>(ppw, wpp);
    proj_mfma<<<NN / 16, 256, 0, stream>>>(xa, xp, wpa, wpp, pab, ppb, x0b);

    // segment index (shared by both layers)
    hipMemsetAsync(cnt, 0, (size_t)NSEG * 4, stream);
    hipMemsetAsync(pnscr, 0, 512 * 4, stream);
    hipMemsetAsync(rows + NE, 0, 64 * 4, stream);
    hipMemsetAsync(escal + NE, 0, 64 * 4, stream);
    hist_kernel<<<(NE + 255) / 256, 256, 0, stream>>>(ei, et, cnt);
    const int nb = (NSEG + 2047) / 2048;
    scan1<<<nb, 256, 0, stream>>>(cnt, offs, bsums, NSEG);
    scan2<<<1, 256, 0, stream>>>(bsums, bsums2, nb);
    scan3<<<(NSEG + 255) / 256, 256, 0, stream>>>(offs, bsums2, cursor, NSEG);
    scatter_kernel<<<(NE + 255) / 256, 256, 0, stream>>>(ei, et, cnt, cursor, rows, escal);

    // layer 0 (two 64-feature halves; ytab reused)
    ytab_gemm<<<NN / 16, 256, 0, stream>>>(x0b, wbT0a, ytab, h0, HID, 0);
    agg_kernel<<<NN / 16, 256, 0, stream>>>(ytab, rows, escal, offs, cursor, h0, HID, 0);
    ytab_gemm<<<NN / 16, 256, 0, stream>>>(x0b, wbT0b, ytab, h0, HID, 64);
    agg_kernel<<<NN / 16, 256, 0, stream>>>(ytab, rows, escal, offs, cursor, h0, HID, 64);
    stats_kernel<HID, true><<<512, 256, 0, stream>>>(h0, cs0, ss0);
    finalize_kernel<HID><<<1, HID, 0, stream>>>(cs0, ss0, mu0);
    normalize_dual<<<(NN * HID + 255) / 256, 256, 0, stream>>>(h0, mu0, xlat, xlatb, NN * HID);

    // layer 1 (single pass)
    ytab_gemm<<<NN / 16, 256, 0, stream>>>(xlatb, wbT1, ytab, h1, OUTF, 0);
    agg_kernel<<<NN / 16, 256, 0, stream>>>(ytab, rows, escal, offs, cursor, h1, OUTF, 0);
    stats_kernel<OUTF, false><<<512, 256, 0, stream>>>(h1, cs1, ss1);
    finalize_kernel<OUTF><<<1, OUTF, 0, stream>>>(cs1, ss1, mu1);
    normalize_kernel<OUTF><<<(NN * OUTF + 255) / 256, 256, 0, stream>>>(h1, mu1, out, NN * OUTF);
}

// Round 4
// 674.046 us; speedup vs baseline: 2.2790x; 1.0065x over previous
//
#include <hip/hip_runtime.h>
#include <hip/hip_bf16.h>

constexpr int NPT    = 50000;
constexpr int NN     = 100000;
constexpr int NE     = 1000000;
constexpr int HID    = 128;
constexpr int OUTF   = 64;
constexpr int INF    = 256;
constexpr int NREL   = 5;
constexpr int NSEG   = NN * NREL;

typedef __attribute__((ext_vector_type(8))) short short8v;
typedef __attribute__((ext_vector_type(4))) float f32x4;

__device__ __forceinline__ ushort f2bf(float x) {
    uint u = __builtin_bit_cast(uint, x);
    uint r = (u + 0x7FFFu + ((u >> 16) & 1u)) >> 16;
    return (ushort)r;
}

// ---------------------------------------------------------------------------
// wbT[col][k] bf16, col in [0,384), k in [0,128):
//   col < 320 : rel = col>>6, f = (col&63)+passOff : sum_b comp[r,b]*basis[b,k,f]
//   col >= 320: root[k, (col-320)+passOff]
__global__ void build_wbT(const float* __restrict__ comp,
                          const float* __restrict__ basis,
                          const float* __restrict__ root,
                          ushort* __restrict__ wbT, int fout, int passOff) {
    int idx = blockIdx.x * blockDim.x + threadIdx.x;
    if (idx >= 384 * 128) return;
    int col = idx >> 7, k = idx & 127;
    float v;
    if (col < 320) {
        int r = col >> 6, f = (col & 63) + passOff;
        v = 0.f;
#pragma unroll
        for (int b = 0; b < 8; b++)
            v += comp[r * 8 + b] * basis[(b * 128 + k) * fout + f];
    } else {
        v = root[k * fout + (col - 320) + passOff];
    }
    wbT[col * 128 + k] = f2bf(v);
}

// w[256][128] f32 -> wT[128][256] bf16
__global__ void build_wprojT(const float* __restrict__ w, ushort* __restrict__ wT) {
    int idx = blockIdx.x * blockDim.x + threadIdx.x;
    if (idx >= 256 * 128) return;
    int k = idx >> 7, f = idx & 127;
    wT[(size_t)f * 256 + k] = f2bf(w[idx]);
}

// ---------------------------------------------------------------------------
// proj via MFMA: 16 nodes/block, K=256, N=128. LDS-staged coalesced output.
__launch_bounds__(256, 6)
__global__ void proj_mfma(const float* __restrict__ xa, const float* __restrict__ xp,
                          const ushort* __restrict__ wTa, const ushort* __restrict__ wTp,
                          const float* __restrict__ ba, const float* __restrict__ bp,
                          ushort* __restrict__ x0b) {
    __shared__ ushort sx[16][264];
    __shared__ ushort so[16][132];   // staged bf16 output (pad 132)
    const int tid = threadIdx.x;
    const int n0 = blockIdx.x * 16;
    const bool author = n0 < NPT;
    const float* x = author ? xa : xp;
    const ushort* wT = author ? wTa : wTp;
    const float* bias = author ? ba : bp;
    {
        int r = tid >> 4, part = tid & 15;
        size_t rowoff = (size_t)(n0 - (author ? 0 : NPT) + r) * INF + part * 16;
#pragma unroll
        for (int ii = 0; ii < 4; ii++) {
            float4 v = *(const float4*)&x[rowoff + ii * 4];
            ushort4 h = {f2bf(v.x), f2bf(v.y), f2bf(v.z), f2bf(v.w)};
            *(ushort4*)&sx[r][part * 16 + ii * 4] = h;
        }
    }
    __syncthreads();
    const int wave = tid >> 6, lane = tid & 63;
    const int row = lane & 15, g = lane >> 4;
#pragma unroll
    for (int t = 0; t < 2; t++) {
        int ntile = wave * 2 + t;
        int fcol = ntile * 16 + row;
        f32x4 acc = {0.f, 0.f, 0.f, 0.f};
#pragma unroll
        for (int kk = 0; kk < 8; kk++) {
            short8v a = *(const short8v*)&sx[row][kk * 32 + g * 8];
            short8v b = *(const short8v*)&wT[(size_t)fcol * 256 + kk * 32 + g * 8];
            acc = __builtin_amdgcn_mfma_f32_16x16x32_bf16(a, b, acc, 0, 0, 0);
        }
        float bv = bias[fcol];
#pragma unroll
        for (int q = 0; q < 4; q++) {
            so[g * 4 + q][fcol] = f2bf(fmaxf(acc[q] + bv, 0.f));
        }
    }
    __syncthreads();
    {   // coalesced flush: 16 nodes x 128 f bf16 = 4KB contiguous at n0*128
        int node = tid >> 4, fb = (tid & 15) * 8;
        ushort4 v0 = *(const ushort4*)&so[node][fb];
        ushort4 v1 = *(const ushort4*)&so[node][fb + 4];
        *(ushort4*)&x0b[(size_t)(n0 + node) * 128 + fb] = v0;
        *(ushort4*)&x0b[(size_t)(n0 + node) * 128 + fb + 4] = v1;
    }
}

// ---------------------------------------------------------------------------
__global__ void hist_kernel(const int* __restrict__ ei, const int* __restrict__ et,
                            int* __restrict__ cnt) {
    int e = blockIdx.x * blockDim.x + threadIdx.x;
    if (e < NE) {
        int dst = ei[NE + e];
        int r = et[e];
        atomicAdd(&cnt[dst * NREL + r], 1);
    }
}

__global__ void scan1(const int* __restrict__ cnt, int* __restrict__ offs,
                      int* __restrict__ bsums, int n) {
    __shared__ int lds[256];
    const int t = threadIdx.x;
    const int base = blockIdx.x * 2048 + t * 8;
    int vals[8];
    int s = 0;
#pragma unroll
    for (int v = 0; v < 8; v++) {
        int idx = base + v;
        vals[v] = (idx < n) ? cnt[idx] : 0;
        s += vals[v];
    }
    lds[t] = s;
    __syncthreads();
    for (int off = 1; off < 256; off <<= 1) {
        int x = lds[t];
        int y = (t >= off) ? lds[t - off] : 0;
        __syncthreads();
        lds[t] = x + y;
        __syncthreads();
    }
    int run = (t > 0) ? lds[t - 1] : 0;
    if (t == 255) bsums[blockIdx.x] = lds[255];
#pragma unroll
    for (int v = 0; v < 8; v++) {
        int idx = base + v;
        if (idx < n) offs[idx] = run;
        run += vals[v];
    }
}

__global__ void scan2(const int* __restrict__ bsums, int* __restrict__ bsums2, int nb) {
    __shared__ int lds[256];
    const int t = threadIdx.x;
    lds[t] = (t < nb) ? bsums[t] : 0;
    __syncthreads();
    for (int off = 1; off < 256; off <<= 1) {
        int x = lds[t];
        int y = (t >= off) ? lds[t - off] : 0;
        __syncthreads();
        lds[t] = x + y;
        __syncthreads();
    }
    if (t < nb) bsums2[t] = (t > 0) ? lds[t - 1] : 0;
}

__global__ void scan3(int* __restrict__ offs, const int* __restrict__ bsums2,
                      int* __restrict__ cursor, int n) {
    int i = blockIdx.x * blockDim.x + threadIdx.x;
    if (i < n) {
        int v = offs[i] + bsums2[i >> 11];
        offs[i] = v;
        cursor[i] = v;
    }
}

// rows[pos] = rel*NN + src (direct y-table row); escale[pos] = 1/max(cnt,1)
__global__ void scatter_kernel(const int* __restrict__ ei, const int* __restrict__ et,
                               const int* __restrict__ cnt,
                               int* __restrict__ cursor, int* __restrict__ rows,
                               float* __restrict__ escale) {
    int e = blockIdx.x * blockDim.x + threadIdx.x;
    if (e < NE) {
        int src = ei[e];
        int dst = ei[NE + e];
        int r = et[e];
        int seg = dst * NREL + r;
        int pos = atomicAdd(&cursor[seg], 1);
        rows[pos] = r * NN + src;
        int c = cnt[seg];
        escale[pos] = 1.f / (float)((c > 1) ? c : 1);
    }
}

// ---------------------------------------------------------------------------
// Dense GEMM: X[NN x 128] bf16 @ WbigT -> ytab (5 x NN x 64 bf16) + hout root f32.
// LDS-staged coalesced output: per rel 2KB contiguous chunk, root 4KB strided rows.
__launch_bounds__(256)
__global__ void ytab_gemm(const ushort* __restrict__ xin, const ushort* __restrict__ wbT,
                          ushort* __restrict__ ytab, float* __restrict__ hout,
                          int outStride, int outOff) {
    __shared__ ushort sx[16][136];
    __shared__ ushort so[16][328];   // y part staging (320 + pad 8)
    __shared__ float sroot[16][68];  // root part staging (64 + pad 4)
    const int tid = threadIdx.x;
    const int n0 = blockIdx.x * 16;
    {
        int r = tid >> 4, c = tid & 15;
        *(short8v*)&sx[r][c * 8] = *(const short8v*)&xin[(size_t)(n0 + r) * 128 + c * 8];
    }
    __syncthreads();
    const int wave = tid >> 6, lane = tid & 63;
    const int row = lane & 15, g = lane >> 4;
    short8v a[4];
#pragma unroll
    for (int kk = 0; kk < 4; kk++) a[kk] = *(const short8v*)&sx[row][kk * 32 + g * 8];
    const int colbase = wave * 96;
#pragma unroll
    for (int t = 0; t < 6; t++) {
        const int col = colbase + t * 16 + row;
        f32x4 acc = {0.f, 0.f, 0.f, 0.f};
#pragma unroll
        for (int kk = 0; kk < 4; kk++) {
            short8v b = *(const short8v*)&wbT[(size_t)col * 128 + kk * 32 + g * 8];
            acc = __builtin_amdgcn_mfma_f32_16x16x32_bf16(a[kk], b, acc, 0, 0, 0);
        }
        if (col < 320) {
#pragma unroll
            for (int q = 0; q < 4; q++) so[g * 4 + q][col] = f2bf(acc[q]);
        } else {
            const int f = col - 320;
#pragma unroll
            for (int q = 0; q < 4; q++) sroot[g * 4 + q][f] = acc[q];
        }
    }
    __syncthreads();
    {   // coalesced flush
        const int node = tid >> 4, fb = (tid & 15) * 4;
#pragma unroll
        for (int r = 0; r < NREL; r++) {
            ushort4 v = *(const ushort4*)&so[node][r * 64 + fb];
            *(ushort4*)&ytab[(size_t)r * NN * 64 + (size_t)(n0 + node) * 64 + fb] = v;
        }
        float4 rv = *(const float4*)&sroot[node][fb];
        *(float4*)&hout[(size_t)(n0 + node) * outStride + outOff + fb] = rv;
    }
}

// ---------------------------------------------------------------------------
// Aggregation: hout[n, outOff..outOff+63] += sum_e scale_e * ytab[rows_e].
// 2 edges per wave-iteration (half-wave per edge, 32 lanes x 2 feats each).
__launch_bounds__(256)
__global__ void agg_kernel(const ushort* __restrict__ ytab,
                           const int* __restrict__ rows, const float* __restrict__ escale,
                           const int* __restrict__ offs, const int* __restrict__ cursor,
                           float* __restrict__ hout, int outStride, int outOff) {
    const int tid = threadIdx.x;
    const int wave = tid >> 6, lane = tid & 63;
    const int half = lane >> 5, fl = lane & 31;
    const int n0 = blockIdx.x * 16 + wave * 4;
    for (int rep = 0; rep < 4; rep++) {
        const int n = n0 + rep;
        const int s5 = n * NREL;
        const int start = offs[s5];
        const int end = cursor[s5 + 4];
        const int total = end - start;
        if (total <= 0) continue;
        const size_t hbase = (size_t)n * outStride + outOff + fl * 2;
        float2 hpre = *(const float2*)&hout[hbase];      // RMW load, issued early
        int idxv = rows[start + lane];                   // stage up to 64 idx/scale
        float sclv = escale[start + lane];
        float accx = 0.f, accy = 0.f;
        const int lim = (total > 64) ? 64 : total;
#pragma unroll 2
        for (int j2 = half; j2 < lim; j2 += 2) {
            int rw = __shfl(idxv, j2);
            float sc = __shfl(sclv, j2);
            uint raw = *(const uint*)&ytab[(size_t)rw * 64 + fl * 2];
            float fx = __builtin_bit_cast(float, raw << 16);
            float fy = __builtin_bit_cast(float, raw & 0xFFFF0000u);
            accx += sc * fx;
            accy += sc * fy;
        }
        if (total > 64) {                                // rare fallback
            for (int j = 64 + half; j < total; j += 2) {
                int rw = rows[start + j];
                float sc = escale[start + j];
                uint raw = *(const uint*)&ytab[(size_t)rw * 64 + fl * 2];
                float fx = __builtin_bit_cast(float, raw << 16);
                float fy = __builtin_bit_cast(float, raw & 0xFFFF0000u);
                accx += sc * fx;
                accy += sc * fy;
            }
        }
        accx += __shfl_xor(accx, 32);
        accy += __shfl_xor(accy, 32);
        if (half == 0) {
            float2 o = {hpre.x + accx, hpre.y + accy};
            *(float2*)&hout[hbase] = o;
        }
    }
}

// ---------------------------------------------------------------------------
template <int F, bool RELU>
__global__ void stats_kernel(const float* __restrict__ x, float* __restrict__ colsum,
                             float* __restrict__ sumsq) {
    constexpr int NSUB = 256 / F;
    const int f = threadIdx.x & (F - 1);
    const int sub = threadIdx.x / F;
    float cs = 0.f, ss = 0.f;
    const int stride = gridDim.x * NSUB;
    for (int n = blockIdx.x * NSUB + sub; n < NN; n += stride) {
        float v = x[(size_t)n * F + f];
        if (RELU) v = fmaxf(v, 0.f);
        cs += v;
        ss += v * v;
    }
    __shared__ float sred[256];
    sred[threadIdx.x] = cs;
    __syncthreads();
    if (sub == 0) {
        float t = cs;
#pragma unroll
        for (int s2 = 1; s2 < NSUB; s2++) t += sred[s2 * F + f];
        atomicAdd(&colsum[f], t);
    }
    __syncthreads();
    sred[threadIdx.x] = ss;
    __syncthreads();
    for (int h = 128; h > 0; h >>= 1) {
        if (threadIdx.x < h) sred[threadIdx.x] += sred[threadIdx.x + h];
        __syncthreads();
    }
    if (threadIdx.x == 0) atomicAdd(sumsq, sred[0]);
}

template <int F>
__global__ void finalize_kernel(const float* __restrict__ colsum,
                                const float* __restrict__ sumsq,
                                float* __restrict__ mu_inv) {
    __shared__ float sred[128];
    const int f = threadIdx.x;
    float mu = colsum[f] / (float)NN;
    mu_inv[f] = mu;
    sred[f] = mu * mu;
    __syncthreads();
    for (int h = F / 2; h > 0; h >>= 1) {
        if (f < h) sred[f] += sred[f + h];
        __syncthreads();
    }
    if (f == 0) {
        float var = sumsq[0] / (float)NN - sred[0];
        mu_inv[F] = rsqrtf(1e-5f + var);
    }
}

// layer-0 normalize (in-place over h0==xlat region) + bf16 copy; ReLU on read
__global__ void normalize_dual(const float* __restrict__ x,
                               const float* __restrict__ mu_inv,
                               float* __restrict__ outf, ushort* __restrict__ outb,
                               int total) {
    int i = blockIdx.x * blockDim.x + threadIdx.x;
    if (i < total) {
        int f = i & 127;
        float v = (fmaxf(x[i], 0.f) - mu_inv[f]) * mu_inv[128];
        outf[i] = v;
        outb[i] = f2bf(v);
    }
}

template <int F>
__global__ void normalize_kernel(const float* __restrict__ x,
                                 const float* __restrict__ mu_inv,
                                 float* __restrict__ out, int total) {
    int i = blockIdx.x * blockDim.x + threadIdx.x;
    if (i < total) {
        int f = i & (F - 1);
        out[i] = (x[i] - mu_inv[f]) * mu_inv[F];
    }
}

// ---------------------------------------------------------------------------
extern "C" void kernel_launch(void* const* d_in, const int* in_sizes, int n_in,
                              void* d_out, int out_size, void* d_ws, size_t ws_size,
                              hipStream_t stream) {
    const float* xa    = (const float*)d_in[0];
    const float* xp    = (const float*)d_in[1];
    const int*   ei    = (const int*)d_in[2];
    const int*   et    = (const int*)d_in[3];
    const float* paw   = (const float*)d_in[4];
    const float* pab   = (const float*)d_in[5];
    const float* ppw   = (const float*)d_in[6];
    const float* ppb   = (const float*)d_in[7];
    const float* comp0 = (const float*)d_in[8];
    const float* basis0= (const float*)d_in[9];
    const float* root0 = (const float*)d_in[10];
    const float* comp1 = (const float*)d_in[11];
    const float* basis1= (const float*)d_in[12];
    const float* root1 = (const float*)d_in[13];
    float* out = (float*)d_out;

    char* ws = (char*)d_ws;
    size_t o = 0;
    auto alloc = [&](size_t b) { size_t p = o; o += (b + 255) & ~(size_t)255; return p; };
    ushort* x0b   = (ushort*)(ws + alloc((size_t)NN * HID * 2));        // 25.6 MB
    ushort* xlatb = (ushort*)(ws + alloc((size_t)NN * HID * 2));        // 25.6 MB
    ushort* ytab  = (ushort*)(ws + alloc((size_t)NREL * NN * 64 * 2));  // 64 MB
    int*    cnt   = (int*)(ws + alloc((size_t)NSEG * 4));
    int*    offs  = (int*)(ws + alloc((size_t)NSEG * 4));
    int*    cursor= (int*)(ws + alloc((size_t)NSEG * 4));
    int*    rows  = (int*)(ws + alloc((size_t)(NE + 64) * 4));          // +64 pad
    float*  escal = (float*)(ws + alloc((size_t)(NE + 64) * 4));        // +64 pad
    int*    bsums = (int*)(ws + alloc(1024 * 4));
    int*    bsums2= (int*)(ws + alloc(1024 * 4));
    ushort* wbT0a = (ushort*)(ws + alloc(384 * 128 * 2));
    ushort* wbT0b = (ushort*)(ws + alloc(384 * 128 * 2));
    ushort* wbT1  = (ushort*)(ws + alloc(384 * 128 * 2));
    ushort* wpa   = (ushort*)(ws + alloc(128 * 256 * 2));
    ushort* wpp   = (ushort*)(ws + alloc(128 * 256 * 2));
    float*  pnscr = (float*)(ws + alloc(512 * 4));
    float*  mu0   = (float*)(ws + alloc(129 * 4));
    float*  mu1   = (float*)(ws + alloc(65 * 4));
    float *cs0 = pnscr, *ss0 = pnscr + 128, *cs1 = pnscr + 192, *ss1 = pnscr + 256;

    // h0 lives in d_out's x_latent slice; h1 in d_out's first slice (both
    // fully rewritten every call; normalize passes are elementwise in-place).
    float* h0 = out + (size_t)NN * OUTF;   // [NN][128] f32
    float* h1 = out;                       // [NN][64]  f32
    float* xlat = h0;

    // prep: weights + projection
    build_wbT<<<192, 256, 0, stream>>>(comp0, basis0, root0, wbT0a, HID, 0);
    build_wbT<<<192, 256, 0, stream>>>(comp0, basis0, root0, wbT0b, HID, 64);
    build_wbT<<<192, 256, 0, stream>>>(comp1, basis1, root1, wbT1, OUTF, 0);
    build_wprojT<<<128, 256, 0, stream>>>(paw, wpa);
    build_wprojT<<<128, 256, 0, stream>>>(ppw, wpp);
    proj_mfma<<<NN / 16, 256, 0, stream>>>(xa, xp, wpa, wpp, pab, ppb, x0b);

    // segment index (shared by both layers)
    hipMemsetAsync(cnt, 0, (size_t)NSEG * 4, stream);
    hipMemsetAsync(pnscr, 0, 512 * 4, stream);
    hipMemsetAsync(rows + NE, 0, 64 * 4, stream);
    hipMemsetAsync(escal + NE, 0, 64 * 4, stream);
    hist_kernel<<<(NE + 255) / 256, 256, 0, stream>>>(ei, et, cnt);
    const int nb = (NSEG + 2047) / 2048;
    scan1<<<nb, 256, 0, stream>>>(cnt, offs, bsums, NSEG);
    scan2<<<1, 256, 0, stream>>>(bsums, bsums2, nb);
    scan3<<<(NSEG + 255) / 256, 256, 0, stream>>>(offs, bsums2, cursor, NSEG);
    scatter_kernel<<<(NE + 255) / 256, 256, 0, stream>>>(ei, et, cnt, cursor, rows, escal);

    // layer 0 (two 64-feature halves; ytab reused)
    ytab_gemm<<<NN / 16, 256, 0, stream>>>(x0b, wbT0a, ytab, h0, HID, 0);
    agg_kernel<<<NN / 16, 256, 0, stream>>>(ytab, rows, escal, offs, cursor, h0, HID, 0);
    ytab_gemm<<<NN / 16, 256, 0, stream>>>(x0b, wbT0b, ytab, h0, HID, 64);
    agg_kernel<<<NN / 16, 256, 0, stream>>>(ytab, rows, escal, offs, cursor, h0, HID, 64);
    stats_kernel<HID, true><<<512, 256, 0, stream>>>(h0, cs0, ss0);
    finalize_kernel<HID><<<1, HID, 0, stream>>>(cs0, ss0, mu0);
    normalize_dual<<<(NN * HID + 255) / 256, 256, 0, stream>>>(h0, mu0, xlat, xlatb, NN * HID);

    // layer 1 (single pass)
    ytab_gemm<<<NN / 16, 256, 0, stream>>>(xlatb, wbT1, ytab, h1, OUTF, 0);
    agg_kernel<<<NN / 16, 256, 0, stream>>>(ytab, rows, escal, offs, cursor, h1, OUTF, 0);
    stats_kernel<OUTF, false><<<512, 256, 0, stream>>>(h1, cs1, ss1);
    finalize_kernel<OUTF><<<1, OUTF, 0, stream>>>(cs1, ss1, mu1);
    normalize_kernel<OUTF><<<(NN * OUTF + 255) / 256, 256, 0, stream>>>(h1, mu1, out, NN * OUTF);
}

// Round 5
// 591.127 us; speedup vs baseline: 2.5987x; 1.1403x over previous
//
#include <hip/hip_runtime.h>
#include <hip/hip_bf16.h>

constexpr int NPT    = 50000;
constexpr int NN     = 100000;
constexpr int NE     = 1000000;
constexpr int HID    = 128;
constexpr int OUTF   = 64;
constexpr int INF    = 256;
constexpr int NREL   = 5;
constexpr int NSEG   = NN * NREL;

typedef __attribute__((ext_vector_type(8))) short short8v;
typedef __attribute__((ext_vector_type(4))) float f32x4;

__device__ __forceinline__ ushort f2bf(float x) {
    uint u = __builtin_bit_cast(uint, x);
    uint r = (u + 0x7FFFu + ((u >> 16) & 1u)) >> 16;
    return (ushort)r;
}

// ---------------------------------------------------------------------------
// wbT[col][k] bf16, col in [0,384), k in [0,128):
//   col < 320 : rel = col>>6, f = (col&63)+passOff : sum_b comp[r,b]*basis[b,k,f]
//   col >= 320: root[k, (col-320)+passOff]
__global__ void build_wbT(const float* __restrict__ comp,
                          const float* __restrict__ basis,
                          const float* __restrict__ root,
                          ushort* __restrict__ wbT, int fout, int passOff) {
    int idx = blockIdx.x * blockDim.x + threadIdx.x;
    if (idx >= 384 * 128) return;
    int col = idx >> 7, k = idx & 127;
    float v;
    if (col < 320) {
        int r = col >> 6, f = (col & 63) + passOff;
        v = 0.f;
#pragma unroll
        for (int b = 0; b < 8; b++)
            v += comp[r * 8 + b] * basis[(b * 128 + k) * fout + f];
    } else {
        v = root[k * fout + (col - 320) + passOff];
    }
    wbT[col * 128 + k] = f2bf(v);
}

// w[256][128] f32 -> wT[128][256] bf16
__global__ void build_wprojT(const float* __restrict__ w, ushort* __restrict__ wT) {
    int idx = blockIdx.x * blockDim.x + threadIdx.x;
    if (idx >= 256 * 128) return;
    int k = idx >> 7, f = idx & 127;
    wT[(size_t)f * 256 + k] = f2bf(w[idx]);
}

// ---------------------------------------------------------------------------
// proj via MFMA: 16 nodes/block, K=256, N=128. A held in regs, B preloaded
// (both tiles) so all VMEM loads are in flight before the MFMA chain.
__launch_bounds__(256, 4)
__global__ void proj_mfma(const float* __restrict__ xa, const float* __restrict__ xp,
                          const ushort* __restrict__ wTa, const ushort* __restrict__ wTp,
                          const float* __restrict__ ba, const float* __restrict__ bp,
                          ushort* __restrict__ x0b) {
    __shared__ ushort sx[16][264];
    __shared__ ushort so[16][132];
    const int tid = threadIdx.x;
    const int n0 = blockIdx.x * 16;
    const bool author = n0 < NPT;
    const float* x = author ? xa : xp;
    const ushort* wT = author ? wTa : wTp;
    const float* bias = author ? ba : bp;
    {
        int r = tid >> 4, part = tid & 15;
        size_t rowoff = (size_t)(n0 - (author ? 0 : NPT) + r) * INF + part * 16;
#pragma unroll
        for (int ii = 0; ii < 4; ii++) {
            float4 v = *(const float4*)&x[rowoff + ii * 4];
            ushort4 h = {f2bf(v.x), f2bf(v.y), f2bf(v.z), f2bf(v.w)};
            *(ushort4*)&sx[r][part * 16 + ii * 4] = h;
        }
    }
    __syncthreads();
    const int wave = tid >> 6, lane = tid & 63;
    const int row = lane & 15, g = lane >> 4;

    const ushort* wp0 = wT + (size_t)(wave * 32 + row) * 256 + g * 8;
    const ushort* wp1 = wp0 + 16 * 256;
    short8v bA[8], bB[8];
#pragma unroll
    for (int kk = 0; kk < 8; kk++) bA[kk] = *(const short8v*)&wp0[kk * 32];
#pragma unroll
    for (int kk = 0; kk < 8; kk++) bB[kk] = *(const short8v*)&wp1[kk * 32];
    short8v a[8];
#pragma unroll
    for (int kk = 0; kk < 8; kk++) a[kk] = *(const short8v*)&sx[row][kk * 32 + g * 8];

    int fcol = wave * 32 + row;
    {
        f32x4 acc = {0.f, 0.f, 0.f, 0.f};
#pragma unroll
        for (int kk = 0; kk < 8; kk++)
            acc = __builtin_amdgcn_mfma_f32_16x16x32_bf16(a[kk], bA[kk], acc, 0, 0, 0);
        float bv = bias[fcol];
#pragma unroll
        for (int q = 0; q < 4; q++)
            so[g * 4 + q][fcol] = f2bf(fmaxf(acc[q] + bv, 0.f));
    }
    {
        f32x4 acc = {0.f, 0.f, 0.f, 0.f};
#pragma unroll
        for (int kk = 0; kk < 8; kk++)
            acc = __builtin_amdgcn_mfma_f32_16x16x32_bf16(a[kk], bB[kk], acc, 0, 0, 0);
        float bv = bias[fcol + 16];
#pragma unroll
        for (int q = 0; q < 4; q++)
            so[g * 4 + q][fcol + 16] = f2bf(fmaxf(acc[q] + bv, 0.f));
    }
    __syncthreads();
    {   // coalesced flush: 16 nodes x 128 bf16 = 4KB contiguous
        int node = tid >> 4, fb = (tid & 15) * 8;
        ushort4 v0 = *(const ushort4*)&so[node][fb];
        ushort4 v1 = *(const ushort4*)&so[node][fb + 4];
        *(ushort4*)&x0b[(size_t)(n0 + node) * 128 + fb] = v0;
        *(ushort4*)&x0b[(size_t)(n0 + node) * 128 + fb + 4] = v1;
    }
}

// ---------------------------------------------------------------------------
__global__ void hist_kernel(const int* __restrict__ ei, const int* __restrict__ et,
                            int* __restrict__ cnt) {
    int e = blockIdx.x * blockDim.x + threadIdx.x;
    if (e < NE) {
        int dst = ei[NE + e];
        int r = et[e];
        atomicAdd(&cnt[dst * NREL + r], 1);
    }
}

__global__ void scan1(const int* __restrict__ cnt, int* __restrict__ offs,
                      int* __restrict__ bsums, int n) {
    __shared__ int lds[256];
    const int t = threadIdx.x;
    const int base = blockIdx.x * 2048 + t * 8;
    int vals[8];
    int s = 0;
#pragma unroll
    for (int v = 0; v < 8; v++) {
        int idx = base + v;
        vals[v] = (idx < n) ? cnt[idx] : 0;
        s += vals[v];
    }
    lds[t] = s;
    __syncthreads();
    for (int off = 1; off < 256; off <<= 1) {
        int x = lds[t];
        int y = (t >= off) ? lds[t - off] : 0;
        __syncthreads();
        lds[t] = x + y;
        __syncthreads();
    }
    int run = (t > 0) ? lds[t - 1] : 0;
    if (t == 255) bsums[blockIdx.x] = lds[255];
#pragma unroll
    for (int v = 0; v < 8; v++) {
        int idx = base + v;
        if (idx < n) offs[idx] = run;
        run += vals[v];
    }
}

__global__ void scan2(const int* __restrict__ bsums, int* __restrict__ bsums2, int nb) {
    __shared__ int lds[256];
    const int t = threadIdx.x;
    lds[t] = (t < nb) ? bsums[t] : 0;
    __syncthreads();
    for (int off = 1; off < 256; off <<= 1) {
        int x = lds[t];
        int y = (t >= off) ? lds[t - off] : 0;
        __syncthreads();
        lds[t] = x + y;
        __syncthreads();
    }
    if (t < nb) bsums2[t] = (t > 0) ? lds[t - 1] : 0;
}

__global__ void scan3(int* __restrict__ offs, const int* __restrict__ bsums2,
                      int* __restrict__ cursor, int n) {
    int i = blockIdx.x * blockDim.x + threadIdx.x;
    if (i < n) {
        int v = offs[i] + bsums2[i >> 11];
        offs[i] = v;
        cursor[i] = v;
    }
}

// rows[pos] = rel*NN + src (direct y-table row); escale[pos] = 1/max(cnt,1)
__global__ void scatter_kernel(const int* __restrict__ ei, const int* __restrict__ et,
                               const int* __restrict__ cnt,
                               int* __restrict__ cursor, int* __restrict__ rows,
                               float* __restrict__ escale) {
    int e = blockIdx.x * blockDim.x + threadIdx.x;
    if (e < NE) {
        int src = ei[e];
        int dst = ei[NE + e];
        int r = et[e];
        int seg = dst * NREL + r;
        int pos = atomicAdd(&cursor[seg], 1);
        rows[pos] = r * NN + src;
        int c = cnt[seg];
        escale[pos] = 1.f / (float)((c > 1) ? c : 1);
    }
}

// ---------------------------------------------------------------------------
// Dense GEMM: X[NN x 128] bf16 @ WbigT[384 cols] -> ytab (5 x NN x 64 bf16) +
// hout root f32. 32 nodes/block (2 m-tiles), A held in regs, B double-buffered
// 2-deep so VMEM loads overlap the MFMA chain. LDS-staged coalesced flush.
__launch_bounds__(256, 4)
__global__ void ytab_gemm(const ushort* __restrict__ xin, const ushort* __restrict__ wbT,
                          ushort* __restrict__ ytab, float* __restrict__ hout,
                          int outStride, int outOff) {
    __shared__ ushort sx[32][136];
    __shared__ ushort so[32][328];
    __shared__ float sroot[32][68];
    const int tid = threadIdx.x;
    const int n0 = blockIdx.x * 32;
    {   // stage 32 rows x 128 ushort (16 ushorts per thread)
        int r = tid >> 3, c = (tid & 7) * 16;
        const ushort* src = &xin[(size_t)(n0 + r) * 128 + c];
        *(short8v*)&sx[r][c] = *(const short8v*)&src[0];
        *(short8v*)&sx[r][c + 8] = *(const short8v*)&src[8];
    }
    __syncthreads();
    const int wave = tid >> 6, lane = tid & 63;
    const int row = lane & 15, g = lane >> 4;
    const int wbase = wave * 96;

    const ushort* wp = wbT + (size_t)(wbase + row) * 128 + g * 8;
    short8v b0[4], b1[4];
    auto loadB = [&](short8v (&buf)[4], int T) {
#pragma unroll
        for (int kk = 0; kk < 4; kk++)
            buf[kk] = *(const short8v*)&wp[T * 2048 + kk * 32];
    };
    loadB(b0, 0);
    loadB(b1, 1);

    short8v a[2][4];
#pragma unroll
    for (int m = 0; m < 2; m++)
#pragma unroll
        for (int kk = 0; kk < 4; kk++)
            a[m][kk] = *(const short8v*)&sx[m * 16 + row][kk * 32 + g * 8];

    auto step = [&](int t, short8v (&bc)[4]) {
        f32x4 acc0 = {0.f, 0.f, 0.f, 0.f};
        f32x4 acc1 = {0.f, 0.f, 0.f, 0.f};
#pragma unroll
        for (int kk = 0; kk < 4; kk++) {
            acc0 = __builtin_amdgcn_mfma_f32_16x16x32_bf16(a[0][kk], bc[kk], acc0, 0, 0, 0);
            acc1 = __builtin_amdgcn_mfma_f32_16x16x32_bf16(a[1][kk], bc[kk], acc1, 0, 0, 0);
        }
        const int col = wbase + t * 16 + row;
        if (col < 320) {   // wave-uniform branch (16-col tiles never straddle 320)
#pragma unroll
            for (int q = 0; q < 4; q++) {
                so[g * 4 + q][col] = f2bf(acc0[q]);
                so[16 + g * 4 + q][col] = f2bf(acc1[q]);
            }
        } else {
            const int f = col - 320;
#pragma unroll
            for (int q = 0; q < 4; q++) {
                sroot[g * 4 + q][f] = acc0[q];
                sroot[16 + g * 4 + q][f] = acc1[q];
            }
        }
    };

#pragma unroll
    for (int tp = 0; tp < 3; tp++) {
        step(tp * 2, b0);
        if (tp < 2) loadB(b0, tp * 2 + 2);
        step(tp * 2 + 1, b1);
        if (tp < 2) loadB(b1, tp * 2 + 3);
    }
    __syncthreads();

    {   // coalesced flush: per rel, 32 nodes x 64 f bf16 = 4KB contiguous
        const int node = tid >> 3, fb = (tid & 7) * 8;
#pragma unroll
        for (int r = 0; r < NREL; r++) {
            short8v v = *(const short8v*)&so[node][r * 64 + fb];
            *(short8v*)&ytab[(size_t)r * NN * 64 + (size_t)(n0 + node) * 64 + fb] = v;
        }
        float4 r0 = *(const float4*)&sroot[node][fb];
        float4 r1 = *(const float4*)&sroot[node][fb + 4];
        float* hp = &hout[(size_t)(n0 + node) * outStride + outOff + fb];
        *(float4*)&hp[0] = r0;
        *(float4*)&hp[4] = r1;
    }
}

// ---------------------------------------------------------------------------
// Aggregation: hout[n, outOff..outOff+63] += sum_e scale_e * ytab[rows_e].
__launch_bounds__(256)
__global__ void agg_kernel(const ushort* __restrict__ ytab,
                           const int* __restrict__ rows, const float* __restrict__ escale,
                           const int* __restrict__ offs, const int* __restrict__ cursor,
                           float* __restrict__ hout, int outStride, int outOff) {
    const int tid = threadIdx.x;
    const int wave = tid >> 6, lane = tid & 63;
    const int half = lane >> 5, fl = lane & 31;
    const int n0 = blockIdx.x * 16 + wave * 4;
    for (int rep = 0; rep < 4; rep++) {
        const int n = n0 + rep;
        const int s5 = n * NREL;
        const int start = offs[s5];
        const int end = cursor[s5 + 4];
        const int total = end - start;
        if (total <= 0) continue;
        const size_t hbase = (size_t)n * outStride + outOff + fl * 2;
        float2 hpre = *(const float2*)&hout[hbase];      // RMW load, issued early
        int idxv = rows[start + lane];                   // stage up to 64 idx/scale
        float sclv = escale[start + lane];
        float accx = 0.f, accy = 0.f;
        const int lim = (total > 64) ? 64 : total;
#pragma unroll 2
        for (int j2 = half; j2 < lim; j2 += 2) {
            int rw = __shfl(idxv, j2);
            float sc = __shfl(sclv, j2);
            uint raw = *(const uint*)&ytab[(size_t)rw * 64 + fl * 2];
            float fx = __builtin_bit_cast(float, raw << 16);
            float fy = __builtin_bit_cast(float, raw & 0xFFFF0000u);
            accx += sc * fx;
            accy += sc * fy;
        }
        if (total > 64) {                                // rare fallback
            for (int j = 64 + half; j < total; j += 2) {
                int rw = rows[start + j];
                float sc = escale[start + j];
                uint raw = *(const uint*)&ytab[(size_t)rw * 64 + fl * 2];
                float fx = __builtin_bit_cast(float, raw << 16);
                float fy = __builtin_bit_cast(float, raw & 0xFFFF0000u);
                accx += sc * fx;
                accy += sc * fy;
            }
        }
        accx += __shfl_xor(accx, 32);
        accy += __shfl_xor(accy, 32);
        if (half == 0) {
            float2 o = {hpre.x + accx, hpre.y + accy};
            *(float2*)&hout[hbase] = o;
        }
    }
}

// ---------------------------------------------------------------------------
template <int F, bool RELU>
__global__ void stats_kernel(const float* __restrict__ x, float* __restrict__ colsum,
                             float* __restrict__ sumsq) {
    constexpr int NSUB = 256 / F;
    const int f = threadIdx.x & (F - 1);
    const int sub = threadIdx.x / F;
    float cs = 0.f, ss = 0.f;
    const int stride = gridDim.x * NSUB;
    for (int n = blockIdx.x * NSUB + sub; n < NN; n += stride) {
        float v = x[(size_t)n * F + f];
        if (RELU) v = fmaxf(v, 0.f);
        cs += v;
        ss += v * v;
    }
    __shared__ float sred[256];
    sred[threadIdx.x] = cs;
    __syncthreads();
    if (sub == 0) {
        float t = cs;
#pragma unroll
        for (int s2 = 1; s2 < NSUB; s2++) t += sred[s2 * F + f];
        atomicAdd(&colsum[f], t);
    }
    __syncthreads();
    sred[threadIdx.x] = ss;
    __syncthreads();
    for (int h = 128; h > 0; h >>= 1) {
        if (threadIdx.x < h) sred[threadIdx.x] += sred[threadIdx.x + h];
        __syncthreads();
    }
    if (threadIdx.x == 0) atomicAdd(sumsq, sred[0]);
}

template <int F>
__global__ void finalize_kernel(const float* __restrict__ colsum,
                                const float* __restrict__ sumsq,
                                float* __restrict__ mu_inv) {
    __shared__ float sred[128];
    const int f = threadIdx.x;
    float mu = colsum[f] / (float)NN;
    mu_inv[f] = mu;
    sred[f] = mu * mu;
    __syncthreads();
    for (int h = F / 2; h > 0; h >>= 1) {
        if (f < h) sred[f] += sred[f + h];
        __syncthreads();
    }
    if (f == 0) {
        float var = sumsq[0] / (float)NN - sred[0];
        mu_inv[F] = rsqrtf(1e-5f + var);
    }
}

// layer-0 normalize (in-place over h0==xlat region) + bf16 copy; ReLU on read
__global__ void normalize_dual(const float* __restrict__ x,
                               const float* __restrict__ mu_inv,
                               float* __restrict__ outf, ushort* __restrict__ outb,
                               int total) {
    int i = blockIdx.x * blockDim.x + threadIdx.x;
    if (i < total) {
        int f = i & 127;
        float v = (fmaxf(x[i], 0.f) - mu_inv[f]) * mu_inv[128];
        outf[i] = v;
        outb[i] = f2bf(v);
    }
}

template <int F>
__global__ void normalize_kernel(const float* __restrict__ x,
                                 const float* __restrict__ mu_inv,
                                 float* __restrict__ out, int total) {
    int i = blockIdx.x * blockDim.x + threadIdx.x;
    if (i < total) {
        int f = i & (F - 1);
        out[i] = (x[i] - mu_inv[f]) * mu_inv[F];
    }
}

// ---------------------------------------------------------------------------
extern "C" void kernel_launch(void* const* d_in, const int* in_sizes, int n_in,
                              void* d_out, int out_size, void* d_ws, size_t ws_size,
                              hipStream_t stream) {
    const float* xa    = (const float*)d_in[0];
    const float* xp    = (const float*)d_in[1];
    const int*   ei    = (const int*)d_in[2];
    const int*   et    = (const int*)d_in[3];
    const float* paw   = (const float*)d_in[4];
    const float* pab   = (const float*)d_in[5];
    const float* ppw   = (const float*)d_in[6];
    const float* ppb   = (const float*)d_in[7];
    const float* comp0 = (const float*)d_in[8];
    const float* basis0= (const float*)d_in[9];
    const float* root0 = (const float*)d_in[10];
    const float* comp1 = (const float*)d_in[11];
    const float* basis1= (const float*)d_in[12];
    const float* root1 = (const float*)d_in[13];
    float* out = (float*)d_out;

    char* ws = (char*)d_ws;
    size_t o = 0;
    auto alloc = [&](size_t b) { size_t p = o; o += (b + 255) & ~(size_t)255; return p; };
    ushort* x0b   = (ushort*)(ws + alloc((size_t)NN * HID * 2));        // 25.6 MB
    ushort* xlatb = (ushort*)(ws + alloc((size_t)NN * HID * 2));        // 25.6 MB
    ushort* ytab  = (ushort*)(ws + alloc((size_t)NREL * NN * 64 * 2));  // 64 MB
    int*    cnt   = (int*)(ws + alloc((size_t)NSEG * 4));
    int*    offs  = (int*)(ws + alloc((size_t)NSEG * 4));
    int*    cursor= (int*)(ws + alloc((size_t)NSEG * 4));
    int*    rows  = (int*)(ws + alloc((size_t)(NE + 64) * 4));          // +64 pad
    float*  escal = (float*)(ws + alloc((size_t)(NE + 64) * 4));        // +64 pad
    int*    bsums = (int*)(ws + alloc(1024 * 4));
    int*    bsums2= (int*)(ws + alloc(1024 * 4));
    ushort* wbT0a = (ushort*)(ws + alloc(384 * 128 * 2));
    ushort* wbT0b = (ushort*)(ws + alloc(384 * 128 * 2));
    ushort* wbT1  = (ushort*)(ws + alloc(384 * 128 * 2));
    ushort* wpa   = (ushort*)(ws + alloc(128 * 256 * 2));
    ushort* wpp   = (ushort*)(ws + alloc(128 * 256 * 2));
    float*  pnscr = (float*)(ws + alloc(512 * 4));
    float*  mu0   = (float*)(ws + alloc(129 * 4));
    float*  mu1   = (float*)(ws + alloc(65 * 4));
    float *cs0 = pnscr, *ss0 = pnscr + 128, *cs1 = pnscr + 192, *ss1 = pnscr + 256;

    float* h0 = out + (size_t)NN * OUTF;   // [NN][128] f32 (x_latent slice)
    float* h1 = out;                       // [NN][64]  f32
    float* xlat = h0;

    // prep: weights + projection
    build_wbT<<<192, 256, 0, stream>>>(comp0, basis0, root0, wbT0a, HID, 0);
    build_wbT<<<192, 256, 0, stream>>>(comp0, basis0, root0, wbT0b, HID, 64);
    build_wbT<<<192, 256, 0, stream>>>(comp1, basis1, root1, wbT1, OUTF, 0);
    build_wprojT<<<128, 256, 0, stream>>>(paw, wpa);
    build_wprojT<<<128, 256, 0, stream>>>(ppw, wpp);
    proj_mfma<<<NN / 16, 256, 0, stream>>>(xa, xp, wpa, wpp, pab, ppb, x0b);

    // segment index (shared by both layers)
    hipMemsetAsync(cnt, 0, (size_t)NSEG * 4, stream);
    hipMemsetAsync(pnscr, 0, 512 * 4, stream);
    hipMemsetAsync(rows + NE, 0, 64 * 4, stream);
    hipMemsetAsync(escal + NE, 0, 64 * 4, stream);
    hist_kernel<<<(NE + 255) / 256, 256, 0, stream>>>(ei, et, cnt);
    const int nb = (NSEG + 2047) / 2048;
    scan1<<<nb, 256, 0, stream>>>(cnt, offs, bsums, NSEG);
    scan2<<<1, 256, 0, stream>>>(bsums, bsums2, nb);
    scan3<<<(NSEG + 255) / 256, 256, 0, stream>>>(offs, bsums2, cursor, NSEG);
    scatter_kernel<<<(NE + 255) / 256, 256, 0, stream>>>(ei, et, cnt, cursor, rows, escal);

    // layer 0 (two 64-feature halves; ytab reused)
    ytab_gemm<<<NN / 32, 256, 0, stream>>>(x0b, wbT0a, ytab, h0, HID, 0);
    agg_kernel<<<NN / 16, 256, 0, stream>>>(ytab, rows, escal, offs, cursor, h0, HID, 0);
    ytab_gemm<<<NN / 32, 256, 0, stream>>>(x0b, wbT0b, ytab, h0, HID, 64);
    agg_kernel<<<NN / 16, 256, 0, stream>>>(ytab, rows, escal, offs, cursor, h0, HID, 64);
    stats_kernel<HID, true><<<512, 256, 0, stream>>>(h0, cs0, ss0);
    finalize_kernel<HID><<<1, HID, 0, stream>>>(cs0, ss0, mu0);
    normalize_dual<<<(NN * HID + 255) / 256, 256, 0, stream>>>(h0, mu0, xlat, xlatb, NN * HID);

    // layer 1 (single pass)
    ytab_gemm<<<NN / 32, 256, 0, stream>>>(xlatb, wbT1, ytab, h1, OUTF, 0);
    agg_kernel<<<NN / 16, 256, 0, stream>>>(ytab, rows, escal, offs, cursor, h1, OUTF, 0);
    stats_kernel<OUTF, false><<<512, 256, 0, stream>>>(h1, cs1, ss1);
    finalize_kernel<OUTF><<<1, OUTF, 0, stream>>>(cs1, ss1, mu1);
    normalize_kernel<OUTF><<<(NN * OUTF + 255) / 256, 256, 0, stream>>>(h1, mu1, out, NN * OUTF);
}

// Round 6
// 567.115 us; speedup vs baseline: 2.7087x; 1.0423x over previous
//
#include <hip/hip_runtime.h>
#include <hip/hip_bf16.h>

constexpr int NPT    = 50000;
constexpr int NN     = 100000;
constexpr int NE     = 1000000;
constexpr int HID    = 128;
constexpr int OUTF   = 64;
constexpr int INF    = 256;
constexpr int NREL   = 5;
constexpr int NSEG   = NN * NREL;

typedef __attribute__((ext_vector_type(8))) short short8v;
typedef __attribute__((ext_vector_type(4))) float f32x4;

__device__ __forceinline__ ushort f2bf(float x) {
    uint u = __builtin_bit_cast(uint, x);
    uint r = (u + 0x7FFFu + ((u >> 16) & 1u)) >> 16;
    return (ushort)r;
}

// ---------------------------------------------------------------------------
// wbT[col][k] bf16, col in [0,384), k in [0,128):
//   col < 320 : rel = col>>6, f = (col&63)+passOff : sum_b comp[r,b]*basis[b,k,f]
//   col >= 320: root[k, (col-320)+passOff]
__global__ void build_wbT(const float* __restrict__ comp,
                          const float* __restrict__ basis,
                          const float* __restrict__ root,
                          ushort* __restrict__ wbT, int fout, int passOff) {
    int idx = blockIdx.x * blockDim.x + threadIdx.x;
    if (idx >= 384 * 128) return;
    int col = idx >> 7, k = idx & 127;
    float v;
    if (col < 320) {
        int r = col >> 6, f = (col & 63) + passOff;
        v = 0.f;
#pragma unroll
        for (int b = 0; b < 8; b++)
            v += comp[r * 8 + b] * basis[(b * 128 + k) * fout + f];
    } else {
        v = root[k * fout + (col - 320) + passOff];
    }
    wbT[col * 128 + k] = f2bf(v);
}

// w[256][128] f32 -> wT[128][256] bf16
__global__ void build_wprojT(const float* __restrict__ w, ushort* __restrict__ wT) {
    int idx = blockIdx.x * blockDim.x + threadIdx.x;
    if (idx >= 256 * 128) return;
    int k = idx >> 7, f = idx & 127;
    wT[(size_t)f * 256 + k] = f2bf(w[idx]);
}

// ---------------------------------------------------------------------------
// proj via MFMA: 16 nodes/block, K=256, N=128.
// All B-frags issued at kernel top (fly under staging); sched_barrier pins
// the load-all-then-compute order so loads stay parallel in flight.
__launch_bounds__(256, 3)
__global__ void proj_mfma(const float* __restrict__ xa, const float* __restrict__ xp,
                          const ushort* __restrict__ wTa, const ushort* __restrict__ wTp,
                          const float* __restrict__ ba, const float* __restrict__ bp,
                          ushort* __restrict__ x0b) {
    __shared__ ushort sx[16][264];
    __shared__ ushort so[16][132];
    const int tid = threadIdx.x;
    const int n0 = blockIdx.x * 16;
    const bool author = n0 < NPT;
    const float* x = author ? xa : xp;
    const ushort* wT = author ? wTa : wTp;
    const float* bias = author ? ba : bp;

    const int wave = tid >> 6, lane = tid & 63;
    const int row = lane & 15, g = lane >> 4;

    // issue ALL B loads first — they complete while we stage A
    const ushort* wp0 = wT + (size_t)(wave * 32 + row) * 256 + g * 8;
    const ushort* wp1 = wp0 + 16 * 256;
    short8v bA[8], bB[8];
#pragma unroll
    for (int kk = 0; kk < 8; kk++) bA[kk] = *(const short8v*)&wp0[kk * 32];
#pragma unroll
    for (int kk = 0; kk < 8; kk++) bB[kk] = *(const short8v*)&wp1[kk * 32];
    __builtin_amdgcn_sched_barrier(0);

    {
        int r = tid >> 4, part = tid & 15;
        size_t rowoff = (size_t)(n0 - (author ? 0 : NPT) + r) * INF + part * 16;
#pragma unroll
        for (int ii = 0; ii < 4; ii++) {
            float4 v = *(const float4*)&x[rowoff + ii * 4];
            ushort4 h = {f2bf(v.x), f2bf(v.y), f2bf(v.z), f2bf(v.w)};
            *(ushort4*)&sx[r][part * 16 + ii * 4] = h;
        }
    }
    __syncthreads();

    short8v a[8];
#pragma unroll
    for (int kk = 0; kk < 8; kk++) a[kk] = *(const short8v*)&sx[row][kk * 32 + g * 8];
    __builtin_amdgcn_sched_barrier(0);

    int fcol = wave * 32 + row;
    {
        f32x4 acc = {0.f, 0.f, 0.f, 0.f};
#pragma unroll
        for (int kk = 0; kk < 8; kk++)
            acc = __builtin_amdgcn_mfma_f32_16x16x32_bf16(a[kk], bA[kk], acc, 0, 0, 0);
        float bv = bias[fcol];
#pragma unroll
        for (int q = 0; q < 4; q++)
            so[g * 4 + q][fcol] = f2bf(fmaxf(acc[q] + bv, 0.f));
    }
    {
        f32x4 acc = {0.f, 0.f, 0.f, 0.f};
#pragma unroll
        for (int kk = 0; kk < 8; kk++)
            acc = __builtin_amdgcn_mfma_f32_16x16x32_bf16(a[kk], bB[kk], acc, 0, 0, 0);
        float bv = bias[fcol + 16];
#pragma unroll
        for (int q = 0; q < 4; q++)
            so[g * 4 + q][fcol + 16] = f2bf(fmaxf(acc[q] + bv, 0.f));
    }
    __syncthreads();
    {   // coalesced flush: 16 nodes x 128 bf16 = 4KB contiguous
        int node = tid >> 4, fb = (tid & 15) * 8;
        ushort4 v0 = *(const ushort4*)&so[node][fb];
        ushort4 v1 = *(const ushort4*)&so[node][fb + 4];
        *(ushort4*)&x0b[(size_t)(n0 + node) * 128 + fb] = v0;
        *(ushort4*)&x0b[(size_t)(n0 + node) * 128 + fb + 4] = v1;
    }
}

// ---------------------------------------------------------------------------
__global__ void hist_kernel(const int* __restrict__ ei, const int* __restrict__ et,
                            int* __restrict__ cnt) {
    int e = blockIdx.x * blockDim.x + threadIdx.x;
    if (e < NE) {
        int dst = ei[NE + e];
        int r = et[e];
        atomicAdd(&cnt[dst * NREL + r], 1);
    }
}

__global__ void scan1(const int* __restrict__ cnt, int* __restrict__ offs,
                      int* __restrict__ bsums, int n) {
    __shared__ int lds[256];
    const int t = threadIdx.x;
    const int base = blockIdx.x * 2048 + t * 8;
    int vals[8];
    int s = 0;
#pragma unroll
    for (int v = 0; v < 8; v++) {
        int idx = base + v;
        vals[v] = (idx < n) ? cnt[idx] : 0;
        s += vals[v];
    }
    lds[t] = s;
    __syncthreads();
    for (int off = 1; off < 256; off <<= 1) {
        int x = lds[t];
        int y = (t >= off) ? lds[t - off] : 0;
        __syncthreads();
        lds[t] = x + y;
        __syncthreads();
    }
    int run = (t > 0) ? lds[t - 1] : 0;
    if (t == 255) bsums[blockIdx.x] = lds[255];
#pragma unroll
    for (int v = 0; v < 8; v++) {
        int idx = base + v;
        if (idx < n) offs[idx] = run;
        run += vals[v];
    }
}

__global__ void scan2(const int* __restrict__ bsums, int* __restrict__ bsums2, int nb) {
    __shared__ int lds[256];
    const int t = threadIdx.x;
    lds[t] = (t < nb) ? bsums[t] : 0;
    __syncthreads();
    for (int off = 1; off < 256; off <<= 1) {
        int x = lds[t];
        int y = (t >= off) ? lds[t - off] : 0;
        __syncthreads();
        lds[t] = x + y;
        __syncthreads();
    }
    if (t < nb) bsums2[t] = (t > 0) ? lds[t - 1] : 0;
}

__global__ void scan3(int* __restrict__ offs, const int* __restrict__ bsums2,
                      int* __restrict__ cursor, int n) {
    int i = blockIdx.x * blockDim.x + threadIdx.x;
    if (i < n) {
        int v = offs[i] + bsums2[i >> 11];
        offs[i] = v;
        cursor[i] = v;
    }
}

// recs[pos] = { rel*NN+src , bitcast(1/max(cnt,1)) } — ONE 8B scatter per edge
__global__ void scatter_kernel(const int* __restrict__ ei, const int* __restrict__ et,
                               const int* __restrict__ cnt,
                               int* __restrict__ cursor, int2* __restrict__ recs) {
    int e = blockIdx.x * blockDim.x + threadIdx.x;
    if (e < NE) {
        int src = ei[e];
        int dst = ei[NE + e];
        int r = et[e];
        int seg = dst * NREL + r;
        int pos = atomicAdd(&cursor[seg], 1);
        int c = cnt[seg];
        float sc = 1.f / (float)((c > 1) ? c : 1);
        int2 rec = {r * NN + src, __builtin_bit_cast(int, sc)};
        recs[pos] = rec;
    }
}

// ---------------------------------------------------------------------------
// Dense GEMM: X[NN x 128] bf16 @ WbigT[384 cols] -> ytab (5 x NN x 64 bf16) +
// hout root f32. 32 nodes/block. Full 6-tile B panel loaded upfront (fly
// under staging), sched_barrier pins load-all-then-compute.
__launch_bounds__(256, 2)
__global__ void ytab_gemm(const ushort* __restrict__ xin, const ushort* __restrict__ wbT,
                          ushort* __restrict__ ytab, float* __restrict__ hout,
                          int outStride, int outOff) {
    __shared__ ushort sx[32][136];
    __shared__ ushort so[32][328];
    __shared__ float sroot[32][68];
    const int tid = threadIdx.x;
    const int n0 = blockIdx.x * 32;
    const int wave = tid >> 6, lane = tid & 63;
    const int row = lane & 15, g = lane >> 4;
    const int wbase = wave * 96;

    // issue ALL 24 B loads first — they complete while we stage A
    const ushort* wp = wbT + (size_t)(wbase + row) * 128 + g * 8;
    short8v B[6][4];
#pragma unroll
    for (int t = 0; t < 6; t++)
#pragma unroll
        for (int kk = 0; kk < 4; kk++)
            B[t][kk] = *(const short8v*)&wp[t * 2048 + kk * 32];
    __builtin_amdgcn_sched_barrier(0);

    {   // stage 32 rows x 128 ushort (16 ushorts per thread)
        int r = tid >> 3, c = (tid & 7) * 16;
        const ushort* src = &xin[(size_t)(n0 + r) * 128 + c];
        *(short8v*)&sx[r][c] = *(const short8v*)&src[0];
        *(short8v*)&sx[r][c + 8] = *(const short8v*)&src[8];
    }
    __syncthreads();

    short8v a[2][4];
#pragma unroll
    for (int m = 0; m < 2; m++)
#pragma unroll
        for (int kk = 0; kk < 4; kk++)
            a[m][kk] = *(const short8v*)&sx[m * 16 + row][kk * 32 + g * 8];
    __builtin_amdgcn_sched_barrier(0);

#pragma unroll
    for (int t = 0; t < 6; t++) {
        f32x4 acc0 = {0.f, 0.f, 0.f, 0.f};
        f32x4 acc1 = {0.f, 0.f, 0.f, 0.f};
#pragma unroll
        for (int kk = 0; kk < 4; kk++) {
            acc0 = __builtin_amdgcn_mfma_f32_16x16x32_bf16(a[0][kk], B[t][kk], acc0, 0, 0, 0);
            acc1 = __builtin_amdgcn_mfma_f32_16x16x32_bf16(a[1][kk], B[t][kk], acc1, 0, 0, 0);
        }
        const int col = wbase + t * 16 + row;
        if (col < 320) {   // wave-uniform (16-col tiles never straddle 320)
#pragma unroll
            for (int q = 0; q < 4; q++) {
                so[g * 4 + q][col] = f2bf(acc0[q]);
                so[16 + g * 4 + q][col] = f2bf(acc1[q]);
            }
        } else {
            const int f = col - 320;
#pragma unroll
            for (int q = 0; q < 4; q++) {
                sroot[g * 4 + q][f] = acc0[q];
                sroot[16 + g * 4 + q][f] = acc1[q];
            }
        }
    }
    __syncthreads();

    {   // coalesced flush: per rel, 32 nodes x 64 bf16 = 4KB contiguous
        const int node = tid >> 3, fb = (tid & 7) * 8;
#pragma unroll
        for (int r = 0; r < NREL; r++) {
            short8v v = *(const short8v*)&so[node][r * 64 + fb];
            *(short8v*)&ytab[(size_t)r * NN * 64 + (size_t)(n0 + node) * 64 + fb] = v;
        }
        float4 r0 = *(const float4*)&sroot[node][fb];
        float4 r1 = *(const float4*)&sroot[node][fb + 4];
        float* hp = &hout[(size_t)(n0 + node) * outStride + outOff + fb];
        *(float4*)&hp[0] = r0;
        *(float4*)&hp[4] = r1;
    }
}

// ---------------------------------------------------------------------------
// Aggregation: hout[n, outOff..outOff+63] += sum_e scale_e * ytab[row_e].
__launch_bounds__(256)
__global__ void agg_kernel(const ushort* __restrict__ ytab,
                           const int2* __restrict__ recs,
                           const int* __restrict__ offs, const int* __restrict__ cursor,
                           float* __restrict__ hout, int outStride, int outOff) {
    const int tid = threadIdx.x;
    const int wave = tid >> 6, lane = tid & 63;
    const int half = lane >> 5, fl = lane & 31;
    const int n0 = blockIdx.x * 16 + wave * 4;
    for (int rep = 0; rep < 4; rep++) {
        const int n = n0 + rep;
        const int s5 = n * NREL;
        const int start = offs[s5];
        const int end = cursor[s5 + 4];
        const int total = end - start;
        if (total <= 0) continue;
        const size_t hbase = (size_t)n * outStride + outOff + fl * 2;
        float2 hpre = *(const float2*)&hout[hbase];      // RMW load, issued early
        int2 rec = recs[start + lane];                   // stage up to 64 records
        float accx = 0.f, accy = 0.f;
        const int lim = (total > 64) ? 64 : total;
#pragma unroll 2
        for (int j2 = half; j2 < lim; j2 += 2) {
            int rw = __shfl(rec.x, j2);
            float sc = __builtin_bit_cast(float, __shfl(rec.y, j2));
            uint raw = *(const uint*)&ytab[(size_t)rw * 64 + fl * 2];
            float fx = __builtin_bit_cast(float, raw << 16);
            float fy = __builtin_bit_cast(float, raw & 0xFFFF0000u);
            accx += sc * fx;
            accy += sc * fy;
        }
        if (total > 64) {                                // rare fallback
            for (int j = 64 + half; j < total; j += 2) {
                int2 r2 = recs[start + j];
                float sc = __builtin_bit_cast(float, r2.y);
                uint raw = *(const uint*)&ytab[(size_t)r2.x * 64 + fl * 2];
                float fx = __builtin_bit_cast(float, raw << 16);
                float fy = __builtin_bit_cast(float, raw & 0xFFFF0000u);
                accx += sc * fx;
                accy += sc * fy;
            }
        }
        accx += __shfl_xor(accx, 32);
        accy += __shfl_xor(accy, 32);
        if (half == 0) {
            float2 o = {hpre.x + accx, hpre.y + accy};
            *(float2*)&hout[hbase] = o;
        }
    }
}

// ---------------------------------------------------------------------------
template <int F, bool RELU>
__global__ void stats_kernel(const float* __restrict__ x, float* __restrict__ colsum,
                             float* __restrict__ sumsq) {
    constexpr int NSUB = 256 / F;
    const int f = threadIdx.x & (F - 1);
    const int sub = threadIdx.x / F;
    float cs = 0.f, ss = 0.f;
    const int stride = gridDim.x * NSUB;
    for (int n = blockIdx.x * NSUB + sub; n < NN; n += stride) {
        float v = x[(size_t)n * F + f];
        if (RELU) v = fmaxf(v, 0.f);
        cs += v;
        ss += v * v;
    }
    __shared__ float sred[256];
    sred[threadIdx.x] = cs;
    __syncthreads();
    if (sub == 0) {
        float t = cs;
#pragma unroll
        for (int s2 = 1; s2 < NSUB; s2++) t += sred[s2 * F + f];
        atomicAdd(&colsum[f], t);
    }
    __syncthreads();
    sred[threadIdx.x] = ss;
    __syncthreads();
    for (int h = 128; h > 0; h >>= 1) {
        if (threadIdx.x < h) sred[threadIdx.x] += sred[threadIdx.x + h];
        __syncthreads();
    }
    if (threadIdx.x == 0) atomicAdd(sumsq, sred[0]);
}

template <int F>
__global__ void finalize_kernel(const float* __restrict__ colsum,
                                const float* __restrict__ sumsq,
                                float* __restrict__ mu_inv) {
    __shared__ float sred[128];
    const int f = threadIdx.x;
    float mu = colsum[f] / (float)NN;
    mu_inv[f] = mu;
    sred[f] = mu * mu;
    __syncthreads();
    for (int h = F / 2; h > 0; h >>= 1) {
        if (f < h) sred[f] += sred[f + h];
        __syncthreads();
    }
    if (f == 0) {
        float var = sumsq[0] / (float)NN - sred[0];
        mu_inv[F] = rsqrtf(1e-5f + var);
    }
}

// layer-0 normalize (in-place over h0==xlat region) + bf16 copy; ReLU on read
__global__ void normalize_dual(const float* __restrict__ x,
                               const float* __restrict__ mu_inv,
                               float* __restrict__ outf, ushort* __restrict__ outb,
                               int total) {
    int i = blockIdx.x * blockDim.x + threadIdx.x;
    if (i < total) {
        int f = i & 127;
        float v = (fmaxf(x[i], 0.f) - mu_inv[f]) * mu_inv[128];
        outf[i] = v;
        outb[i] = f2bf(v);
    }
}

template <int F>
__global__ void normalize_kernel(const float* __restrict__ x,
                                 const float* __restrict__ mu_inv,
                                 float* __restrict__ out, int total) {
    int i = blockIdx.x * blockDim.x + threadIdx.x;
    if (i < total) {
        int f = i & (F - 1);
        out[i] = (x[i] - mu_inv[f]) * mu_inv[F];
    }
}

// ---------------------------------------------------------------------------
extern "C" void kernel_launch(void* const* d_in, const int* in_sizes, int n_in,
                              void* d_out, int out_size, void* d_ws, size_t ws_size,
                              hipStream_t stream) {
    const float* xa    = (const float*)d_in[0];
    const float* xp    = (const float*)d_in[1];
    const int*   ei    = (const int*)d_in[2];
    const int*   et    = (const int*)d_in[3];
    const float* paw   = (const float*)d_in[4];
    const float* pab   = (const float*)d_in[5];
    const float* ppw   = (const float*)d_in[6];
    const float* ppb   = (const float*)d_in[7];
    const float* comp0 = (const float*)d_in[8];
    const float* basis0= (const float*)d_in[9];
    const float* root0 = (const float*)d_in[10];
    const float* comp1 = (const float*)d_in[11];
    const float* basis1= (const float*)d_in[12];
    const float* root1 = (const float*)d_in[13];
    float* out = (float*)d_out;

    char* ws = (char*)d_ws;
    size_t o = 0;
    auto alloc = [&](size_t b) { size_t p = o; o += (b + 255) & ~(size_t)255; return p; };
    ushort* x0b   = (ushort*)(ws + alloc((size_t)NN * HID * 2));        // 25.6 MB
    ushort* xlatb = (ushort*)(ws + alloc((size_t)NN * HID * 2));        // 25.6 MB
    ushort* ytab  = (ushort*)(ws + alloc((size_t)NREL * NN * 64 * 2));  // 64 MB
    int*    cnt   = (int*)(ws + alloc((size_t)NSEG * 4));
    int*    offs  = (int*)(ws + alloc((size_t)NSEG * 4));
    int*    cursor= (int*)(ws + alloc((size_t)NSEG * 4));
    int2*   recs  = (int2*)(ws + alloc((size_t)(NE + 64) * 8));         // +64 pad
    int*    bsums = (int*)(ws + alloc(1024 * 4));
    int*    bsums2= (int*)(ws + alloc(1024 * 4));
    ushort* wbT0a = (ushort*)(ws + alloc(384 * 128 * 2));
    ushort* wbT0b = (ushort*)(ws + alloc(384 * 128 * 2));
    ushort* wbT1  = (ushort*)(ws + alloc(384 * 128 * 2));
    ushort* wpa   = (ushort*)(ws + alloc(128 * 256 * 2));
    ushort* wpp   = (ushort*)(ws + alloc(128 * 256 * 2));
    float*  pnscr = (float*)(ws + alloc(512 * 4));
    float*  mu0   = (float*)(ws + alloc(129 * 4));
    float*  mu1   = (float*)(ws + alloc(65 * 4));
    float *cs0 = pnscr, *ss0 = pnscr + 128, *cs1 = pnscr + 192, *ss1 = pnscr + 256;

    float* h0 = out + (size_t)NN * OUTF;   // [NN][128] f32 (x_latent slice)
    float* h1 = out;                       // [NN][64]  f32
    float* xlat = h0;

    // prep: weights + projection
    build_wbT<<<192, 256, 0, stream>>>(comp0, basis0, root0, wbT0a, HID, 0);
    build_wbT<<<192, 256, 0, stream>>>(comp0, basis0, root0, wbT0b, HID, 64);
    build_wbT<<<192, 256, 0, stream>>>(comp1, basis1, root1, wbT1, OUTF, 0);
    build_wprojT<<<128, 256, 0, stream>>>(paw, wpa);
    build_wprojT<<<128, 256, 0, stream>>>(ppw, wpp);
    proj_mfma<<<NN / 16, 256, 0, stream>>>(xa, xp, wpa, wpp, pab, ppb, x0b);

    // segment index (shared by both layers)
    hipMemsetAsync(cnt, 0, (size_t)NSEG * 4, stream);
    hipMemsetAsync(pnscr, 0, 512 * 4, stream);
    hipMemsetAsync(recs + NE, 0, 64 * 8, stream);
    hist_kernel<<<(NE + 255) / 256, 256, 0, stream>>>(ei, et, cnt);
    const int nb = (NSEG + 2047) / 2048;
    scan1<<<nb, 256, 0, stream>>>(cnt, offs, bsums, NSEG);
    scan2<<<1, 256, 0, stream>>>(bsums, bsums2, nb);
    scan3<<<(NSEG + 255) / 256, 256, 0, stream>>>(offs, bsums2, cursor, NSEG);
    scatter_kernel<<<(NE + 255) / 256, 256, 0, stream>>>(ei, et, cnt, cursor, recs);

    // layer 0 (two 64-feature halves; ytab reused)
    ytab_gemm<<<NN / 32, 256, 0, stream>>>(x0b, wbT0a, ytab, h0, HID, 0);
    agg_kernel<<<NN / 16, 256, 0, stream>>>(ytab, recs, offs, cursor, h0, HID, 0);
    ytab_gemm<<<NN / 32, 256, 0, stream>>>(x0b, wbT0b, ytab, h0, HID, 64);
    agg_kernel<<<NN / 16, 256, 0, stream>>>(ytab, recs, offs, cursor, h0, HID, 64);
    stats_kernel<HID, true><<<512, 256, 0, stream>>>(h0, cs0, ss0);
    finalize_kernel<HID><<<1, HID, 0, stream>>>(cs0, ss0, mu0);
    normalize_dual<<<(NN * HID + 255) / 256, 256, 0, stream>>>(h0, mu0, xlat, xlatb, NN * HID);

    // layer 1 (single pass)
    ytab_gemm<<<NN / 32, 256, 0, stream>>>(xlatb, wbT1, ytab, h1, OUTF, 0);
    agg_kernel<<<NN / 16, 256, 0, stream>>>(ytab, recs, offs, cursor, h1, OUTF, 0);
    stats_kernel<OUTF, false><<<512, 256, 0, stream>>>(h1, cs1, ss1);
    finalize_kernel<OUTF><<<1, OUTF, 0, stream>>>(cs1, ss1, mu1);
    normalize_kernel<OUTF><<<(NN * OUTF + 255) / 256, 256, 0, stream>>>(h1, mu1, out, NN * OUTF);
}

// Round 7
// 502.804 us; speedup vs baseline: 3.0552x; 1.1279x over previous
//
#include <hip/hip_runtime.h>
#include <hip/hip_bf16.h>

constexpr int NPT    = 50000;
constexpr int NN     = 100000;
constexpr int NE     = 1000000;
constexpr int HID    = 128;
constexpr int OUTF   = 64;
constexpr int INF    = 256;
constexpr int NREL   = 5;
constexpr int NSEG   = NN * NREL;

typedef __attribute__((ext_vector_type(8))) short short8v;
typedef __attribute__((ext_vector_type(4))) float f32x4;

__device__ __forceinline__ ushort f2bf(float x) {
    uint u = __builtin_bit_cast(uint, x);
    uint r = (u + 0x7FFFu + ((u >> 16) & 1u)) >> 16;
    return (ushort)r;
}

// ---------------------------------------------------------------------------
// wbT[col][k] bf16, col in [0,384), k in [0,128):
//   col < 320 : rel = col>>6, f = (col&63)+passOff : sum_b comp[r,b]*basis[b,k,f]
//   col >= 320: root[k, (col-320)+passOff]
__global__ void build_wbT(const float* __restrict__ comp,
                          const float* __restrict__ basis,
                          const float* __restrict__ root,
                          ushort* __restrict__ wbT, int fout, int passOff) {
    int idx = blockIdx.x * blockDim.x + threadIdx.x;
    if (idx >= 384 * 128) return;
    int col = idx >> 7, k = idx & 127;
    float v;
    if (col < 320) {
        int r = col >> 6, f = (col & 63) + passOff;
        v = 0.f;
#pragma unroll
        for (int b = 0; b < 8; b++)
            v += comp[r * 8 + b] * basis[(b * 128 + k) * fout + f];
    } else {
        v = root[k * fout + (col - 320) + passOff];
    }
    wbT[col * 128 + k] = f2bf(v);
}

// w[256][128] f32 -> wT[128][256] bf16
__global__ void build_wprojT(const float* __restrict__ w, ushort* __restrict__ wT) {
    int idx = blockIdx.x * blockDim.x + threadIdx.x;
    if (idx >= 256 * 128) return;
    int k = idx >> 7, f = idx & 127;
    wT[(size_t)f * 256 + k] = f2bf(w[idx]);
}

// ---------------------------------------------------------------------------
// proj via MFMA, B-stationary: 1250 blocks (625 author + 625 paper), each
// loops over 5 tiles of 16 nodes. B panel (2 col-tiles/wave, 64 VGPR) is
// loaded ONCE and lives across the loop -> compiler must keep it resident.
__launch_bounds__(256)
__global__ void proj_mfma(const float* __restrict__ xa, const float* __restrict__ xp,
                          const ushort* __restrict__ wTa, const ushort* __restrict__ wTp,
                          const float* __restrict__ ba, const float* __restrict__ bp,
                          ushort* __restrict__ x0b) {
    __shared__ ushort sx[16][264];
    __shared__ ushort so[16][132];
    const int tid = threadIdx.x;
    const bool author = blockIdx.x < 625;
    const int tile0 = (blockIdx.x - (author ? 0 : 625)) * 5;  // tiles within type
    const float* x = author ? xa : xp;
    const ushort* wT = author ? wTa : wTp;
    const float* bias = author ? ba : bp;
    const int typeBase = author ? 0 : NPT;

    const int wave = tid >> 6, lane = tid & 63;
    const int row = lane & 15, g = lane >> 4;
    const int fcol = wave * 32 + row;

    // B resident across the tile loop
    const ushort* wp0 = wT + (size_t)fcol * 256 + g * 8;
    short8v bA[8], bB[8];
#pragma unroll
    for (int kk = 0; kk < 8; kk++) bA[kk] = *(const short8v*)&wp0[kk * 32];
#pragma unroll
    for (int kk = 0; kk < 8; kk++) bB[kk] = *(const short8v*)&wp0[16 * 256 + kk * 32];
    const float bv0 = bias[fcol], bv1 = bias[fcol + 16];

    const int sr = tid >> 4, part = tid & 15;       // staging role
    const int fnode = tid >> 4, fb = (tid & 15) * 8; // flush role

    for (int t = 0; t < 5; t++) {
        const int nloc = (tile0 + t) * 16;          // local node base in type
        {   // stage 16 x 256 f32 -> bf16 LDS
            size_t rowoff = (size_t)(nloc + sr) * INF + part * 16;
#pragma unroll
            for (int ii = 0; ii < 4; ii++) {
                float4 v = *(const float4*)&x[rowoff + ii * 4];
                ushort4 h = {f2bf(v.x), f2bf(v.y), f2bf(v.z), f2bf(v.w)};
                *(ushort4*)&sx[sr][part * 16 + ii * 4] = h;
            }
        }
        __syncthreads();
        short8v a[8];
#pragma unroll
        for (int kk = 0; kk < 8; kk++) a[kk] = *(const short8v*)&sx[row][kk * 32 + g * 8];
        {
            f32x4 acc0 = {0.f, 0.f, 0.f, 0.f};
            f32x4 acc1 = {0.f, 0.f, 0.f, 0.f};
#pragma unroll
            for (int kk = 0; kk < 8; kk++) {
                acc0 = __builtin_amdgcn_mfma_f32_16x16x32_bf16(a[kk], bA[kk], acc0, 0, 0, 0);
                acc1 = __builtin_amdgcn_mfma_f32_16x16x32_bf16(a[kk], bB[kk], acc1, 0, 0, 0);
            }
#pragma unroll
            for (int q = 0; q < 4; q++) {
                so[g * 4 + q][fcol]      = f2bf(fmaxf(acc0[q] + bv0, 0.f));
                so[g * 4 + q][fcol + 16] = f2bf(fmaxf(acc1[q] + bv1, 0.f));
            }
        }
        __syncthreads();
        {   // coalesced flush: 16 nodes x 128 bf16 = 4KB contiguous
            ushort4 v0 = *(const ushort4*)&so[fnode][fb];
            ushort4 v1 = *(const ushort4*)&so[fnode][fb + 4];
            size_t gbase = (size_t)(typeBase + nloc + fnode) * 128 + fb;
            *(ushort4*)&x0b[gbase] = v0;
            *(ushort4*)&x0b[gbase + 4] = v1;
        }
    }
}

// ---------------------------------------------------------------------------
__global__ void hist_kernel(const int* __restrict__ ei, const int* __restrict__ et,
                            int* __restrict__ cnt) {
    int e = blockIdx.x * blockDim.x + threadIdx.x;
    if (e < NE) {
        int dst = ei[NE + e];
        int r = et[e];
        atomicAdd(&cnt[dst * NREL + r], 1);
    }
}

__global__ void scan1(const int* __restrict__ cnt, int* __restrict__ offs,
                      int* __restrict__ bsums, int n) {
    __shared__ int lds[256];
    const int t = threadIdx.x;
    const int base = blockIdx.x * 2048 + t * 8;
    int vals[8];
    int s = 0;
#pragma unroll
    for (int v = 0; v < 8; v++) {
        int idx = base + v;
        vals[v] = (idx < n) ? cnt[idx] : 0;
        s += vals[v];
    }
    lds[t] = s;
    __syncthreads();
    for (int off = 1; off < 256; off <<= 1) {
        int x = lds[t];
        int y = (t >= off) ? lds[t - off] : 0;
        __syncthreads();
        lds[t] = x + y;
        __syncthreads();
    }
    int run = (t > 0) ? lds[t - 1] : 0;
    if (t == 255) bsums[blockIdx.x] = lds[255];
#pragma unroll
    for (int v = 0; v < 8; v++) {
        int idx = base + v;
        if (idx < n) offs[idx] = run;
        run += vals[v];
    }
}

__global__ void scan2(const int* __restrict__ bsums, int* __restrict__ bsums2, int nb) {
    __shared__ int lds[256];
    const int t = threadIdx.x;
    lds[t] = (t < nb) ? bsums[t] : 0;
    __syncthreads();
    for (int off = 1; off < 256; off <<= 1) {
        int x = lds[t];
        int y = (t >= off) ? lds[t - off] : 0;
        __syncthreads();
        lds[t] = x + y;
        __syncthreads();
    }
    if (t < nb) bsums2[t] = (t > 0) ? lds[t - 1] : 0;
}

__global__ void scan3(int* __restrict__ offs, const int* __restrict__ bsums2,
                      int* __restrict__ cursor, int n) {
    int i = blockIdx.x * blockDim.x + threadIdx.x;
    if (i < n) {
        int v = offs[i] + bsums2[i >> 11];
        offs[i] = v;
        cursor[i] = v;
    }
}

// recs[pos] = { rel*NN+src , bitcast(1/max(cnt,1)) } — ONE 8B scatter per edge
__global__ void scatter_kernel(const int* __restrict__ ei, const int* __restrict__ et,
                               const int* __restrict__ cnt,
                               int* __restrict__ cursor, int2* __restrict__ recs) {
    int e = blockIdx.x * blockDim.x + threadIdx.x;
    if (e < NE) {
        int src = ei[e];
        int dst = ei[NE + e];
        int r = et[e];
        int seg = dst * NREL + r;
        int pos = atomicAdd(&cursor[seg], 1);
        int c = cnt[seg];
        float sc = 1.f / (float)((c > 1) ? c : 1);
        int2 rec = {r * NN + src, __builtin_bit_cast(int, sc)};
        recs[pos] = rec;
    }
}

// ---------------------------------------------------------------------------
// Dense GEMM, B-stationary: 625 blocks, each loops over 5 tiles of 32 nodes.
// Full 6-tile B panel per wave (96 VGPR) loaded once, lives across the loop.
__launch_bounds__(256)
__global__ void ytab_gemm(const ushort* __restrict__ xin, const ushort* __restrict__ wbT,
                          ushort* __restrict__ ytab, float* __restrict__ hout,
                          int outStride, int outOff) {
    __shared__ ushort sx[32][136];
    __shared__ ushort so[32][328];
    __shared__ float sroot[32][68];
    const int tid = threadIdx.x;
    const int tile0 = blockIdx.x * 5;
    const int wave = tid >> 6, lane = tid & 63;
    const int row = lane & 15, g = lane >> 4;
    const int wbase = wave * 96;

    // B resident across the tile loop (24 loads, all live)
    const ushort* wp = wbT + (size_t)(wbase + row) * 128 + g * 8;
    short8v B[6][4];
#pragma unroll
    for (int t = 0; t < 6; t++)
#pragma unroll
        for (int kk = 0; kk < 4; kk++)
            B[t][kk] = *(const short8v*)&wp[t * 2048 + kk * 32];

    const int sr = tid >> 3, sc = (tid & 7) * 16;    // staging role
    const int fnode = tid >> 3, fb = (tid & 7) * 8;  // flush role

    for (int tt = 0; tt < 5; tt++) {
        const int n0 = (tile0 + tt) * 32;
        {   // stage 32 rows x 128 bf16
            const ushort* src = &xin[(size_t)(n0 + sr) * 128 + sc];
            *(short8v*)&sx[sr][sc] = *(const short8v*)&src[0];
            *(short8v*)&sx[sr][sc + 8] = *(const short8v*)&src[8];
        }
        __syncthreads();

        short8v a[2][4];
#pragma unroll
        for (int m = 0; m < 2; m++)
#pragma unroll
            for (int kk = 0; kk < 4; kk++)
                a[m][kk] = *(const short8v*)&sx[m * 16 + row][kk * 32 + g * 8];

#pragma unroll
        for (int t = 0; t < 6; t++) {
            f32x4 acc0 = {0.f, 0.f, 0.f, 0.f};
            f32x4 acc1 = {0.f, 0.f, 0.f, 0.f};
#pragma unroll
            for (int kk = 0; kk < 4; kk++) {
                acc0 = __builtin_amdgcn_mfma_f32_16x16x32_bf16(a[0][kk], B[t][kk], acc0, 0, 0, 0);
                acc1 = __builtin_amdgcn_mfma_f32_16x16x32_bf16(a[1][kk], B[t][kk], acc1, 0, 0, 0);
            }
            const int col = wbase + t * 16 + row;
            if (col < 320) {   // wave-uniform (16-col tiles never straddle 320)
#pragma unroll
                for (int q = 0; q < 4; q++) {
                    so[g * 4 + q][col] = f2bf(acc0[q]);
                    so[16 + g * 4 + q][col] = f2bf(acc1[q]);
                }
            } else {
                const int f = col - 320;
#pragma unroll
                for (int q = 0; q < 4; q++) {
                    sroot[g * 4 + q][f] = acc0[q];
                    sroot[16 + g * 4 + q][f] = acc1[q];
                }
            }
        }
        __syncthreads();

        {   // coalesced flush: per rel, 32 nodes x 64 bf16 = 4KB contiguous
#pragma unroll
            for (int r = 0; r < NREL; r++) {
                short8v v = *(const short8v*)&so[fnode][r * 64 + fb];
                *(short8v*)&ytab[(size_t)r * NN * 64 + (size_t)(n0 + fnode) * 64 + fb] = v;
            }
            float4 r0 = *(const float4*)&sroot[fnode][fb];
            float4 r1 = *(const float4*)&sroot[fnode][fb + 4];
            float* hp = &hout[(size_t)(n0 + fnode) * outStride + outOff + fb];
            *(float4*)&hp[0] = r0;
            *(float4*)&hp[4] = r1;
        }
    }
}

// ---------------------------------------------------------------------------
// Aggregation: hout[n, outOff..outOff+63] += sum_e scale_e * ytab[row_e].
__launch_bounds__(256)
__global__ void agg_kernel(const ushort* __restrict__ ytab,
                           const int2* __restrict__ recs,
                           const int* __restrict__ offs, const int* __restrict__ cursor,
                           float* __restrict__ hout, int outStride, int outOff) {
    const int tid = threadIdx.x;
    const int wave = tid >> 6, lane = tid & 63;
    const int half = lane >> 5, fl = lane & 31;
    const int n0 = blockIdx.x * 16 + wave * 4;
    for (int rep = 0; rep < 4; rep++) {
        const int n = n0 + rep;
        const int s5 = n * NREL;
        const int start = offs[s5];
        const int end = cursor[s5 + 4];
        const int total = end - start;
        if (total <= 0) continue;
        const size_t hbase = (size_t)n * outStride + outOff + fl * 2;
        float2 hpre = *(const float2*)&hout[hbase];      // RMW load, issued early
        int2 rec = recs[start + lane];                   // stage up to 64 records
        float accx = 0.f, accy = 0.f;
        const int lim = (total > 64) ? 64 : total;
#pragma unroll 2
        for (int j2 = half; j2 < lim; j2 += 2) {
            int rw = __shfl(rec.x, j2);
            float sc = __builtin_bit_cast(float, __shfl(rec.y, j2));
            uint raw = *(const uint*)&ytab[(size_t)rw * 64 + fl * 2];
            float fx = __builtin_bit_cast(float, raw << 16);
            float fy = __builtin_bit_cast(float, raw & 0xFFFF0000u);
            accx += sc * fx;
            accy += sc * fy;
        }
        if (total > 64) {                                // rare fallback
            for (int j = 64 + half; j < total; j += 2) {
                int2 r2 = recs[start + j];
                float sc = __builtin_bit_cast(float, r2.y);
                uint raw = *(const uint*)&ytab[(size_t)r2.x * 64 + fl * 2];
                float fx = __builtin_bit_cast(float, raw << 16);
                float fy = __builtin_bit_cast(float, raw & 0xFFFF0000u);
                accx += sc * fx;
                accy += sc * fy;
            }
        }
        accx += __shfl_xor(accx, 32);
        accy += __shfl_xor(accy, 32);
        if (half == 0) {
            float2 o = {hpre.x + accx, hpre.y + accy};
            *(float2*)&hout[hbase] = o;
        }
    }
}

// ---------------------------------------------------------------------------
template <int F, bool RELU>
__global__ void stats_kernel(const float* __restrict__ x, float* __restrict__ colsum,
                             float* __restrict__ sumsq) {
    constexpr int NSUB = 256 / F;
    const int f = threadIdx.x & (F - 1);
    const int sub = threadIdx.x / F;
    float cs = 0.f, ss = 0.f;
    const int stride = gridDim.x * NSUB;
    for (int n = blockIdx.x * NSUB + sub; n < NN; n += stride) {
        float v = x[(size_t)n * F + f];
        if (RELU) v = fmaxf(v, 0.f);
        cs += v;
        ss += v * v;
    }
    __shared__ float sred[256];
    sred[threadIdx.x] = cs;
    __syncthreads();
    if (sub == 0) {
        float t = cs;
#pragma unroll
        for (int s2 = 1; s2 < NSUB; s2++) t += sred[s2 * F + f];
        atomicAdd(&colsum[f], t);
    }
    __syncthreads();
    sred[threadIdx.x] = ss;
    __syncthreads();
    for (int h = 128; h > 0; h >>= 1) {
        if (threadIdx.x < h) sred[threadIdx.x] += sred[threadIdx.x + h];
        __syncthreads();
    }
    if (threadIdx.x == 0) atomicAdd(sumsq, sred[0]);
}

template <int F>
__global__ void finalize_kernel(const float* __restrict__ colsum,
                                const float* __restrict__ sumsq,
                                float* __restrict__ mu_inv) {
    __shared__ float sred[128];
    const int f = threadIdx.x;
    float mu = colsum[f] / (float)NN;
    mu_inv[f] = mu;
    sred[f] = mu * mu;
    __syncthreads();
    for (int h = F / 2; h > 0; h >>= 1) {
        if (f < h) sred[f] += sred[f + h];
        __syncthreads();
    }
    if (f == 0) {
        float var = sumsq[0] / (float)NN - sred[0];
        mu_inv[F] = rsqrtf(1e-5f + var);
    }
}

// layer-0 normalize (in-place over h0==xlat region) + bf16 copy; ReLU on read
__global__ void normalize_dual(const float* __restrict__ x,
                               const float* __restrict__ mu_inv,
                               float* __restrict__ outf, ushort* __restrict__ outb,
                               int total) {
    int i = blockIdx.x * blockDim.x + threadIdx.x;
    if (i < total) {
        int f = i & 127;
        float v = (fmaxf(x[i], 0.f) - mu_inv[f]) * mu_inv[128];
        outf[i] = v;
        outb[i] = f2bf(v);
    }
}

template <int F>
__global__ void normalize_kernel(const float* __restrict__ x,
                                 const float* __restrict__ mu_inv,
                                 float* __restrict__ out, int total) {
    int i = blockIdx.x * blockDim.x + threadIdx.x;
    if (i < total) {
        int f = i & (F - 1);
        out[i] = (x[i] - mu_inv[f]) * mu_inv[F];
    }
}

// ---------------------------------------------------------------------------
extern "C" void kernel_launch(void* const* d_in, const int* in_sizes, int n_in,
                              void* d_out, int out_size, void* d_ws, size_t ws_size,
                              hipStream_t stream) {
    const float* xa    = (const float*)d_in[0];
    const float* xp    = (const float*)d_in[1];
    const int*   ei    = (const int*)d_in[2];
    const int*   et    = (const int*)d_in[3];
    const float* paw   = (const float*)d_in[4];
    const float* pab   = (const float*)d_in[5];
    const float* ppw   = (const float*)d_in[6];
    const float* ppb   = (const float*)d_in[7];
    const float* comp0 = (const float*)d_in[8];
    const float* basis0= (const float*)d_in[9];
    const float* root0 = (const float*)d_in[10];
    const float* comp1 = (const float*)d_in[11];
    const float* basis1= (const float*)d_in[12];
    const float* root1 = (const float*)d_in[13];
    float* out = (float*)d_out;

    char* ws = (char*)d_ws;
    size_t o = 0;
    auto alloc = [&](size_t b) { size_t p = o; o += (b + 255) & ~(size_t)255; return p; };
    ushort* x0b   = (ushort*)(ws + alloc((size_t)NN * HID * 2));        // 25.6 MB
    ushort* xlatb = (ushort*)(ws + alloc((size_t)NN * HID * 2));        // 25.6 MB
    ushort* ytab  = (ushort*)(ws + alloc((size_t)NREL * NN * 64 * 2));  // 64 MB
    int*    cnt   = (int*)(ws + alloc((size_t)NSEG * 4));
    int*    offs  = (int*)(ws + alloc((size_t)NSEG * 4));
    int*    cursor= (int*)(ws + alloc((size_t)NSEG * 4));
    int2*   recs  = (int2*)(ws + alloc((size_t)(NE + 64) * 8));         // +64 pad
    int*    bsums = (int*)(ws + alloc(1024 * 4));
    int*    bsums2= (int*)(ws + alloc(1024 * 4));
    ushort* wbT0a = (ushort*)(ws + alloc(384 * 128 * 2));
    ushort* wbT0b = (ushort*)(ws + alloc(384 * 128 * 2));
    ushort* wbT1  = (ushort*)(ws + alloc(384 * 128 * 2));
    ushort* wpa   = (ushort*)(ws + alloc(128 * 256 * 2));
    ushort* wpp   = (ushort*)(ws + alloc(128 * 256 * 2));
    float*  pnscr = (float*)(ws + alloc(512 * 4));
    float*  mu0   = (float*)(ws + alloc(129 * 4));
    float*  mu1   = (float*)(ws + alloc(65 * 4));
    float *cs0 = pnscr, *ss0 = pnscr + 128, *cs1 = pnscr + 192, *ss1 = pnscr + 256;

    float* h0 = out + (size_t)NN * OUTF;   // [NN][128] f32 (x_latent slice)
    float* h1 = out;                       // [NN][64]  f32
    float* xlat = h0;

    // prep: weights + projection
    build_wbT<<<192, 256, 0, stream>>>(comp0, basis0, root0, wbT0a, HID, 0);
    build_wbT<<<192, 256, 0, stream>>>(comp0, basis0, root0, wbT0b, HID, 64);
    build_wbT<<<192, 256, 0, stream>>>(comp1, basis1, root1, wbT1, OUTF, 0);
    build_wprojT<<<128, 256, 0, stream>>>(paw, wpa);
    build_wprojT<<<128, 256, 0, stream>>>(ppw, wpp);
    proj_mfma<<<1250, 256, 0, stream>>>(xa, xp, wpa, wpp, pab, ppb, x0b);

    // segment index (shared by both layers)
    hipMemsetAsync(cnt, 0, (size_t)NSEG * 4, stream);
    hipMemsetAsync(pnscr, 0, 512 * 4, stream);
    hipMemsetAsync(recs + NE, 0, 64 * 8, stream);
    hist_kernel<<<(NE + 255) / 256, 256, 0, stream>>>(ei, et, cnt);
    const int nb = (NSEG + 2047) / 2048;
    scan1<<<nb, 256, 0, stream>>>(cnt, offs, bsums, NSEG);
    scan2<<<1, 256, 0, stream>>>(bsums, bsums2, nb);
    scan3<<<(NSEG + 255) / 256, 256, 0, stream>>>(offs, bsums2, cursor, NSEG);
    scatter_kernel<<<(NE + 255) / 256, 256, 0, stream>>>(ei, et, cnt, cursor, recs);

    // layer 0 (two 64-feature halves; ytab reused)
    ytab_gemm<<<625, 256, 0, stream>>>(x0b, wbT0a, ytab, h0, HID, 0);
    agg_kernel<<<NN / 16, 256, 0, stream>>>(ytab, recs, offs, cursor, h0, HID, 0);
    ytab_gemm<<<625, 256, 0, stream>>>(x0b, wbT0b, ytab, h0, HID, 64);
    agg_kernel<<<NN / 16, 256, 0, stream>>>(ytab, recs, offs, cursor, h0, HID, 64);
    stats_kernel<HID, true><<<512, 256, 0, stream>>>(h0, cs0, ss0);
    finalize_kernel<HID><<<1, HID, 0, stream>>>(cs0, ss0, mu0);
    normalize_dual<<<(NN * HID + 255) / 256, 256, 0, stream>>>(h0, mu0, xlat, xlatb, NN * HID);

    // layer 1 (single pass)
    ytab_gemm<<<625, 256, 0, stream>>>(xlatb, wbT1, ytab, h1, OUTF, 0);
    agg_kernel<<<NN / 16, 256, 0, stream>>>(ytab, recs, offs, cursor, h1, OUTF, 0);
    stats_kernel<OUTF, false><<<512, 256, 0, stream>>>(h1, cs1, ss1);
    finalize_kernel<OUTF><<<1, OUTF, 0, stream>>>(cs1, ss1, mu1);
    normalize_kernel<OUTF><<<(NN * OUTF + 255) / 256, 256, 0, stream>>>(h1, mu1, out, NN * OUTF);
}

// Round 8
// 462.516 us; speedup vs baseline: 3.3213x; 1.0871x over previous
//
#include <hip/hip_runtime.h>
#include <hip/hip_bf16.h>

constexpr int NPT    = 50000;
constexpr int NN     = 100000;
constexpr int NE     = 1000000;
constexpr int HID    = 128;
constexpr int OUTF   = 64;
constexpr int INF    = 256;
constexpr int NREL   = 5;
constexpr int NSEG   = NN * NREL;

typedef __attribute__((ext_vector_type(8))) short short8v;
typedef __attribute__((ext_vector_type(4))) float f32x4;

__device__ __forceinline__ ushort f2bf(float x) {
    uint u = __builtin_bit_cast(uint, x);
    uint r = (u + 0x7FFFu + ((u >> 16) & 1u)) >> 16;
    return (ushort)r;
}

// ---------------------------------------------------------------------------
// fused prep: zero cnt/pnscr/recs-pad + build all weight stacks in ONE launch.
__device__ __forceinline__ void build_wbT_body(const float* __restrict__ comp,
                                               const float* __restrict__ basis,
                                               const float* __restrict__ root,
                                               ushort* __restrict__ wbT,
                                               int fout, int passOff, int idx) {
    int col = idx >> 7, k = idx & 127;
    float v;
    if (col < 320) {
        int r = col >> 6, f = (col & 63) + passOff;
        v = 0.f;
#pragma unroll
        for (int b = 0; b < 8; b++)
            v += comp[r * 8 + b] * basis[(b * 128 + k) * fout + f];
    } else {
        v = root[k * fout + (col - 320) + passOff];
    }
    wbT[col * 128 + k] = f2bf(v);
}

__global__ void prep_kernel(const float* __restrict__ comp0, const float* __restrict__ basis0,
                            const float* __restrict__ root0,
                            const float* __restrict__ comp1, const float* __restrict__ basis1,
                            const float* __restrict__ root1,
                            const float* __restrict__ paw, const float* __restrict__ ppw,
                            ushort* __restrict__ wbT0a, ushort* __restrict__ wbT0b,
                            ushort* __restrict__ wbT1,
                            ushort* __restrict__ wpa, ushort* __restrict__ wpp,
                            int* __restrict__ cnt, float* __restrict__ pnscr,
                            int* __restrict__ recs_pad) {
    const int b = blockIdx.x, t = threadIdx.x;
    if (b < 1954) {                       // zero cnt[NSEG]
        int i = b * 256 + t;
        if (i < NSEG) cnt[i] = 0;
    } else if (b < 1956) {                // zero pnscr[512]
        pnscr[(b - 1954) * 256 + t] = 0.f;
    } else if (b == 1956) {               // zero recs pad (64 int2)
        if (t < 128) recs_pad[t] = 0;
    } else if (b < 2149) {
        build_wbT_body(comp0, basis0, root0, wbT0a, HID, 0, (b - 1957) * 256 + t);
    } else if (b < 2341) {
        build_wbT_body(comp0, basis0, root0, wbT0b, HID, 64, (b - 2149) * 256 + t);
    } else if (b < 2533) {
        build_wbT_body(comp1, basis1, root1, wbT1, OUTF, 0, (b - 2341) * 256 + t);
    } else if (b < 2661) {                // wpa: w[256][128] -> wT[128][256]
        int i = (b - 2533) * 256 + t;
        wpa[(size_t)(i & 127) * 256 + (i >> 7)] = f2bf(paw[i]);
    } else {
        int i = (b - 2661) * 256 + t;
        wpp[(size_t)(i & 127) * 256 + (i >> 7)] = f2bf(ppw[i]);
    }
}

// ---------------------------------------------------------------------------
// proj via MFMA, B-stationary: 1250 blocks (625 author + 625 paper), each
// loops over 5 tiles of 16 nodes. B panel lives across the loop.
__launch_bounds__(256)
__global__ void proj_mfma(const float* __restrict__ xa, const float* __restrict__ xp,
                          const ushort* __restrict__ wTa, const ushort* __restrict__ wTp,
                          const float* __restrict__ ba, const float* __restrict__ bp,
                          ushort* __restrict__ x0b) {
    __shared__ ushort sx[16][264];
    __shared__ ushort so[16][132];
    const int tid = threadIdx.x;
    const bool author = blockIdx.x < 625;
    const int tile0 = (blockIdx.x - (author ? 0 : 625)) * 5;
    const float* x = author ? xa : xp;
    const ushort* wT = author ? wTa : wTp;
    const float* bias = author ? ba : bp;
    const int typeBase = author ? 0 : NPT;

    const int wave = tid >> 6, lane = tid & 63;
    const int row = lane & 15, g = lane >> 4;
    const int fcol = wave * 32 + row;

    const ushort* wp0 = wT + (size_t)fcol * 256 + g * 8;
    short8v bA[8], bB[8];
#pragma unroll
    for (int kk = 0; kk < 8; kk++) bA[kk] = *(const short8v*)&wp0[kk * 32];
#pragma unroll
    for (int kk = 0; kk < 8; kk++) bB[kk] = *(const short8v*)&wp0[16 * 256 + kk * 32];
    const float bv0 = bias[fcol], bv1 = bias[fcol + 16];

    const int sr = tid >> 4, part = tid & 15;
    const int fnode = tid >> 4, fb = (tid & 15) * 8;

    for (int t = 0; t < 5; t++) {
        const int nloc = (tile0 + t) * 16;
        {
            size_t rowoff = (size_t)(nloc + sr) * INF + part * 16;
#pragma unroll
            for (int ii = 0; ii < 4; ii++) {
                float4 v = *(const float4*)&x[rowoff + ii * 4];
                ushort4 h = {f2bf(v.x), f2bf(v.y), f2bf(v.z), f2bf(v.w)};
                *(ushort4*)&sx[sr][part * 16 + ii * 4] = h;
            }
        }
        __syncthreads();
        short8v a[8];
#pragma unroll
        for (int kk = 0; kk < 8; kk++) a[kk] = *(const short8v*)&sx[row][kk * 32 + g * 8];
        {
            f32x4 acc0 = {0.f, 0.f, 0.f, 0.f};
            f32x4 acc1 = {0.f, 0.f, 0.f, 0.f};
#pragma unroll
            for (int kk = 0; kk < 8; kk++) {
                acc0 = __builtin_amdgcn_mfma_f32_16x16x32_bf16(a[kk], bA[kk], acc0, 0, 0, 0);
                acc1 = __builtin_amdgcn_mfma_f32_16x16x32_bf16(a[kk], bB[kk], acc1, 0, 0, 0);
            }
#pragma unroll
            for (int q = 0; q < 4; q++) {
                so[g * 4 + q][fcol]      = f2bf(fmaxf(acc0[q] + bv0, 0.f));
                so[g * 4 + q][fcol + 16] = f2bf(fmaxf(acc1[q] + bv1, 0.f));
            }
        }
        __syncthreads();
        {
            ushort4 v0 = *(const ushort4*)&so[fnode][fb];
            ushort4 v1 = *(const ushort4*)&so[fnode][fb + 4];
            size_t gbase = (size_t)(typeBase + nloc + fnode) * 128 + fb;
            *(ushort4*)&x0b[gbase] = v0;
            *(ushort4*)&x0b[gbase + 4] = v1;
        }
    }
}

// ---------------------------------------------------------------------------
// hist: count segments AND capture each edge's rank within its segment
// (atomic return). rank store is coalesced.
__global__ void hist_kernel(const int* __restrict__ ei, const int* __restrict__ et,
                            int* __restrict__ cnt, int* __restrict__ rank) {
    int e = blockIdx.x * blockDim.x + threadIdx.x;
    if (e < NE) {
        int seg = ei[NE + e] * NREL + et[e];
        rank[e] = atomicAdd(&cnt[seg], 1);
    }
}

__global__ void scan1(const int* __restrict__ cnt, int* __restrict__ offs,
                      int* __restrict__ bsums, int n) {
    __shared__ int lds[256];
    const int t = threadIdx.x;
    const int base = blockIdx.x * 2048 + t * 8;
    int vals[8];
    int s = 0;
#pragma unroll
    for (int v = 0; v < 8; v++) {
        int idx = base + v;
        vals[v] = (idx < n) ? cnt[idx] : 0;
        s += vals[v];
    }
    lds[t] = s;
    __syncthreads();
    for (int off = 1; off < 256; off <<= 1) {
        int x = lds[t];
        int y = (t >= off) ? lds[t - off] : 0;
        __syncthreads();
        lds[t] = x + y;
        __syncthreads();
    }
    int run = (t > 0) ? lds[t - 1] : 0;
    if (t == 255) bsums[blockIdx.x] = lds[255];
#pragma unroll
    for (int v = 0; v < 8; v++) {
        int idx = base + v;
        if (idx < n) offs[idx] = run;
        run += vals[v];
    }
}

__global__ void scan2(const int* __restrict__ bsums, int* __restrict__ bsums2, int nb) {
    __shared__ int lds[256];
    const int t = threadIdx.x;
    lds[t] = (t < nb) ? bsums[t] : 0;
    __syncthreads();
    for (int off = 1; off < 256; off <<= 1) {
        int x = lds[t];
        int y = (t >= off) ? lds[t - off] : 0;
        __syncthreads();
        lds[t] = x + y;
        __syncthreads();
    }
    if (t < nb) bsums2[t] = (t > 0) ? lds[t - 1] : 0;
}

// desc[i] = { global segment offset, count } — one 8B record per segment
__global__ void scan3_desc(const int* __restrict__ offs, const int* __restrict__ bsums2,
                           const int* __restrict__ cnt, int2* __restrict__ desc, int n) {
    int i = blockIdx.x * blockDim.x + threadIdx.x;
    if (i < n) {
        int2 d = {offs[i] + bsums2[i >> 11], cnt[i]};
        desc[i] = d;
    }
}

// atomic-free scatter: pos = desc[seg].x + rank[e]
__global__ void scatter_kernel(const int* __restrict__ ei, const int* __restrict__ et,
                               const int* __restrict__ rank,
                               const int2* __restrict__ desc, int2* __restrict__ recs) {
    int e = blockIdx.x * blockDim.x + threadIdx.x;
    if (e < NE) {
        int src = ei[e];
        int dst = ei[NE + e];
        int r = et[e];
        int2 d = desc[dst * NREL + r];
        int c = d.y;
        float sc = 1.f / (float)((c > 1) ? c : 1);
        int2 rec = {r * NN + src, __builtin_bit_cast(int, sc)};
        recs[d.x + rank[e]] = rec;
    }
}

// ---------------------------------------------------------------------------
// Dense GEMM, B-stationary: 625 blocks, each loops over 5 tiles of 32 nodes.
__launch_bounds__(256)
__global__ void ytab_gemm(const ushort* __restrict__ xin, const ushort* __restrict__ wbT,
                          ushort* __restrict__ ytab, float* __restrict__ hout,
                          int outStride, int outOff) {
    __shared__ ushort sx[32][136];
    __shared__ ushort so[32][328];
    __shared__ float sroot[32][68];
    const int tid = threadIdx.x;
    const int tile0 = blockIdx.x * 5;
    const int wave = tid >> 6, lane = tid & 63;
    const int row = lane & 15, g = lane >> 4;
    const int wbase = wave * 96;

    const ushort* wp = wbT + (size_t)(wbase + row) * 128 + g * 8;
    short8v B[6][4];
#pragma unroll
    for (int t = 0; t < 6; t++)
#pragma unroll
        for (int kk = 0; kk < 4; kk++)
            B[t][kk] = *(const short8v*)&wp[t * 2048 + kk * 32];

    const int sr = tid >> 3, sc = (tid & 7) * 16;
    const int fnode = tid >> 3, fb = (tid & 7) * 8;

    for (int tt = 0; tt < 5; tt++) {
        const int n0 = (tile0 + tt) * 32;
        {
            const ushort* src = &xin[(size_t)(n0 + sr) * 128 + sc];
            *(short8v*)&sx[sr][sc] = *(const short8v*)&src[0];
            *(short8v*)&sx[sr][sc + 8] = *(const short8v*)&src[8];
        }
        __syncthreads();

        short8v a[2][4];
#pragma unroll
        for (int m = 0; m < 2; m++)
#pragma unroll
            for (int kk = 0; kk < 4; kk++)
                a[m][kk] = *(const short8v*)&sx[m * 16 + row][kk * 32 + g * 8];

#pragma unroll
        for (int t = 0; t < 6; t++) {
            f32x4 acc0 = {0.f, 0.f, 0.f, 0.f};
            f32x4 acc1 = {0.f, 0.f, 0.f, 0.f};
#pragma unroll
            for (int kk = 0; kk < 4; kk++) {
                acc0 = __builtin_amdgcn_mfma_f32_16x16x32_bf16(a[0][kk], B[t][kk], acc0, 0, 0, 0);
                acc1 = __builtin_amdgcn_mfma_f32_16x16x32_bf16(a[1][kk], B[t][kk], acc1, 0, 0, 0);
            }
            const int col = wbase + t * 16 + row;
            if (col < 320) {
#pragma unroll
                for (int q = 0; q < 4; q++) {
                    so[g * 4 + q][col] = f2bf(acc0[q]);
                    so[16 + g * 4 + q][col] = f2bf(acc1[q]);
                }
            } else {
                const int f = col - 320;
#pragma unroll
                for (int q = 0; q < 4; q++) {
                    sroot[g * 4 + q][f] = acc0[q];
                    sroot[16 + g * 4 + q][f] = acc1[q];
                }
            }
        }
        __syncthreads();

        {
#pragma unroll
            for (int r = 0; r < NREL; r++) {
                short8v v = *(const short8v*)&so[fnode][r * 64 + fb];
                *(short8v*)&ytab[(size_t)r * NN * 64 + (size_t)(n0 + fnode) * 64 + fb] = v;
            }
            float4 r0 = *(const float4*)&sroot[fnode][fb];
            float4 r1 = *(const float4*)&sroot[fnode][fb + 4];
            float* hp = &hout[(size_t)(n0 + fnode) * outStride + outOff + fb];
            *(float4*)&hp[0] = r0;
            *(float4*)&hp[4] = r1;
        }
    }
}

// ---------------------------------------------------------------------------
// Aggregation: hout[n, outOff..outOff+63] += sum_e scale_e * ytab[row_e].
__launch_bounds__(256)
__global__ void agg_kernel(const ushort* __restrict__ ytab,
                           const int2* __restrict__ recs,
                           const int2* __restrict__ desc,
                           float* __restrict__ hout, int outStride, int outOff) {
    const int tid = threadIdx.x;
    const int wave = tid >> 6, lane = tid & 63;
    const int half = lane >> 5, fl = lane & 31;
    const int n0 = blockIdx.x * 16 + wave * 4;
    for (int rep = 0; rep < 4; rep++) {
        const int n = n0 + rep;
        const int s5 = n * NREL;
        const int2 d0 = desc[s5];
        const int2 d4 = desc[s5 + 4];
        const int start = d0.x;
        const int total = d4.x + d4.y - start;
        if (total <= 0) continue;
        const size_t hbase = (size_t)n * outStride + outOff + fl * 2;
        float2 hpre = *(const float2*)&hout[hbase];      // RMW load, issued early
        int2 rec = recs[start + lane];                   // stage up to 64 records
        float accx = 0.f, accy = 0.f;
        const int lim = (total > 64) ? 64 : total;
#pragma unroll 2
        for (int j2 = half; j2 < lim; j2 += 2) {
            int rw = __shfl(rec.x, j2);
            float sc = __builtin_bit_cast(float, __shfl(rec.y, j2));
            uint raw = *(const uint*)&ytab[(size_t)rw * 64 + fl * 2];
            float fx = __builtin_bit_cast(float, raw << 16);
            float fy = __builtin_bit_cast(float, raw & 0xFFFF0000u);
            accx += sc * fx;
            accy += sc * fy;
        }
        if (total > 64) {                                // rare fallback
            for (int j = 64 + half; j < total; j += 2) {
                int2 r2 = recs[start + j];
                float sc = __builtin_bit_cast(float, r2.y);
                uint raw = *(const uint*)&ytab[(size_t)r2.x * 64 + fl * 2];
                float fx = __builtin_bit_cast(float, raw << 16);
                float fy = __builtin_bit_cast(float, raw & 0xFFFF0000u);
                accx += sc * fx;
                accy += sc * fy;
            }
        }
        accx += __shfl_xor(accx, 32);
        accy += __shfl_xor(accy, 32);
        if (half == 0) {
            float2 o = {hpre.x + accx, hpre.y + accy};
            *(float2*)&hout[hbase] = o;
        }
    }
}

// ---------------------------------------------------------------------------
template <int F, bool RELU>
__global__ void stats_kernel(const float* __restrict__ x, float* __restrict__ colsum,
                             float* __restrict__ sumsq) {
    constexpr int NSUB = 256 / F;
    const int f = threadIdx.x & (F - 1);
    const int sub = threadIdx.x / F;
    float cs = 0.f, ss = 0.f;
    const int stride = gridDim.x * NSUB;
    for (int n = blockIdx.x * NSUB + sub; n < NN; n += stride) {
        float v = x[(size_t)n * F + f];
        if (RELU) v = fmaxf(v, 0.f);
        cs += v;
        ss += v * v;
    }
    __shared__ float sred[256];
    sred[threadIdx.x] = cs;
    __syncthreads();
    if (sub == 0) {
        float t = cs;
#pragma unroll
        for (int s2 = 1; s2 < NSUB; s2++) t += sred[s2 * F + f];
        atomicAdd(&colsum[f], t);
    }
    __syncthreads();
    sred[threadIdx.x] = ss;
    __syncthreads();
    for (int h = 128; h > 0; h >>= 1) {
        if (threadIdx.x < h) sred[threadIdx.x] += sred[threadIdx.x + h];
        __syncthreads();
    }
    if (threadIdx.x == 0) atomicAdd(sumsq, sred[0]);
}

template <int F>
__global__ void finalize_kernel(const float* __restrict__ colsum,
                                const float* __restrict__ sumsq,
                                float* __restrict__ mu_inv) {
    __shared__ float sred[128];
    const int f = threadIdx.x;
    float mu = colsum[f] / (float)NN;
    mu_inv[f] = mu;
    sred[f] = mu * mu;
    __syncthreads();
    for (int h = F / 2; h > 0; h >>= 1) {
        if (f < h) sred[f] += sred[f + h];
        __syncthreads();
    }
    if (f == 0) {
        float var = sumsq[0] / (float)NN - sred[0];
        mu_inv[F] = rsqrtf(1e-5f + var);
    }
}

// layer-0 normalize (in-place) + bf16 copy; ReLU on read; float4-vectorized
__global__ void normalize_dual(const float* __restrict__ x,
                               const float* __restrict__ mu_inv,
                               float* __restrict__ outf, ushort* __restrict__ outb,
                               int total4) {
    int i = blockIdx.x * blockDim.x + threadIdx.x;
    if (i < total4) {
        int base = i * 4;
        int f = base & 127;
        float4 v = *(const float4*)&x[base];
        float4 m = *(const float4*)&mu_inv[f];
        float s = mu_inv[128];
        float4 o = {(fmaxf(v.x, 0.f) - m.x) * s, (fmaxf(v.y, 0.f) - m.y) * s,
                    (fmaxf(v.z, 0.f) - m.z) * s, (fmaxf(v.w, 0.f) - m.w) * s};
        *(float4*)&outf[base] = o;
        ushort4 h = {f2bf(o.x), f2bf(o.y), f2bf(o.z), f2bf(o.w)};
        *(ushort4*)&outb[base] = h;
    }
}

template <int F>
__global__ void normalize_kernel(const float* __restrict__ x,
                                 const float* __restrict__ mu_inv,
                                 float* __restrict__ out, int total4) {
    int i = blockIdx.x * blockDim.x + threadIdx.x;
    if (i < total4) {
        int base = i * 4;
        int f = base & (F - 1);
        float4 v = *(const float4*)&x[base];
        float4 m = *(const float4*)&mu_inv[f];
        float s = mu_inv[F];
        float4 o = {(v.x - m.x) * s, (v.y - m.y) * s, (v.z - m.z) * s, (v.w - m.w) * s};
        *(float4*)&out[base] = o;
    }
}

// ---------------------------------------------------------------------------
extern "C" void kernel_launch(void* const* d_in, const int* in_sizes, int n_in,
                              void* d_out, int out_size, void* d_ws, size_t ws_size,
                              hipStream_t stream) {
    const float* xa    = (const float*)d_in[0];
    const float* xp    = (const float*)d_in[1];
    const int*   ei    = (const int*)d_in[2];
    const int*   et    = (const int*)d_in[3];
    const float* paw   = (const float*)d_in[4];
    const float* pab   = (const float*)d_in[5];
    const float* ppw   = (const float*)d_in[6];
    const float* ppb   = (const float*)d_in[7];
    const float* comp0 = (const float*)d_in[8];
    const float* basis0= (const float*)d_in[9];
    const float* root0 = (const float*)d_in[10];
    const float* comp1 = (const float*)d_in[11];
    const float* basis1= (const float*)d_in[12];
    const float* root1 = (const float*)d_in[13];
    float* out = (float*)d_out;

    char* ws = (char*)d_ws;
    size_t o = 0;
    auto alloc = [&](size_t b) { size_t p = o; o += (b + 255) & ~(size_t)255; return p; };
    ushort* x0b   = (ushort*)(ws + alloc((size_t)NN * HID * 2));        // 25.6 MB
    ushort* xlatb = (ushort*)(ws + alloc((size_t)NN * HID * 2));        // 25.6 MB
    ushort* ytab  = (ushort*)(ws + alloc((size_t)NREL * NN * 64 * 2));  // 64 MB
    int*    cnt   = (int*)(ws + alloc((size_t)NSEG * 4));
    int*    offs  = (int*)(ws + alloc((size_t)NSEG * 4));
    int2*   desc  = (int2*)(ws + alloc((size_t)NSEG * 8));
    int*    rank  = (int*)(ws + alloc((size_t)NE * 4));
    int2*   recs  = (int2*)(ws + alloc((size_t)(NE + 64) * 8));         // +64 pad
    int*    bsums = (int*)(ws + alloc(1024 * 4));
    int*    bsums2= (int*)(ws + alloc(1024 * 4));
    ushort* wbT0a = (ushort*)(ws + alloc(384 * 128 * 2));
    ushort* wbT0b = (ushort*)(ws + alloc(384 * 128 * 2));
    ushort* wbT1  = (ushort*)(ws + alloc(384 * 128 * 2));
    ushort* wpa   = (ushort*)(ws + alloc(128 * 256 * 2));
    ushort* wpp   = (ushort*)(ws + alloc(128 * 256 * 2));
    float*  pnscr = (float*)(ws + alloc(512 * 4));
    float*  mu0   = (float*)(ws + alloc(129 * 4));
    float*  mu1   = (float*)(ws + alloc(65 * 4));
    float *cs0 = pnscr, *ss0 = pnscr + 128, *cs1 = pnscr + 192, *ss1 = pnscr + 256;

    float* h0 = out + (size_t)NN * OUTF;   // [NN][128] f32 (x_latent slice)
    float* h1 = out;                       // [NN][64]  f32
    float* xlat = h0;

    // fused prep (zeros + all weight builds), then projection
    prep_kernel<<<2789, 256, 0, stream>>>(comp0, basis0, root0, comp1, basis1, root1,
                                          paw, ppw, wbT0a, wbT0b, wbT1, wpa, wpp,
                                          cnt, pnscr, (int*)(recs + NE));
    proj_mfma<<<1250, 256, 0, stream>>>(xa, xp, wpa, wpp, pab, ppb, x0b);

    // segment index (shared by both layers)
    hist_kernel<<<(NE + 255) / 256, 256, 0, stream>>>(ei, et, cnt, rank);
    const int nb = (NSEG + 2047) / 2048;
    scan1<<<nb, 256, 0, stream>>>(cnt, offs, bsums, NSEG);
    scan2<<<1, 256, 0, stream>>>(bsums, bsums2, nb);
    scan3_desc<<<(NSEG + 255) / 256, 256, 0, stream>>>(offs, bsums2, cnt, desc, NSEG);
    scatter_kernel<<<(NE + 255) / 256, 256, 0, stream>>>(ei, et, rank, desc, recs);

    // layer 0 (two 64-feature halves; ytab reused)
    ytab_gemm<<<625, 256, 0, stream>>>(x0b, wbT0a, ytab, h0, HID, 0);
    agg_kernel<<<NN / 16, 256, 0, stream>>>(ytab, recs, desc, h0, HID, 0);
    ytab_gemm<<<625, 256, 0, stream>>>(x0b, wbT0b, ytab, h0, HID, 64);
    agg_kernel<<<NN / 16, 256, 0, stream>>>(ytab, recs, desc, h0, HID, 64);
    stats_kernel<HID, true><<<512, 256, 0, stream>>>(h0, cs0, ss0);
    finalize_kernel<HID><<<1, HID, 0, stream>>>(cs0, ss0, mu0);
    normalize_dual<<<(NN * HID / 4 + 255) / 256, 256, 0, stream>>>(h0, mu0, xlat, xlatb,
                                                                   NN * HID / 4);

    // layer 1 (single pass)
    ytab_gemm<<<625, 256, 0, stream>>>(xlatb, wbT1, ytab, h1, OUTF, 0);
    agg_kernel<<<NN / 16, 256, 0, stream>>>(ytab, recs, desc, h1, OUTF, 0);
    stats_kernel<OUTF, false><<<512, 256, 0, stream>>>(h1, cs1, ss1);
    finalize_kernel<OUTF><<<1, OUTF, 0, stream>>>(cs1, ss1, mu1);
    normalize_kernel<OUTF><<<(NN * OUTF / 4 + 255) / 256, 256, 0, stream>>>(h1, mu1, out,
                                                                            NN * OUTF / 4);
}

// Round 9
// 425.198 us; speedup vs baseline: 3.6128x; 1.0878x over previous
//
#include <hip/hip_runtime.h>
#include <hip/hip_bf16.h>

constexpr int NPT    = 50000;
constexpr int NN     = 100000;
constexpr int NE     = 1000000;
constexpr int HID    = 128;
constexpr int OUTF   = 64;
constexpr int INF    = 256;
constexpr int NREL   = 5;
constexpr int NSEG   = NN * NREL;

typedef __attribute__((ext_vector_type(8))) short short8v;
typedef __attribute__((ext_vector_type(4))) float f32x4;

__device__ __forceinline__ ushort f2bf(float x) {
    uint u = __builtin_bit_cast(uint, x);
    uint r = (u + 0x7FFFu + ((u >> 16) & 1u)) >> 16;
    return (ushort)r;
}
__device__ __forceinline__ float bfhi(uint raw) {  // high ushort -> float
    return __builtin_bit_cast(float, raw & 0xFFFF0000u);
}
__device__ __forceinline__ float bflo(uint raw) {  // low ushort -> float
    return __builtin_bit_cast(float, raw << 16);
}

// ---------------------------------------------------------------------------
// fused prep: zero cnt/pnscr/recs-pad + build all weight stacks in ONE launch.
__device__ __forceinline__ void build_wbT_body(const float* __restrict__ comp,
                                               const float* __restrict__ basis,
                                               const float* __restrict__ root,
                                               ushort* __restrict__ wbT,
                                               int fout, int passOff, int idx) {
    int col = idx >> 7, k = idx & 127;
    float v;
    if (col < 320) {
        int r = col >> 6, f = (col & 63) + passOff;
        v = 0.f;
#pragma unroll
        for (int b = 0; b < 8; b++)
            v += comp[r * 8 + b] * basis[(b * 128 + k) * fout + f];
    } else {
        v = root[k * fout + (col - 320) + passOff];
    }
    wbT[col * 128 + k] = f2bf(v);
}

__global__ void prep_kernel(const float* __restrict__ comp0, const float* __restrict__ basis0,
                            const float* __restrict__ root0,
                            const float* __restrict__ comp1, const float* __restrict__ basis1,
                            const float* __restrict__ root1,
                            const float* __restrict__ paw, const float* __restrict__ ppw,
                            ushort* __restrict__ wbT0a, ushort* __restrict__ wbT0b,
                            ushort* __restrict__ wbT1,
                            ushort* __restrict__ wpa, ushort* __restrict__ wpp,
                            int* __restrict__ cnt, float* __restrict__ pnscr,
                            int* __restrict__ recs_pad) {
    const int b = blockIdx.x, t = threadIdx.x;
    if (b < 1954) {                       // zero cnt[NSEG]
        int i = b * 256 + t;
        if (i < NSEG) cnt[i] = 0;
    } else if (b < 1956) {                // zero pnscr[512]
        pnscr[(b - 1954) * 256 + t] = 0.f;
    } else if (b == 1956) {               // zero recs pad (64 int2)
        if (t < 128) recs_pad[t] = 0;
    } else if (b < 2149) {
        build_wbT_body(comp0, basis0, root0, wbT0a, HID, 0, (b - 1957) * 256 + t);
    } else if (b < 2341) {
        build_wbT_body(comp0, basis0, root0, wbT0b, HID, 64, (b - 2149) * 256 + t);
    } else if (b < 2533) {
        build_wbT_body(comp1, basis1, root1, wbT1, OUTF, 0, (b - 2341) * 256 + t);
    } else if (b < 2661) {                // wpa: w[256][128] -> wT[128][256]
        int i = (b - 2533) * 256 + t;
        wpa[(size_t)(i & 127) * 256 + (i >> 7)] = f2bf(paw[i]);
    } else {
        int i = (b - 2661) * 256 + t;
        wpp[(size_t)(i & 127) * 256 + (i >> 7)] = f2bf(ppw[i]);
    }
}

// ---------------------------------------------------------------------------
// proj via MFMA, B-stationary: 1250 blocks (625 author + 625 paper), each
// loops over 5 tiles of 16 nodes. B panel lives across the loop.
__launch_bounds__(256)
__global__ void proj_mfma(const float* __restrict__ xa, const float* __restrict__ xp,
                          const ushort* __restrict__ wTa, const ushort* __restrict__ wTp,
                          const float* __restrict__ ba, const float* __restrict__ bp,
                          ushort* __restrict__ x0b) {
    __shared__ ushort sx[16][264];
    __shared__ ushort so[16][132];
    const int tid = threadIdx.x;
    const bool author = blockIdx.x < 625;
    const int tile0 = (blockIdx.x - (author ? 0 : 625)) * 5;
    const float* x = author ? xa : xp;
    const ushort* wT = author ? wTa : wTp;
    const float* bias = author ? ba : bp;
    const int typeBase = author ? 0 : NPT;

    const int wave = tid >> 6, lane = tid & 63;
    const int row = lane & 15, g = lane >> 4;
    const int fcol = wave * 32 + row;

    const ushort* wp0 = wT + (size_t)fcol * 256 + g * 8;
    short8v bA[8], bB[8];
#pragma unroll
    for (int kk = 0; kk < 8; kk++) bA[kk] = *(const short8v*)&wp0[kk * 32];
#pragma unroll
    for (int kk = 0; kk < 8; kk++) bB[kk] = *(const short8v*)&wp0[16 * 256 + kk * 32];
    const float bv0 = bias[fcol], bv1 = bias[fcol + 16];

    const int sr = tid >> 4, part = tid & 15;
    const int fnode = tid >> 4, fb = (tid & 15) * 8;

    for (int t = 0; t < 5; t++) {
        const int nloc = (tile0 + t) * 16;
        {
            size_t rowoff = (size_t)(nloc + sr) * INF + part * 16;
#pragma unroll
            for (int ii = 0; ii < 4; ii++) {
                float4 v = *(const float4*)&x[rowoff + ii * 4];
                ushort4 h = {f2bf(v.x), f2bf(v.y), f2bf(v.z), f2bf(v.w)};
                *(ushort4*)&sx[sr][part * 16 + ii * 4] = h;
            }
        }
        __syncthreads();
        short8v a[8];
#pragma unroll
        for (int kk = 0; kk < 8; kk++) a[kk] = *(const short8v*)&sx[row][kk * 32 + g * 8];
        {
            f32x4 acc0 = {0.f, 0.f, 0.f, 0.f};
            f32x4 acc1 = {0.f, 0.f, 0.f, 0.f};
#pragma unroll
            for (int kk = 0; kk < 8; kk++) {
                acc0 = __builtin_amdgcn_mfma_f32_16x16x32_bf16(a[kk], bA[kk], acc0, 0, 0, 0);
                acc1 = __builtin_amdgcn_mfma_f32_16x16x32_bf16(a[kk], bB[kk], acc1, 0, 0, 0);
            }
#pragma unroll
            for (int q = 0; q < 4; q++) {
                so[g * 4 + q][fcol]      = f2bf(fmaxf(acc0[q] + bv0, 0.f));
                so[g * 4 + q][fcol + 16] = f2bf(fmaxf(acc1[q] + bv1, 0.f));
            }
        }
        __syncthreads();
        {
            ushort4 v0 = *(const ushort4*)&so[fnode][fb];
            ushort4 v1 = *(const ushort4*)&so[fnode][fb + 4];
            size_t gbase = (size_t)(typeBase + nloc + fnode) * 128 + fb;
            *(ushort4*)&x0b[gbase] = v0;
            *(ushort4*)&x0b[gbase + 4] = v1;
        }
    }
}

// ---------------------------------------------------------------------------
__global__ void hist_kernel(const int* __restrict__ ei, const int* __restrict__ et,
                            int* __restrict__ cnt, int* __restrict__ rank) {
    int e = blockIdx.x * blockDim.x + threadIdx.x;
    if (e < NE) {
        int seg = ei[NE + e] * NREL + et[e];
        rank[e] = atomicAdd(&cnt[seg], 1);
    }
}

__global__ void scan1(const int* __restrict__ cnt, int* __restrict__ offs,
                      int* __restrict__ bsums, int n) {
    __shared__ int lds[256];
    const int t = threadIdx.x;
    const int base = blockIdx.x * 2048 + t * 8;
    int vals[8];
    int s = 0;
#pragma unroll
    for (int v = 0; v < 8; v++) {
        int idx = base + v;
        vals[v] = (idx < n) ? cnt[idx] : 0;
        s += vals[v];
    }
    lds[t] = s;
    __syncthreads();
    for (int off = 1; off < 256; off <<= 1) {
        int x = lds[t];
        int y = (t >= off) ? lds[t - off] : 0;
        __syncthreads();
        lds[t] = x + y;
        __syncthreads();
    }
    int run = (t > 0) ? lds[t - 1] : 0;
    if (t == 255) bsums[blockIdx.x] = lds[255];
#pragma unroll
    for (int v = 0; v < 8; v++) {
        int idx = base + v;
        if (idx < n) offs[idx] = run;
        run += vals[v];
    }
}

__global__ void scan2(const int* __restrict__ bsums, int* __restrict__ bsums2, int nb) {
    __shared__ int lds[256];
    const int t = threadIdx.x;
    lds[t] = (t < nb) ? bsums[t] : 0;
    __syncthreads();
    for (int off = 1; off < 256; off <<= 1) {
        int x = lds[t];
        int y = (t >= off) ? lds[t - off] : 0;
        __syncthreads();
        lds[t] = x + y;
        __syncthreads();
    }
    if (t < nb) bsums2[t] = (t > 0) ? lds[t - 1] : 0;
}

// desc[i] = { global segment offset, count }
__global__ void scan3_desc(const int* __restrict__ offs, const int* __restrict__ bsums2,
                           const int* __restrict__ cnt, int2* __restrict__ desc, int n) {
    int i = blockIdx.x * blockDim.x + threadIdx.x;
    if (i < n) {
        int2 d = {offs[i] + bsums2[i >> 11], cnt[i]};
        desc[i] = d;
    }
}

// atomic-free scatter: pos = desc[seg].x + rank[e]
__global__ void scatter_kernel(const int* __restrict__ ei, const int* __restrict__ et,
                               const int* __restrict__ rank,
                               const int2* __restrict__ desc, int2* __restrict__ recs) {
    int e = blockIdx.x * blockDim.x + threadIdx.x;
    if (e < NE) {
        int src = ei[e];
        int dst = ei[NE + e];
        int r = et[e];
        int2 d = desc[dst * NREL + r];
        int c = d.y;
        float sc = 1.f / (float)((c > 1) ? c : 1);
        int2 rec = {r * NN + src, __builtin_bit_cast(int, sc)};
        recs[d.x + rank[e]] = rec;
    }
}

// ---------------------------------------------------------------------------
// Dense GEMM, B-stationary: 625 blocks x 5 tiles of 32 nodes. ytabW-wide rows.
__launch_bounds__(256)
__global__ void ytab_gemm(const ushort* __restrict__ xin, const ushort* __restrict__ wbT,
                          ushort* __restrict__ ytab, float* __restrict__ hout,
                          int ytabW, int outStride, int outOff) {
    __shared__ ushort sx[32][136];
    __shared__ ushort so[32][328];
    __shared__ float sroot[32][68];
    const int tid = threadIdx.x;
    const int tile0 = blockIdx.x * 5;
    const int wave = tid >> 6, lane = tid & 63;
    const int row = lane & 15, g = lane >> 4;
    const int wbase = wave * 96;

    const ushort* wp = wbT + (size_t)(wbase + row) * 128 + g * 8;
    short8v B[6][4];
#pragma unroll
    for (int t = 0; t < 6; t++)
#pragma unroll
        for (int kk = 0; kk < 4; kk++)
            B[t][kk] = *(const short8v*)&wp[t * 2048 + kk * 32];

    const int sr = tid >> 3, sc = (tid & 7) * 16;
    const int fnode = tid >> 3, fb = (tid & 7) * 8;

    for (int tt = 0; tt < 5; tt++) {
        const int n0 = (tile0 + tt) * 32;
        {
            const ushort* src = &xin[(size_t)(n0 + sr) * 128 + sc];
            *(short8v*)&sx[sr][sc] = *(const short8v*)&src[0];
            *(short8v*)&sx[sr][sc + 8] = *(const short8v*)&src[8];
        }
        __syncthreads();

        short8v a[2][4];
#pragma unroll
        for (int m = 0; m < 2; m++)
#pragma unroll
            for (int kk = 0; kk < 4; kk++)
                a[m][kk] = *(const short8v*)&sx[m * 16 + row][kk * 32 + g * 8];

#pragma unroll
        for (int t = 0; t < 6; t++) {
            f32x4 acc0 = {0.f, 0.f, 0.f, 0.f};
            f32x4 acc1 = {0.f, 0.f, 0.f, 0.f};
#pragma unroll
            for (int kk = 0; kk < 4; kk++) {
                acc0 = __builtin_amdgcn_mfma_f32_16x16x32_bf16(a[0][kk], B[t][kk], acc0, 0, 0, 0);
                acc1 = __builtin_amdgcn_mfma_f32_16x16x32_bf16(a[1][kk], B[t][kk], acc1, 0, 0, 0);
            }
            const int col = wbase + t * 16 + row;
            if (col < 320) {
#pragma unroll
                for (int q = 0; q < 4; q++) {
                    so[g * 4 + q][col] = f2bf(acc0[q]);
                    so[16 + g * 4 + q][col] = f2bf(acc1[q]);
                }
            } else {
                const int f = col - 320;
#pragma unroll
                for (int q = 0; q < 4; q++) {
                    sroot[g * 4 + q][f] = acc0[q];
                    sroot[16 + g * 4 + q][f] = acc1[q];
                }
            }
        }
        __syncthreads();

        {
#pragma unroll
            for (int r = 0; r < NREL; r++) {
                short8v v = *(const short8v*)&so[fnode][r * 64 + fb];
                *(short8v*)&ytab[(size_t)r * NN * ytabW + (size_t)(n0 + fnode) * ytabW
                                 + outOff + fb] = v;
            }
            float4 r0 = *(const float4*)&sroot[fnode][fb];
            float4 r1 = *(const float4*)&sroot[fnode][fb + 4];
            float* hp = &hout[(size_t)(n0 + fnode) * outStride + outOff + fb];
            *(float4*)&hp[0] = r0;
            *(float4*)&hp[4] = r1;
        }
    }
}

// ---------------------------------------------------------------------------
// Aggregation, FW = feats per row (128 for L0, 64 for L1):
// hout[n,:FW] += sum_e scale_e * ytab[row_e]. All per-rep descriptors/records/
// h-rows staged UPFRONT so staging latencies overlap.
template <int FW>
__launch_bounds__(256)
__global__ void agg_kernel(const ushort* __restrict__ ytab,
                           const int2* __restrict__ recs,
                           const int2* __restrict__ desc,
                           float* __restrict__ hout) {
    const int tid = threadIdx.x;
    const int wave = tid >> 6, lane = tid & 63;
    const int half = lane >> 5, fl = lane & 31;
    const int n0 = blockIdx.x * 16 + wave * 4;

    int start[4], total[4];
#pragma unroll
    for (int rep = 0; rep < 4; rep++) {
        const int s5 = (n0 + rep) * NREL;
        int2 d0 = desc[s5];
        int2 d4 = desc[s5 + 4];
        start[rep] = d0.x;
        total[rep] = d4.x + d4.y - d0.x;
    }
    int2 rec[4];
#pragma unroll
    for (int rep = 0; rep < 4; rep++) rec[rep] = recs[start[rep] + lane];

    constexpr int FPL = FW / 32;          // floats per lane (4 or 2)
    float hpre[4][FPL];
#pragma unroll
    for (int rep = 0; rep < 4; rep++) {
        const float* hp = &hout[(size_t)(n0 + rep) * FW + fl * FPL];
#pragma unroll
        for (int q = 0; q < FPL; q++) hpre[rep][q] = hp[q];
    }

#pragma unroll
    for (int rep = 0; rep < 4; rep++) {
        if (total[rep] <= 0) continue;
        float acc[FPL];
#pragma unroll
        for (int q = 0; q < FPL; q++) acc[q] = 0.f;
        const int lim = (total[rep] > 64) ? 64 : total[rep];
#pragma unroll 2
        for (int j2 = half; j2 < lim; j2 += 2) {
            int rw = __shfl(rec[rep].x, j2);
            float sc = __builtin_bit_cast(float, __shfl(rec[rep].y, j2));
            if (FW == 128) {
                uint2 raw = *(const uint2*)&ytab[(size_t)rw * FW + fl * 4];
                acc[0] += sc * bflo(raw.x);
                acc[1] += sc * bfhi(raw.x);
                acc[2] += sc * bflo(raw.y);
                acc[3] += sc * bfhi(raw.y);
            } else {
                uint raw = *(const uint*)&ytab[(size_t)rw * FW + fl * 2];
                acc[0] += sc * bflo(raw);
                acc[1] += sc * bfhi(raw);
            }
        }
        if (total[rep] > 64) {            // rare fallback
            for (int j = 64 + half; j < total[rep]; j += 2) {
                int2 r2 = recs[start[rep] + j];
                float sc = __builtin_bit_cast(float, r2.y);
                if (FW == 128) {
                    uint2 raw = *(const uint2*)&ytab[(size_t)r2.x * FW + fl * 4];
                    acc[0] += sc * bflo(raw.x);
                    acc[1] += sc * bfhi(raw.x);
                    acc[2] += sc * bflo(raw.y);
                    acc[3] += sc * bfhi(raw.y);
                } else {
                    uint raw = *(const uint*)&ytab[(size_t)r2.x * FW + fl * 2];
                    acc[0] += sc * bflo(raw);
                    acc[1] += sc * bfhi(raw);
                }
            }
        }
#pragma unroll
        for (int q = 0; q < FPL; q++) acc[q] += __shfl_xor(acc[q], 32);
        if (half == 0) {
            float* hp = &hout[(size_t)(n0 + rep) * FW + fl * FPL];
            float o[FPL];
#pragma unroll
            for (int q = 0; q < FPL; q++) o[q] = hpre[rep][q] + acc[q];
            if (FW == 128) *(float4*)hp = *(float4*)o;
            else           *(float2*)hp = *(float2*)o;
        }
    }
}

// ---------------------------------------------------------------------------
template <int F, bool RELU>
__global__ void stats_kernel(const float* __restrict__ x, float* __restrict__ colsum,
                             float* __restrict__ sumsq) {
    constexpr int NSUB = 256 / F;
    const int f = threadIdx.x & (F - 1);
    const int sub = threadIdx.x / F;
    float cs = 0.f, ss = 0.f;
    const int stride = gridDim.x * NSUB;
    for (int n = blockIdx.x * NSUB + sub; n < NN; n += stride) {
        float v = x[(size_t)n * F + f];
        if (RELU) v = fmaxf(v, 0.f);
        cs += v;
        ss += v * v;
    }
    __shared__ float sred[256];
    sred[threadIdx.x] = cs;
    __syncthreads();
    if (sub == 0) {
        float t = cs;
#pragma unroll
        for (int s2 = 1; s2 < NSUB; s2++) t += sred[s2 * F + f];
        atomicAdd(&colsum[f], t);
    }
    __syncthreads();
    sred[threadIdx.x] = ss;
    __syncthreads();
    for (int h = 128; h > 0; h >>= 1) {
        if (threadIdx.x < h) sred[threadIdx.x] += sred[threadIdx.x + h];
        __syncthreads();
    }
    if (threadIdx.x == 0) atomicAdd(sumsq, sred[0]);
}

template <int F>
__global__ void finalize_kernel(const float* __restrict__ colsum,
                                const float* __restrict__ sumsq,
                                float* __restrict__ mu_inv) {
    __shared__ float sred[128];
    const int f = threadIdx.x;
    float mu = colsum[f] / (float)NN;
    mu_inv[f] = mu;
    sred[f] = mu * mu;
    __syncthreads();
    for (int h = F / 2; h > 0; h >>= 1) {
        if (f < h) sred[f] += sred[f + h];
        __syncthreads();
    }
    if (f == 0) {
        float var = sumsq[0] / (float)NN - sred[0];
        mu_inv[F] = rsqrtf(1e-5f + var);
    }
}

// layer-0 normalize (in-place) + bf16 copy; ReLU on read; float4-vectorized
__global__ void normalize_dual(const float* __restrict__ x,
                               const float* __restrict__ mu_inv,
                               float* __restrict__ outf, ushort* __restrict__ outb,
                               int total4) {
    int i = blockIdx.x * blockDim.x + threadIdx.x;
    if (i < total4) {
        int base = i * 4;
        int f = base & 127;
        float4 v = *(const float4*)&x[base];
        float4 m = *(const float4*)&mu_inv[f];
        float s = mu_inv[128];
        float4 o = {(fmaxf(v.x, 0.f) - m.x) * s, (fmaxf(v.y, 0.f) - m.y) * s,
                    (fmaxf(v.z, 0.f) - m.z) * s, (fmaxf(v.w, 0.f) - m.w) * s};
        *(float4*)&outf[base] = o;
        ushort4 h = {f2bf(o.x), f2bf(o.y), f2bf(o.z), f2bf(o.w)};
        *(ushort4*)&outb[base] = h;
    }
}

template <int F>
__global__ void normalize_kernel(const float* __restrict__ x,
                                 const float* __restrict__ mu_inv,
                                 float* __restrict__ out, int total4) {
    int i = blockIdx.x * blockDim.x + threadIdx.x;
    if (i < total4) {
        int base = i * 4;
        int f = base & (F - 1);
        float4 v = *(const float4*)&x[base];
        float4 m = *(const float4*)&mu_inv[f];
        float s = mu_inv[F];
        float4 o = {(v.x - m.x) * s, (v.y - m.y) * s, (v.z - m.z) * s, (v.w - m.w) * s};
        *(float4*)&out[base] = o;
    }
}

// ---------------------------------------------------------------------------
extern "C" void kernel_launch(void* const* d_in, const int* in_sizes, int n_in,
                              void* d_out, int out_size, void* d_ws, size_t ws_size,
                              hipStream_t stream) {
    const float* xa    = (const float*)d_in[0];
    const float* xp    = (const float*)d_in[1];
    const int*   ei    = (const int*)d_in[2];
    const int*   et    = (const int*)d_in[3];
    const float* paw   = (const float*)d_in[4];
    const float* pab   = (const float*)d_in[5];
    const float* ppw   = (const float*)d_in[6];
    const float* ppb   = (const float*)d_in[7];
    const float* comp0 = (const float*)d_in[8];
    const float* basis0= (const float*)d_in[9];
    const float* root0 = (const float*)d_in[10];
    const float* comp1 = (const float*)d_in[11];
    const float* basis1= (const float*)d_in[12];
    const float* root1 = (const float*)d_in[13];
    float* out = (float*)d_out;

    char* ws = (char*)d_ws;
    size_t o = 0;
    auto alloc = [&](size_t b) { size_t p = o; o += (b + 255) & ~(size_t)255; return p; };
    ushort* x0b   = (ushort*)(ws + alloc((size_t)NN * HID * 2));        // 25.6 MB
    ushort* xlatb = (ushort*)(ws + alloc((size_t)NN * HID * 2));        // 25.6 MB
    ushort* ytab  = (ushort*)(ws + alloc((size_t)NREL * NN * 128 * 2)); // 128 MB
    int2*   desc  = (int2*)(ws + alloc((size_t)NSEG * 8));              // 4 MB
    int2*   recs  = (int2*)(ws + alloc((size_t)(NE + 64) * 8));         // 8 MB
    ushort* wbT0a = (ushort*)(ws + alloc(384 * 128 * 2));
    ushort* wbT0b = (ushort*)(ws + alloc(384 * 128 * 2));
    ushort* wbT1  = (ushort*)(ws + alloc(384 * 128 * 2));
    ushort* wpa   = (ushort*)(ws + alloc(128 * 256 * 2));
    ushort* wpp   = (ushort*)(ws + alloc(128 * 256 * 2));
    float*  pnscr = (float*)(ws + alloc(512 * 4));
    float*  mu0   = (float*)(ws + alloc(129 * 4));
    float*  mu1   = (float*)(ws + alloc(65 * 4));
    float *cs0 = pnscr, *ss0 = pnscr + 128, *cs1 = pnscr + 192, *ss1 = pnscr + 256;

    // index-build scratch ALIASED into ytab region (dead before first ytab write)
    char* ybase = (char*)ytab;
    int* cnt    = (int*)(ybase);
    int* offs   = (int*)(ybase + (size_t)NSEG * 4);
    int* rank   = (int*)(ybase + (size_t)NSEG * 8);
    int* bsums  = (int*)(ybase + (size_t)NSEG * 8 + (size_t)NE * 4);
    int* bsums2 = (int*)(ybase + (size_t)NSEG * 8 + (size_t)NE * 4 + 4096);

    float* h0 = out + (size_t)NN * OUTF;   // [NN][128] f32 (x_latent slice)
    float* h1 = out;                       // [NN][64]  f32
    float* xlat = h0;

    // fused prep (zeros + all weight builds), then projection
    prep_kernel<<<2789, 256, 0, stream>>>(comp0, basis0, root0, comp1, basis1, root1,
                                          paw, ppw, wbT0a, wbT0b, wbT1, wpa, wpp,
                                          cnt, pnscr, (int*)(recs + NE));
    proj_mfma<<<1250, 256, 0, stream>>>(xa, xp, wpa, wpp, pab, ppb, x0b);

    // segment index (shared by both layers)
    hist_kernel<<<(NE + 255) / 256, 256, 0, stream>>>(ei, et, cnt, rank);
    const int nb = (NSEG + 2047) / 2048;
    scan1<<<nb, 256, 0, stream>>>(cnt, offs, bsums, NSEG);
    scan2<<<1, 256, 0, stream>>>(bsums, bsums2, nb);
    scan3_desc<<<(NSEG + 255) / 256, 256, 0, stream>>>(offs, bsums2, cnt, desc, NSEG);
    scatter_kernel<<<(NE + 255) / 256, 256, 0, stream>>>(ei, et, rank, desc, recs);

    // layer 0: two GEMM passes fill the 128-wide ytab; ONE merged agg pass
    ytab_gemm<<<625, 256, 0, stream>>>(x0b, wbT0a, ytab, h0, 128, HID, 0);
    ytab_gemm<<<625, 256, 0, stream>>>(x0b, wbT0b, ytab, h0, 128, HID, 64);
    agg_kernel<128><<<NN / 16, 256, 0, stream>>>(ytab, recs, desc, h0);
    stats_kernel<HID, true><<<512, 256, 0, stream>>>(h0, cs0, ss0);
    finalize_kernel<HID><<<1, HID, 0, stream>>>(cs0, ss0, mu0);
    normalize_dual<<<(NN * HID / 4 + 255) / 256, 256, 0, stream>>>(h0, mu0, xlat, xlatb,
                                                                   NN * HID / 4);

    // layer 1 (single pass, 64-wide ytab rows)
    ytab_gemm<<<625, 256, 0, stream>>>(xlatb, wbT1, ytab, h1, 64, OUTF, 0);
    agg_kernel<64><<<NN / 16, 256, 0, stream>>>(ytab, recs, desc, h1);
    stats_kernel<OUTF, false><<<512, 256, 0, stream>>>(h1, cs1, ss1);
    finalize_kernel<OUTF><<<1, OUTF, 0, stream>>>(cs1, ss1, mu1);
    normalize_kernel<OUTF><<<(NN * OUTF / 4 + 255) / 256, 256, 0, stream>>>(h1, mu1, out,
                                                                            NN * OUTF / 4);
}

// Round 10
// 364.310 us; speedup vs baseline: 4.2166x; 1.1671x over previous
//
#include <hip/hip_runtime.h>
#include <hip/hip_bf16.h>

constexpr int NPT    = 50000;
constexpr int NN     = 100000;
constexpr int NE     = 1000000;
constexpr int HID    = 128;
constexpr int OUTF   = 64;
constexpr int INF    = 256;
constexpr int NREL   = 5;
constexpr int NSEG   = NN * NREL;

typedef __attribute__((ext_vector_type(8))) short short8v;
typedef __attribute__((ext_vector_type(4))) float f32x4;

__device__ __forceinline__ ushort f2bf(float x) {
    uint u = __builtin_bit_cast(uint, x);
    uint r = (u + 0x7FFFu + ((u >> 16) & 1u)) >> 16;
    return (ushort)r;
}
__device__ __forceinline__ float bfhi(uint raw) {
    return __builtin_bit_cast(float, raw & 0xFFFF0000u);
}
__device__ __forceinline__ float bflo(uint raw) {
    return __builtin_bit_cast(float, raw << 16);
}

// ---------------------------------------------------------------------------
// fused prep: zero cnt/statscr/recs-pad + build all weight stacks in ONE launch
__device__ __forceinline__ void build_wbT_body(const float* __restrict__ comp,
                                               const float* __restrict__ basis,
                                               const float* __restrict__ root,
                                               ushort* __restrict__ wbT,
                                               int fout, int passOff, int idx) {
    int col = idx >> 7, k = idx & 127;
    float v;
    if (col < 320) {
        int r = col >> 6, f = (col & 63) + passOff;
        v = 0.f;
#pragma unroll
        for (int b = 0; b < 8; b++)
            v += comp[r * 8 + b] * basis[(b * 128 + k) * fout + f];
    } else {
        v = root[k * fout + (col - 320) + passOff];
    }
    wbT[col * 128 + k] = f2bf(v);
}

__global__ void prep_kernel(const float* __restrict__ comp0, const float* __restrict__ basis0,
                            const float* __restrict__ root0,
                            const float* __restrict__ comp1, const float* __restrict__ basis1,
                            const float* __restrict__ root1,
                            const float* __restrict__ paw, const float* __restrict__ ppw,
                            ushort* __restrict__ wbT0a, ushort* __restrict__ wbT0b,
                            ushort* __restrict__ wbT1,
                            ushort* __restrict__ wpa, ushort* __restrict__ wpp,
                            int* __restrict__ cnt, float* __restrict__ statscr,
                            int* __restrict__ recs_pad) {
    const int b = blockIdx.x, t = threadIdx.x;
    if (b < 1954) {                       // zero cnt[NSEG]
        int i = b * 256 + t;
        if (i < NSEG) cnt[i] = 0;
    } else if (b < 1979) {                // zero statscr[6400]
        statscr[(b - 1954) * 256 + t] = 0.f;
    } else if (b == 1979) {               // zero recs pad (64 int2)
        if (t < 128) recs_pad[t] = 0;
    } else if (b < 2172) {
        build_wbT_body(comp0, basis0, root0, wbT0a, HID, 0, (b - 1980) * 256 + t);
    } else if (b < 2364) {
        build_wbT_body(comp0, basis0, root0, wbT0b, HID, 64, (b - 2172) * 256 + t);
    } else if (b < 2556) {
        build_wbT_body(comp1, basis1, root1, wbT1, OUTF, 0, (b - 2364) * 256 + t);
    } else if (b < 2684) {                // wpa: w[256][128] -> wT[128][256]
        int i = (b - 2556) * 256 + t;
        wpa[(size_t)(i & 127) * 256 + (i >> 7)] = f2bf(paw[i]);
    } else {
        int i = (b - 2684) * 256 + t;
        wpp[(size_t)(i & 127) * 256 + (i >> 7)] = f2bf(ppw[i]);
    }
}

// ---------------------------------------------------------------------------
// proj (blocks 0..1249, B-stationary 5-tile loop) FUSED with hist
// (blocks 1250..5156) — independent work overlaps on the device.
__launch_bounds__(256)
__global__ void proj_hist(const float* __restrict__ xa, const float* __restrict__ xp,
                          const ushort* __restrict__ wTa, const ushort* __restrict__ wTp,
                          const float* __restrict__ ba, const float* __restrict__ bp,
                          ushort* __restrict__ x0b,
                          const int* __restrict__ ei, const int* __restrict__ et,
                          int* __restrict__ cnt, int* __restrict__ rank) {
    __shared__ ushort sx[16][264];
    __shared__ ushort so[16][132];
    const int tid = threadIdx.x;
    if (blockIdx.x >= 1250) {             // ---- hist part ----
        int e = (blockIdx.x - 1250) * 256 + tid;
        if (e < NE) {
            int seg = ei[NE + e] * NREL + et[e];
            rank[e] = atomicAdd(&cnt[seg], 1);
        }
        return;
    }
    // ---- proj part ----
    const bool author = blockIdx.x < 625;
    const int tile0 = (blockIdx.x - (author ? 0 : 625)) * 5;
    const float* x = author ? xa : xp;
    const ushort* wT = author ? wTa : wTp;
    const float* bias = author ? ba : bp;
    const int typeBase = author ? 0 : NPT;

    const int wave = tid >> 6, lane = tid & 63;
    const int row = lane & 15, g = lane >> 4;
    const int fcol = wave * 32 + row;

    const ushort* wp0 = wT + (size_t)fcol * 256 + g * 8;
    short8v bA[8], bB[8];
#pragma unroll
    for (int kk = 0; kk < 8; kk++) bA[kk] = *(const short8v*)&wp0[kk * 32];
#pragma unroll
    for (int kk = 0; kk < 8; kk++) bB[kk] = *(const short8v*)&wp0[16 * 256 + kk * 32];
    const float bv0 = bias[fcol], bv1 = bias[fcol + 16];

    const int sr = tid >> 4, part = tid & 15;
    const int fnode = tid >> 4, fb = (tid & 15) * 8;

    for (int t = 0; t < 5; t++) {
        const int nloc = (tile0 + t) * 16;
        {
            size_t rowoff = (size_t)(nloc + sr) * INF + part * 16;
#pragma unroll
            for (int ii = 0; ii < 4; ii++) {
                float4 v = *(const float4*)&x[rowoff + ii * 4];
                ushort4 h = {f2bf(v.x), f2bf(v.y), f2bf(v.z), f2bf(v.w)};
                *(ushort4*)&sx[sr][part * 16 + ii * 4] = h;
            }
        }
        __syncthreads();
        short8v a[8];
#pragma unroll
        for (int kk = 0; kk < 8; kk++) a[kk] = *(const short8v*)&sx[row][kk * 32 + g * 8];
        {
            f32x4 acc0 = {0.f, 0.f, 0.f, 0.f};
            f32x4 acc1 = {0.f, 0.f, 0.f, 0.f};
#pragma unroll
            for (int kk = 0; kk < 8; kk++) {
                acc0 = __builtin_amdgcn_mfma_f32_16x16x32_bf16(a[kk], bA[kk], acc0, 0, 0, 0);
                acc1 = __builtin_amdgcn_mfma_f32_16x16x32_bf16(a[kk], bB[kk], acc1, 0, 0, 0);
            }
#pragma unroll
            for (int q = 0; q < 4; q++) {
                so[g * 4 + q][fcol]      = f2bf(fmaxf(acc0[q] + bv0, 0.f));
                so[g * 4 + q][fcol + 16] = f2bf(fmaxf(acc1[q] + bv1, 0.f));
            }
        }
        __syncthreads();
        {
            ushort4 v0 = *(const ushort4*)&so[fnode][fb];
            ushort4 v1 = *(const ushort4*)&so[fnode][fb + 4];
            size_t gbase = (size_t)(typeBase + nloc + fnode) * 128 + fb;
            *(ushort4*)&x0b[gbase] = v0;
            *(ushort4*)&x0b[gbase + 4] = v1;
        }
    }
}

// ---------------------------------------------------------------------------
__global__ void scan1(const int* __restrict__ cnt, int* __restrict__ offs,
                      int* __restrict__ bsums, int n) {
    __shared__ int lds[256];
    const int t = threadIdx.x;
    const int base = blockIdx.x * 2048 + t * 8;
    int vals[8];
    int s = 0;
#pragma unroll
    for (int v = 0; v < 8; v++) {
        int idx = base + v;
        vals[v] = (idx < n) ? cnt[idx] : 0;
        s += vals[v];
    }
    lds[t] = s;
    __syncthreads();
    for (int off = 1; off < 256; off <<= 1) {
        int x = lds[t];
        int y = (t >= off) ? lds[t - off] : 0;
        __syncthreads();
        lds[t] = x + y;
        __syncthreads();
    }
    int run = (t > 0) ? lds[t - 1] : 0;
    if (t == 255) bsums[blockIdx.x] = lds[255];
#pragma unroll
    for (int v = 0; v < 8; v++) {
        int idx = base + v;
        if (idx < n) offs[idx] = run;
        run += vals[v];
    }
}

__global__ void scan2(const int* __restrict__ bsums, int* __restrict__ bsums2, int nb) {
    __shared__ int lds[256];
    const int t = threadIdx.x;
    lds[t] = (t < nb) ? bsums[t] : 0;
    __syncthreads();
    for (int off = 1; off < 256; off <<= 1) {
        int x = lds[t];
        int y = (t >= off) ? lds[t - off] : 0;
        __syncthreads();
        lds[t] = x + y;
        __syncthreads();
    }
    if (t < nb) bsums2[t] = (t > 0) ? lds[t - 1] : 0;
}

__global__ void scan3_desc(const int* __restrict__ offs, const int* __restrict__ bsums2,
                           const int* __restrict__ cnt, int2* __restrict__ desc, int n) {
    int i = blockIdx.x * blockDim.x + threadIdx.x;
    if (i < n) {
        int2 d = {offs[i] + bsums2[i >> 11], cnt[i]};
        desc[i] = d;
    }
}

__global__ void scatter_kernel(const int* __restrict__ ei, const int* __restrict__ et,
                               const int* __restrict__ rank,
                               const int2* __restrict__ desc, int2* __restrict__ recs) {
    int e = blockIdx.x * blockDim.x + threadIdx.x;
    if (e < NE) {
        int src = ei[e];
        int dst = ei[NE + e];
        int r = et[e];
        int2 d = desc[dst * NREL + r];
        int c = d.y;
        float sc = 1.f / (float)((c > 1) ? c : 1);
        int2 rec = {r * NN + src, __builtin_bit_cast(int, sc)};
        recs[d.x + rank[e]] = rec;
    }
}

// ---------------------------------------------------------------------------
// L0 dense GEMM, both 64-col halves in ONE launch (1250 blocks): blocks
// 0..624 use wbT_a -> cols 0..63, 625..1249 use wbT_b -> cols 64..127.
__launch_bounds__(256)
__global__ void ytab_gemm0(const ushort* __restrict__ xin,
                           const ushort* __restrict__ wbT_a, const ushort* __restrict__ wbT_b,
                           ushort* __restrict__ ytab, float* __restrict__ hout) {
    __shared__ ushort sx[32][136];
    __shared__ ushort so[32][328];
    __shared__ float sroot[32][68];
    const int tid = threadIdx.x;
    const bool first = blockIdx.x < 625;
    const int tile0 = (first ? blockIdx.x : blockIdx.x - 625) * 5;
    const ushort* wbT = first ? wbT_a : wbT_b;
    const int outOff = first ? 0 : 64;
    const int wave = tid >> 6, lane = tid & 63;
    const int row = lane & 15, g = lane >> 4;
    const int wbase = wave * 96;

    const ushort* wp = wbT + (size_t)(wbase + row) * 128 + g * 8;
    short8v B[6][4];
#pragma unroll
    for (int t = 0; t < 6; t++)
#pragma unroll
        for (int kk = 0; kk < 4; kk++)
            B[t][kk] = *(const short8v*)&wp[t * 2048 + kk * 32];

    const int sr = tid >> 3, scl = (tid & 7) * 16;
    const int fnode = tid >> 3, fb = (tid & 7) * 8;

    for (int tt = 0; tt < 5; tt++) {
        const int n0 = (tile0 + tt) * 32;
        {
            const ushort* src = &xin[(size_t)(n0 + sr) * 128 + scl];
            *(short8v*)&sx[sr][scl] = *(const short8v*)&src[0];
            *(short8v*)&sx[sr][scl + 8] = *(const short8v*)&src[8];
        }
        __syncthreads();

        short8v a[2][4];
#pragma unroll
        for (int m = 0; m < 2; m++)
#pragma unroll
            for (int kk = 0; kk < 4; kk++)
                a[m][kk] = *(const short8v*)&sx[m * 16 + row][kk * 32 + g * 8];

#pragma unroll
        for (int t = 0; t < 6; t++) {
            f32x4 acc0 = {0.f, 0.f, 0.f, 0.f};
            f32x4 acc1 = {0.f, 0.f, 0.f, 0.f};
#pragma unroll
            for (int kk = 0; kk < 4; kk++) {
                acc0 = __builtin_amdgcn_mfma_f32_16x16x32_bf16(a[0][kk], B[t][kk], acc0, 0, 0, 0);
                acc1 = __builtin_amdgcn_mfma_f32_16x16x32_bf16(a[1][kk], B[t][kk], acc1, 0, 0, 0);
            }
            const int col = wbase + t * 16 + row;
            if (col < 320) {
#pragma unroll
                for (int q = 0; q < 4; q++) {
                    so[g * 4 + q][col] = f2bf(acc0[q]);
                    so[16 + g * 4 + q][col] = f2bf(acc1[q]);
                }
            } else {
                const int f = col - 320;
#pragma unroll
                for (int q = 0; q < 4; q++) {
                    sroot[g * 4 + q][f] = acc0[q];
                    sroot[16 + g * 4 + q][f] = acc1[q];
                }
            }
        }
        __syncthreads();

        {
#pragma unroll
            for (int r = 0; r < NREL; r++) {
                short8v v = *(const short8v*)&so[fnode][r * 64 + fb];
                *(short8v*)&ytab[(size_t)r * NN * 128 + (size_t)(n0 + fnode) * 128
                                 + outOff + fb] = v;
            }
            float4 r0 = *(const float4*)&sroot[fnode][fb];
            float4 r1 = *(const float4*)&sroot[fnode][fb + 4];
            float* hp = &hout[(size_t)(n0 + fnode) * HID + outOff + fb];
            *(float4*)&hp[0] = r0;
            *(float4*)&hp[4] = r1;
        }
    }
}

// ---------------------------------------------------------------------------
// L1 dense GEMM with FUSED PairNorm-0 on input: reads h0 (relu'd, raw scale),
// normalizes with mu0, writes normalized f32 back in place (= x_latent output)
// and bf16 into the LDS A-tile. 625 blocks x 5 tiles of 32 nodes.
__launch_bounds__(256)
__global__ void ytab_gemm1(float* __restrict__ h0x, const float* __restrict__ mu,
                           const ushort* __restrict__ wbT,
                           ushort* __restrict__ ytab, float* __restrict__ h1) {
    __shared__ ushort sx[32][136];
    __shared__ ushort so[32][328];
    __shared__ float sroot[32][68];
    const int tid = threadIdx.x;
    const int tile0 = blockIdx.x * 5;
    const int wave = tid >> 6, lane = tid & 63;
    const int row = lane & 15, g = lane >> 4;
    const int wbase = wave * 96;

    const ushort* wp = wbT + (size_t)(wbase + row) * 128 + g * 8;
    short8v B[6][4];
#pragma unroll
    for (int t = 0; t < 6; t++)
#pragma unroll
        for (int kk = 0; kk < 4; kk++)
            B[t][kk] = *(const short8v*)&wp[t * 2048 + kk * 32];

    const int sr = tid >> 3, scl = (tid & 7) * 16;
    const int fnode = tid >> 3, fb = (tid & 7) * 8;

    float m[16];
#pragma unroll
    for (int i = 0; i < 16; i++) m[i] = mu[scl + i];
    const float s = mu[128];

    for (int tt = 0; tt < 5; tt++) {
        const int n0 = (tile0 + tt) * 32;
        {   // stage + normalize + write-back (in place)
            float* hp = &h0x[(size_t)(n0 + sr) * 128 + scl];
            float v[16];
#pragma unroll
            for (int i = 0; i < 4; i++) {
                float4 t4 = *(const float4*)&hp[i * 4];
                v[i * 4 + 0] = (t4.x - m[i * 4 + 0]) * s;
                v[i * 4 + 1] = (t4.y - m[i * 4 + 1]) * s;
                v[i * 4 + 2] = (t4.z - m[i * 4 + 2]) * s;
                v[i * 4 + 3] = (t4.w - m[i * 4 + 3]) * s;
            }
            ushort hb[16];
#pragma unroll
            for (int i = 0; i < 16; i++) hb[i] = f2bf(v[i]);
#pragma unroll
            for (int i = 0; i < 4; i++) {
                float4 t4 = {v[i * 4], v[i * 4 + 1], v[i * 4 + 2], v[i * 4 + 3]};
                *(float4*)&hp[i * 4] = t4;
            }
            *(short8v*)&sx[sr][scl] = *(const short8v*)&hb[0];
            *(short8v*)&sx[sr][scl + 8] = *(const short8v*)&hb[8];
        }
        __syncthreads();

        short8v a[2][4];
#pragma unroll
        for (int mi = 0; mi < 2; mi++)
#pragma unroll
            for (int kk = 0; kk < 4; kk++)
                a[mi][kk] = *(const short8v*)&sx[mi * 16 + row][kk * 32 + g * 8];

#pragma unroll
        for (int t = 0; t < 6; t++) {
            f32x4 acc0 = {0.f, 0.f, 0.f, 0.f};
            f32x4 acc1 = {0.f, 0.f, 0.f, 0.f};
#pragma unroll
            for (int kk = 0; kk < 4; kk++) {
                acc0 = __builtin_amdgcn_mfma_f32_16x16x32_bf16(a[0][kk], B[t][kk], acc0, 0, 0, 0);
                acc1 = __builtin_amdgcn_mfma_f32_16x16x32_bf16(a[1][kk], B[t][kk], acc1, 0, 0, 0);
            }
            const int col = wbase + t * 16 + row;
            if (col < 320) {
#pragma unroll
                for (int q = 0; q < 4; q++) {
                    so[g * 4 + q][col] = f2bf(acc0[q]);
                    so[16 + g * 4 + q][col] = f2bf(acc1[q]);
                }
            } else {
                const int f = col - 320;
#pragma unroll
                for (int q = 0; q < 4; q++) {
                    sroot[g * 4 + q][f] = acc0[q];
                    sroot[16 + g * 4 + q][f] = acc1[q];
                }
            }
        }
        __syncthreads();

        {
#pragma unroll
            for (int r = 0; r < NREL; r++) {
                short8v v = *(const short8v*)&so[fnode][r * 64 + fb];
                *(short8v*)&ytab[(size_t)r * NN * 64 + (size_t)(n0 + fnode) * 64 + fb] = v;
            }
            float4 r0 = *(const float4*)&sroot[fnode][fb];
            float4 r1 = *(const float4*)&sroot[fnode][fb + 4];
            float* hp = &h1[(size_t)(n0 + fnode) * OUTF + fb];
            *(float4*)&hp[0] = r0;
            *(float4*)&hp[4] = r1;
        }
    }
}

// ---------------------------------------------------------------------------
// Aggregation + FUSED PairNorm stats. FW feats/row. Writes final h (relu'd if
// RELU) and accumulates colsum/sumsq into 32 replicated accumulators.
template <int FW, bool RELU>
__launch_bounds__(256)
__global__ void agg_kernel(const ushort* __restrict__ ytab,
                           const int2* __restrict__ recs,
                           const int2* __restrict__ desc,
                           float* __restrict__ hout,
                           float* __restrict__ csrep, float* __restrict__ ssrep) {
    constexpr int FPL = FW / 32;          // floats per lane (4 or 2)
    __shared__ float sred[4][32][FPL + 1];
    const int tid = threadIdx.x;
    const int wave = tid >> 6, lane = tid & 63;
    const int half = lane >> 5, fl = lane & 31;
    const int n0 = blockIdx.x * 16 + wave * 4;

    int start[4], total[4];
#pragma unroll
    for (int rep = 0; rep < 4; rep++) {
        const int s5 = (n0 + rep) * NREL;
        int2 d0 = desc[s5];
        int2 d4 = desc[s5 + 4];
        start[rep] = d0.x;
        total[rep] = d4.x + d4.y - d0.x;
    }
    int2 rec[4];
#pragma unroll
    for (int rep = 0; rep < 4; rep++) {
        rec[rep].x = 0; rec[rep].y = 0;
        if (lane < total[rep]) rec[rep] = recs[start[rep] + lane];
    }

    float hpre[4][FPL];
#pragma unroll
    for (int rep = 0; rep < 4; rep++) {
        const float* hp = &hout[(size_t)(n0 + rep) * FW + fl * FPL];
#pragma unroll
        for (int q = 0; q < FPL; q++) hpre[rep][q] = hp[q];
    }

    float cs_loc[FPL];
#pragma unroll
    for (int q = 0; q < FPL; q++) cs_loc[q] = 0.f;
    float ss_loc = 0.f;

#pragma unroll
    for (int rep = 0; rep < 4; rep++) {
        float acc[FPL];
#pragma unroll
        for (int q = 0; q < FPL; q++) acc[q] = 0.f;
        const int lim = (total[rep] > 64) ? 64 : total[rep];
#pragma unroll 2
        for (int j2 = half; j2 < lim; j2 += 2) {
            int rw = __shfl(rec[rep].x, j2);
            float sc = __builtin_bit_cast(float, __shfl(rec[rep].y, j2));
            if (FW == 128) {
                uint2 raw = *(const uint2*)&ytab[(size_t)rw * FW + fl * 4];
                acc[0] += sc * bflo(raw.x);
                acc[1] += sc * bfhi(raw.x);
                acc[2] += sc * bflo(raw.y);
                acc[3] += sc * bfhi(raw.y);
            } else {
                uint raw = *(const uint*)&ytab[(size_t)rw * FW + fl * 2];
                acc[0] += sc * bflo(raw);
                acc[1] += sc * bfhi(raw);
            }
        }
        if (total[rep] > 64) {
            for (int j = 64 + half; j < total[rep]; j += 2) {
                int2 r2 = recs[start[rep] + j];
                float sc = __builtin_bit_cast(float, r2.y);
                if (FW == 128) {
                    uint2 raw = *(const uint2*)&ytab[(size_t)r2.x * FW + fl * 4];
                    acc[0] += sc * bflo(raw.x);
                    acc[1] += sc * bfhi(raw.x);
                    acc[2] += sc * bflo(raw.y);
                    acc[3] += sc * bfhi(raw.y);
                } else {
                    uint raw = *(const uint*)&ytab[(size_t)r2.x * FW + fl * 2];
                    acc[0] += sc * bflo(raw);
                    acc[1] += sc * bfhi(raw);
                }
            }
        }
#pragma unroll
        for (int q = 0; q < FPL; q++) acc[q] += __shfl_xor(acc[q], 32);
        if (half == 0) {
            float o[FPL];
#pragma unroll
            for (int q = 0; q < FPL; q++) {
                o[q] = hpre[rep][q] + acc[q];
                if (RELU) o[q] = fmaxf(o[q], 0.f);
                cs_loc[q] += o[q];
                ss_loc += o[q] * o[q];
            }
            float* hp = &hout[(size_t)(n0 + rep) * FW + fl * FPL];
            if (FW == 128) *(float4*)hp = *(float4*)o;
            else           *(float2*)hp = *(float2*)o;
        }
    }

    // block-level stats reduce -> replicated global accumulators
    if (half == 0) {
#pragma unroll
        for (int q = 0; q < FPL; q++) sred[wave][fl][q] = cs_loc[q];
        sred[wave][fl][FPL] = ss_loc;
    }
    __syncthreads();
    if (tid < 32) {                        // wave 0, lanes 0..31
        float sq[FPL + 1];
#pragma unroll
        for (int q = 0; q <= FPL; q++)
            sq[q] = sred[0][tid][q] + sred[1][tid][q] + sred[2][tid][q] + sred[3][tid][q];
        const int repl = blockIdx.x & 31;
#pragma unroll
        for (int q = 0; q < FPL; q++)
            atomicAdd(&csrep[repl * FW + tid * FPL + q], sq[q]);
        float ssv = sq[FPL];
#pragma unroll
        for (int mof = 16; mof > 0; mof >>= 1) ssv += __shfl_xor(ssv, mof);
        if (tid == 0) atomicAdd(&ssrep[repl], ssv);
    }
}

// ---------------------------------------------------------------------------
template <int F>
__global__ void finalize_rep(const float* __restrict__ csrep,
                             const float* __restrict__ ssrep,
                             float* __restrict__ mu_inv) {
    __shared__ float sred[128];
    const int f = threadIdx.x;            // F threads
    float s = 0.f;
    for (int r = 0; r < 32; r++) s += csrep[r * F + f];
    float mu = s / (float)NN;
    mu_inv[f] = mu;
    sred[f] = mu * mu;
    __syncthreads();
    for (int h = F / 2; h > 0; h >>= 1) {
        if (f < h) sred[f] += sred[f + h];
        __syncthreads();
    }
    if (f == 0) {
        float ss = 0.f;
        for (int r = 0; r < 32; r++) ss += ssrep[r];
        float var = ss / (float)NN - sred[0];
        mu_inv[F] = rsqrtf(1e-5f + var);
    }
}

// final L1 normalize (in-place on d_out), float4-vectorized
template <int F>
__global__ void normalize_kernel(const float* __restrict__ x,
                                 const float* __restrict__ mu_inv,
                                 float* __restrict__ out, int total4) {
    int i = blockIdx.x * blockDim.x + threadIdx.x;
    if (i < total4) {
        int base = i * 4;
        int f = base & (F - 1);
        float4 v = *(const float4*)&x[base];
        float4 m = *(const float4*)&mu_inv[f];
        float s = mu_inv[F];
        float4 o = {(v.x - m.x) * s, (v.y - m.y) * s, (v.z - m.z) * s, (v.w - m.w) * s};
        *(float4*)&out[base] = o;
    }
}

// ---------------------------------------------------------------------------
extern "C" void kernel_launch(void* const* d_in, const int* in_sizes, int n_in,
                              void* d_out, int out_size, void* d_ws, size_t ws_size,
                              hipStream_t stream) {
    const float* xa    = (const float*)d_in[0];
    const float* xp    = (const float*)d_in[1];
    const int*   ei    = (const int*)d_in[2];
    const int*   et    = (const int*)d_in[3];
    const float* paw   = (const float*)d_in[4];
    const float* pab   = (const float*)d_in[5];
    const float* ppw   = (const float*)d_in[6];
    const float* ppb   = (const float*)d_in[7];
    const float* comp0 = (const float*)d_in[8];
    const float* basis0= (const float*)d_in[9];
    const float* root0 = (const float*)d_in[10];
    const float* comp1 = (const float*)d_in[11];
    const float* basis1= (const float*)d_in[12];
    const float* root1 = (const float*)d_in[13];
    float* out = (float*)d_out;

    char* ws = (char*)d_ws;
    size_t o = 0;
    auto alloc = [&](size_t b) { size_t p = o; o += (b + 255) & ~(size_t)255; return p; };
    ushort* x0b    = (ushort*)(ws + alloc((size_t)NN * HID * 2));        // 25.6 MB
    ushort* ytab   = (ushort*)(ws + alloc((size_t)NREL * NN * 128 * 2)); // 128 MB
    int2*   desc   = (int2*)(ws + alloc((size_t)NSEG * 8));              // 4 MB
    int2*   recs   = (int2*)(ws + alloc((size_t)(NE + 64) * 8));         // 8 MB
    ushort* wbT0a  = (ushort*)(ws + alloc(384 * 128 * 2));
    ushort* wbT0b  = (ushort*)(ws + alloc(384 * 128 * 2));
    ushort* wbT1   = (ushort*)(ws + alloc(384 * 128 * 2));
    ushort* wpa    = (ushort*)(ws + alloc(128 * 256 * 2));
    ushort* wpp    = (ushort*)(ws + alloc(128 * 256 * 2));
    float*  statscr= (float*)(ws + alloc(6400 * 4));
    float*  mu0    = (float*)(ws + alloc(129 * 4));
    float*  mu1    = (float*)(ws + alloc(65 * 4));
    float* cs0rep = statscr;              // 32 x 128
    float* ss0rep = statscr + 4096;       // 32
    float* cs1rep = statscr + 4128;       // 32 x 64
    float* ss1rep = statscr + 6176;       // 32

    // index-build scratch ALIASED into ytab region (dead before first ytab write)
    char* ybase = (char*)ytab;
    int* cnt    = (int*)(ybase);
    int* offs   = (int*)(ybase + (size_t)NSEG * 4);
    int* rank   = (int*)(ybase + (size_t)NSEG * 8);
    int* bsums  = (int*)(ybase + (size_t)NSEG * 8 + (size_t)NE * 4);
    int* bsums2 = (int*)(ybase + (size_t)NSEG * 8 + (size_t)NE * 4 + 4096);

    float* h0 = out + (size_t)NN * OUTF;   // [NN][128] f32 (x_latent slice)
    float* h1 = out;                       // [NN][64]  f32

    // prep (zeros + all weight builds), then proj FUSED with hist
    prep_kernel<<<2812, 256, 0, stream>>>(comp0, basis0, root0, comp1, basis1, root1,
                                          paw, ppw, wbT0a, wbT0b, wbT1, wpa, wpp,
                                          cnt, statscr, (int*)(recs + NE));
    proj_hist<<<1250 + (NE + 255) / 256, 256, 0, stream>>>(xa, xp, wpa, wpp, pab, ppb,
                                                           x0b, ei, et, cnt, rank);

    // segment index (shared by both layers)
    const int nb = (NSEG + 2047) / 2048;
    scan1<<<nb, 256, 0, stream>>>(cnt, offs, bsums, NSEG);
    scan2<<<1, 256, 0, stream>>>(bsums, bsums2, nb);
    scan3_desc<<<(NSEG + 255) / 256, 256, 0, stream>>>(offs, bsums2, cnt, desc, NSEG);
    scatter_kernel<<<(NE + 255) / 256, 256, 0, stream>>>(ei, et, rank, desc, recs);

    // layer 0: merged GEMM (both halves), agg + fused stats, finalize
    ytab_gemm0<<<1250, 256, 0, stream>>>(x0b, wbT0a, wbT0b, ytab, h0);
    agg_kernel<128, true><<<NN / 16, 256, 0, stream>>>(ytab, recs, desc, h0, cs0rep, ss0rep);
    finalize_rep<128><<<1, 128, 0, stream>>>(cs0rep, ss0rep, mu0);

    // layer 1: GEMM with fused PairNorm-0 (writes x_latent in place), agg+stats
    ytab_gemm1<<<625, 256, 0, stream>>>(h0, mu0, wbT1, ytab, h1);
    agg_kernel<64, false><<<NN / 16, 256, 0, stream>>>(ytab, recs, desc, h1, cs1rep, ss1rep);
    finalize_rep<64><<<1, 64, 0, stream>>>(cs1rep, ss1rep, mu1);
    normalize_kernel<OUTF><<<(NN * OUTF / 4 + 255) / 256, 256, 0, stream>>>(h1, mu1, out,
                                                                            NN * OUTF / 4);
}

// Round 12
// 345.473 us; speedup vs baseline: 4.4465x; 1.0545x over previous
//
#include <hip/hip_runtime.h>
#include <hip/hip_bf16.h>

constexpr int NPT    = 50000;
constexpr int NN     = 100000;
constexpr int NE     = 1000000;
constexpr int HID    = 128;
constexpr int OUTF   = 64;
constexpr int INF    = 256;
constexpr int NREL   = 5;
constexpr int NSEG   = NN * NREL;

typedef __attribute__((ext_vector_type(8))) short short8v;
typedef __attribute__((ext_vector_type(4))) float f32x4;

__device__ __forceinline__ ushort f2bf(float x) {
    uint u = __builtin_bit_cast(uint, x);
    uint r = (u + 0x7FFFu + ((u >> 16) & 1u)) >> 16;
    return (ushort)r;
}
__device__ __forceinline__ float bfhi(uint raw) {
    return __builtin_bit_cast(float, raw & 0xFFFF0000u);
}
__device__ __forceinline__ float bflo(uint raw) {
    return __builtin_bit_cast(float, raw << 16);
}

// ---------------------------------------------------------------------------
// fused prep: zero cnt/statscr/recs-pad + build all weight stacks in ONE launch
__device__ __forceinline__ void build_wbT_body(const float* __restrict__ comp,
                                               const float* __restrict__ basis,
                                               const float* __restrict__ root,
                                               ushort* __restrict__ wbT,
                                               int fout, int passOff, int idx) {
    int col = idx >> 7, k = idx & 127;
    float v;
    if (col < 320) {
        int r = col >> 6, f = (col & 63) + passOff;
        v = 0.f;
#pragma unroll
        for (int b = 0; b < 8; b++)
            v += comp[r * 8 + b] * basis[(b * 128 + k) * fout + f];
    } else {
        v = root[k * fout + (col - 320) + passOff];
    }
    wbT[col * 128 + k] = f2bf(v);
}

__global__ void prep_kernel(const float* __restrict__ comp0, const float* __restrict__ basis0,
                            const float* __restrict__ root0,
                            const float* __restrict__ comp1, const float* __restrict__ basis1,
                            const float* __restrict__ root1,
                            const float* __restrict__ paw, const float* __restrict__ ppw,
                            ushort* __restrict__ wbT0a, ushort* __restrict__ wbT0b,
                            ushort* __restrict__ wbT1,
                            ushort* __restrict__ wpa, ushort* __restrict__ wpp,
                            int* __restrict__ cnt, float* __restrict__ statscr,
                            int* __restrict__ recs_pad) {
    const int b = blockIdx.x, t = threadIdx.x;
    if (b < 1954) {                       // zero cnt[NSEG]
        int i = b * 256 + t;
        if (i < NSEG) cnt[i] = 0;
    } else if (b < 1979) {                // zero statscr[6400]
        statscr[(b - 1954) * 256 + t] = 0.f;
    } else if (b == 1979) {               // zero recs pad (64 int2)
        if (t < 128) recs_pad[t] = 0;
    } else if (b < 2172) {
        build_wbT_body(comp0, basis0, root0, wbT0a, HID, 0, (b - 1980) * 256 + t);
    } else if (b < 2364) {
        build_wbT_body(comp0, basis0, root0, wbT0b, HID, 64, (b - 2172) * 256 + t);
    } else if (b < 2556) {
        build_wbT_body(comp1, basis1, root1, wbT1, OUTF, 0, (b - 2364) * 256 + t);
    } else if (b < 2684) {                // wpa: w[256][128] -> wT[128][256]
        int i = (b - 2556) * 256 + t;
        wpa[(size_t)(i & 127) * 256 + (i >> 7)] = f2bf(paw[i]);
    } else {
        int i = (b - 2684) * 256 + t;
        wpp[(size_t)(i & 127) * 256 + (i >> 7)] = f2bf(ppw[i]);
    }
}

// ---------------------------------------------------------------------------
// proj (blocks 0..1249, B-stationary 5-tile loop) FUSED with hist
// (blocks 1250..5156) — independent work overlaps on the device.
__launch_bounds__(256)
__global__ void proj_hist(const float* __restrict__ xa, const float* __restrict__ xp,
                          const ushort* __restrict__ wTa, const ushort* __restrict__ wTp,
                          const float* __restrict__ ba, const float* __restrict__ bp,
                          ushort* __restrict__ x0b,
                          const int* __restrict__ ei, const int* __restrict__ et,
                          int* __restrict__ cnt, int* __restrict__ rank) {
    __shared__ ushort sx[16][264];
    __shared__ ushort so[16][132];
    const int tid = threadIdx.x;
    if (blockIdx.x >= 1250) {             // ---- hist part ----
        int e = (blockIdx.x - 1250) * 256 + tid;
        if (e < NE) {
            int seg = ei[NE + e] * NREL + et[e];
            rank[e] = atomicAdd(&cnt[seg], 1);
        }
        return;
    }
    // ---- proj part ----
    const bool author = blockIdx.x < 625;
    const int tile0 = (blockIdx.x - (author ? 0 : 625)) * 5;
    const float* x = author ? xa : xp;
    const ushort* wT = author ? wTa : wTp;
    const float* bias = author ? ba : bp;
    const int typeBase = author ? 0 : NPT;

    const int wave = tid >> 6, lane = tid & 63;
    const int row = lane & 15, g = lane >> 4;
    const int fcol = wave * 32 + row;

    const ushort* wp0 = wT + (size_t)fcol * 256 + g * 8;
    short8v bA[8], bB[8];
#pragma unroll
    for (int kk = 0; kk < 8; kk++) bA[kk] = *(const short8v*)&wp0[kk * 32];
#pragma unroll
    for (int kk = 0; kk < 8; kk++) bB[kk] = *(const short8v*)&wp0[16 * 256 + kk * 32];
    const float bv0 = bias[fcol], bv1 = bias[fcol + 16];

    const int sr = tid >> 4, part = tid & 15;
    const int fnode = tid >> 4, fb = (tid & 15) * 8;

    for (int t = 0; t < 5; t++) {
        const int nloc = (tile0 + t) * 16;
        {
            size_t rowoff = (size_t)(nloc + sr) * INF + part * 16;
#pragma unroll
            for (int ii = 0; ii < 4; ii++) {
                float4 v = *(const float4*)&x[rowoff + ii * 4];
                ushort4 h = {f2bf(v.x), f2bf(v.y), f2bf(v.z), f2bf(v.w)};
                *(ushort4*)&sx[sr][part * 16 + ii * 4] = h;
            }
        }
        __syncthreads();
        short8v a[8];
#pragma unroll
        for (int kk = 0; kk < 8; kk++) a[kk] = *(const short8v*)&sx[row][kk * 32 + g * 8];
        {
            f32x4 acc0 = {0.f, 0.f, 0.f, 0.f};
            f32x4 acc1 = {0.f, 0.f, 0.f, 0.f};
#pragma unroll
            for (int kk = 0; kk < 8; kk++) {
                acc0 = __builtin_amdgcn_mfma_f32_16x16x32_bf16(a[kk], bA[kk], acc0, 0, 0, 0);
                acc1 = __builtin_amdgcn_mfma_f32_16x16x32_bf16(a[kk], bB[kk], acc1, 0, 0, 0);
            }
#pragma unroll
            for (int q = 0; q < 4; q++) {
                so[g * 4 + q][fcol]      = f2bf(fmaxf(acc0[q] + bv0, 0.f));
                so[g * 4 + q][fcol + 16] = f2bf(fmaxf(acc1[q] + bv1, 0.f));
            }
        }
        __syncthreads();
        {
            ushort4 v0 = *(const ushort4*)&so[fnode][fb];
            ushort4 v1 = *(const ushort4*)&so[fnode][fb + 4];
            size_t gbase = (size_t)(typeBase + nloc + fnode) * 128 + fb;
            *(ushort4*)&x0b[gbase] = v0;
            *(ushort4*)&x0b[gbase + 4] = v1;
        }
    }
}

// ---------------------------------------------------------------------------
__global__ void scan1(const int* __restrict__ cnt, int* __restrict__ offs,
                      int* __restrict__ bsums, int n) {
    __shared__ int lds[256];
    const int t = threadIdx.x;
    const int base = blockIdx.x * 2048 + t * 8;
    int vals[8];
    int s = 0;
#pragma unroll
    for (int v = 0; v < 8; v++) {
        int idx = base + v;
        vals[v] = (idx < n) ? cnt[idx] : 0;
        s += vals[v];
    }
    lds[t] = s;
    __syncthreads();
    for (int off = 1; off < 256; off <<= 1) {
        int x = lds[t];
        int y = (t >= off) ? lds[t - off] : 0;
        __syncthreads();
        lds[t] = x + y;
        __syncthreads();
    }
    int run = (t > 0) ? lds[t - 1] : 0;
    if (t == 255) bsums[blockIdx.x] = lds[255];
#pragma unroll
    for (int v = 0; v < 8; v++) {
        int idx = base + v;
        if (idx < n) offs[idx] = run;
        run += vals[v];
    }
}

__global__ void scan2(const int* __restrict__ bsums, int* __restrict__ bsums2, int nb) {
    __shared__ int lds[256];
    const int t = threadIdx.x;
    lds[t] = (t < nb) ? bsums[t] : 0;
    __syncthreads();
    for (int off = 1; off < 256; off <<= 1) {
        int x = lds[t];
        int y = (t >= off) ? lds[t - off] : 0;
        __syncthreads();
        lds[t] = x + y;
        __syncthreads();
    }
    if (t < nb) bsums2[t] = (t > 0) ? lds[t - 1] : 0;
}

__global__ void scan3_desc(const int* __restrict__ offs, const int* __restrict__ bsums2,
                           const int* __restrict__ cnt, int2* __restrict__ desc, int n) {
    int i = blockIdx.x * blockDim.x + threadIdx.x;
    if (i < n) {
        int2 d = {offs[i] + bsums2[i >> 11], cnt[i]};
        desc[i] = d;
    }
}

// ---------------------------------------------------------------------------
// L0 dense GEMM (blocks 0..1249: both 64-col halves) FUSED with atomic-free
// scatter (blocks 1250..5156) — independent, overlap on the device.
__launch_bounds__(256)
__global__ void gemm0_scatter(const ushort* __restrict__ xin,
                              const ushort* __restrict__ wbT_a, const ushort* __restrict__ wbT_b,
                              ushort* __restrict__ ytab, float* __restrict__ hout,
                              const int* __restrict__ ei, const int* __restrict__ et,
                              const int* __restrict__ rank,
                              const int2* __restrict__ desc, int2* __restrict__ recs) {
    __shared__ ushort sx[32][136];
    __shared__ ushort so[32][328];
    __shared__ float sroot[32][68];
    const int tid = threadIdx.x;
    if (blockIdx.x >= 1250) {             // ---- scatter part ----
        int e = (blockIdx.x - 1250) * 256 + tid;
        if (e < NE) {
            int src = ei[e];
            int dst = ei[NE + e];
            int r = et[e];
            int2 d = desc[dst * NREL + r];
            int c = d.y;
            float sc = 1.f / (float)((c > 1) ? c : 1);
            int2 rec = {r * NN + src, __builtin_bit_cast(int, sc)};
            recs[d.x + rank[e]] = rec;
        }
        return;
    }
    // ---- gemm0 part ----
    const bool first = blockIdx.x < 625;
    const int tile0 = (first ? blockIdx.x : blockIdx.x - 625) * 5;
    const ushort* wbT = first ? wbT_a : wbT_b;
    const int outOff = first ? 0 : 64;
    const int wave = tid >> 6, lane = tid & 63;
    const int row = lane & 15, g = lane >> 4;
    const int wbase = wave * 96;

    const ushort* wp = wbT + (size_t)(wbase + row) * 128 + g * 8;
    short8v B[6][4];
#pragma unroll
    for (int t = 0; t < 6; t++)
#pragma unroll
        for (int kk = 0; kk < 4; kk++)
            B[t][kk] = *(const short8v*)&wp[t * 2048 + kk * 32];

    const int sr = tid >> 3, scl = (tid & 7) * 16;
    const int fnode = tid >> 3, fb = (tid & 7) * 8;

    for (int tt = 0; tt < 5; tt++) {
        const int n0 = (tile0 + tt) * 32;
        {
            const ushort* src = &xin[(size_t)(n0 + sr) * 128 + scl];
            *(short8v*)&sx[sr][scl] = *(const short8v*)&src[0];
            *(short8v*)&sx[sr][scl + 8] = *(const short8v*)&src[8];
        }
        __syncthreads();

        short8v a[2][4];
#pragma unroll
        for (int m = 0; m < 2; m++)
#pragma unroll
            for (int kk = 0; kk < 4; kk++)
                a[m][kk] = *(const short8v*)&sx[m * 16 + row][kk * 32 + g * 8];

#pragma unroll
        for (int t = 0; t < 6; t++) {
            f32x4 acc0 = {0.f, 0.f, 0.f, 0.f};
            f32x4 acc1 = {0.f, 0.f, 0.f, 0.f};
#pragma unroll
            for (int kk = 0; kk < 4; kk++) {
                acc0 = __builtin_amdgcn_mfma_f32_16x16x32_bf16(a[0][kk], B[t][kk], acc0, 0, 0, 0);
                acc1 = __builtin_amdgcn_mfma_f32_16x16x32_bf16(a[1][kk], B[t][kk], acc1, 0, 0, 0);
            }
            const int col = wbase + t * 16 + row;
            if (col < 320) {
#pragma unroll
                for (int q = 0; q < 4; q++) {
                    so[g * 4 + q][col] = f2bf(acc0[q]);
                    so[16 + g * 4 + q][col] = f2bf(acc1[q]);
                }
            } else {
                const int f = col - 320;
#pragma unroll
                for (int q = 0; q < 4; q++) {
                    sroot[g * 4 + q][f] = acc0[q];
                    sroot[16 + g * 4 + q][f] = acc1[q];
                }
            }
        }
        __syncthreads();

        {
#pragma unroll
            for (int r = 0; r < NREL; r++) {
                short8v v = *(const short8v*)&so[fnode][r * 64 + fb];
                *(short8v*)&ytab[(size_t)r * NN * 128 + (size_t)(n0 + fnode) * 128
                                 + outOff + fb] = v;
            }
            float4 r0 = *(const float4*)&sroot[fnode][fb];
            float4 r1 = *(const float4*)&sroot[fnode][fb + 4];
            float* hp = &hout[(size_t)(n0 + fnode) * HID + outOff + fb];
            *(float4*)&hp[0] = r0;
            *(float4*)&hp[4] = r1;
        }
    }
}

// ---------------------------------------------------------------------------
// L1 dense GEMM with FUSED PairNorm-0 on input (writes x_latent in place).
__launch_bounds__(256)
__global__ void ytab_gemm1(float* __restrict__ h0x, const float* __restrict__ mu,
                           const ushort* __restrict__ wbT,
                           ushort* __restrict__ ytab, float* __restrict__ h1) {
    __shared__ ushort sx[32][136];
    __shared__ ushort so[32][328];
    __shared__ float sroot[32][68];
    const int tid = threadIdx.x;
    const int tile0 = blockIdx.x * 5;
    const int wave = tid >> 6, lane = tid & 63;
    const int row = lane & 15, g = lane >> 4;
    const int wbase = wave * 96;

    const ushort* wp = wbT + (size_t)(wbase + row) * 128 + g * 8;
    short8v B[6][4];
#pragma unroll
    for (int t = 0; t < 6; t++)
#pragma unroll
        for (int kk = 0; kk < 4; kk++)
            B[t][kk] = *(const short8v*)&wp[t * 2048 + kk * 32];

    const int sr = tid >> 3, scl = (tid & 7) * 16;
    const int fnode = tid >> 3, fb = (tid & 7) * 8;

    float m[16];
#pragma unroll
    for (int i = 0; i < 16; i++) m[i] = mu[scl + i];
    const float s = mu[128];

    for (int tt = 0; tt < 5; tt++) {
        const int n0 = (tile0 + tt) * 32;
        {   // stage + normalize + write-back (in place)
            float* hp = &h0x[(size_t)(n0 + sr) * 128 + scl];
            float v[16];
#pragma unroll
            for (int i = 0; i < 4; i++) {
                float4 t4 = *(const float4*)&hp[i * 4];
                v[i * 4 + 0] = (t4.x - m[i * 4 + 0]) * s;
                v[i * 4 + 1] = (t4.y - m[i * 4 + 1]) * s;
                v[i * 4 + 2] = (t4.z - m[i * 4 + 2]) * s;
                v[i * 4 + 3] = (t4.w - m[i * 4 + 3]) * s;
            }
            ushort hb[16];
#pragma unroll
            for (int i = 0; i < 16; i++) hb[i] = f2bf(v[i]);
#pragma unroll
            for (int i = 0; i < 4; i++) {
                float4 t4 = {v[i * 4], v[i * 4 + 1], v[i * 4 + 2], v[i * 4 + 3]};
                *(float4*)&hp[i * 4] = t4;
            }
            *(short8v*)&sx[sr][scl] = *(const short8v*)&hb[0];
            *(short8v*)&sx[sr][scl + 8] = *(const short8v*)&hb[8];
        }
        __syncthreads();

        short8v a[2][4];
#pragma unroll
        for (int mi = 0; mi < 2; mi++)
#pragma unroll
            for (int kk = 0; kk < 4; kk++)
                a[mi][kk] = *(const short8v*)&sx[mi * 16 + row][kk * 32 + g * 8];

#pragma unroll
        for (int t = 0; t < 6; t++) {
            f32x4 acc0 = {0.f, 0.f, 0.f, 0.f};
            f32x4 acc1 = {0.f, 0.f, 0.f, 0.f};
#pragma unroll
            for (int kk = 0; kk < 4; kk++) {
                acc0 = __builtin_amdgcn_mfma_f32_16x16x32_bf16(a[0][kk], B[t][kk], acc0, 0, 0, 0);
                acc1 = __builtin_amdgcn_mfma_f32_16x16x32_bf16(a[1][kk], B[t][kk], acc1, 0, 0, 0);
            }
            const int col = wbase + t * 16 + row;
            if (col < 320) {
#pragma unroll
                for (int q = 0; q < 4; q++) {
                    so[g * 4 + q][col] = f2bf(acc0[q]);
                    so[16 + g * 4 + q][col] = f2bf(acc1[q]);
                }
            } else {
                const int f = col - 320;
#pragma unroll
                for (int q = 0; q < 4; q++) {
                    sroot[g * 4 + q][f] = acc0[q];
                    sroot[16 + g * 4 + q][f] = acc1[q];
                }
            }
        }
        __syncthreads();

        {
#pragma unroll
            for (int r = 0; r < NREL; r++) {
                short8v v = *(const short8v*)&so[fnode][r * 64 + fb];
                *(short8v*)&ytab[(size_t)r * NN * 64 + (size_t)(n0 + fnode) * 64 + fb] = v;
            }
            float4 r0 = *(const float4*)&sroot[fnode][fb];
            float4 r1 = *(const float4*)&sroot[fnode][fb + 4];
            float* hp = &h1[(size_t)(n0 + fnode) * OUTF + fb];
            *(float4*)&hp[0] = r0;
            *(float4*)&hp[4] = r1;
        }
    }
}

// ---------------------------------------------------------------------------
// Aggregation + FUSED PairNorm stats. Quarter-wave (16 lanes) per edge.
// FIX vs R11: the gather loop trip count is WAVE-UNIFORM (ceil(lim/4)) so all
// 64 lanes stay active through every __shfl; out-of-range j4 lanes are
// predicated to {row 0, scale 0} instead of exiting the loop (shfl from an
// exited lane is undefined on CDNA — that was R11's corruption).
template <int FW, bool RELU>
__launch_bounds__(256)
__global__ void agg_kernel(const ushort* __restrict__ ytab,
                           const int2* __restrict__ recs,
                           const int2* __restrict__ desc,
                           float* __restrict__ hout,
                           float* __restrict__ csrep, float* __restrict__ ssrep) {
    constexpr int FPL = FW / 16;          // floats per lane (8 or 4)
    __shared__ float sred[4][16][FPL + 1];
    const int tid = threadIdx.x;
    const int wave = tid >> 6, lane = tid & 63;
    const int q = lane >> 4, fl = lane & 15;
    const int n0 = blockIdx.x * 16 + wave * 4;

    int start[4], total[4];
#pragma unroll
    for (int rep = 0; rep < 4; rep++) {
        const int s5 = (n0 + rep) * NREL;
        int2 d0 = desc[s5];
        int2 d4 = desc[s5 + 4];
        start[rep] = d0.x;
        total[rep] = d4.x + d4.y - d0.x;
    }
    float hpre[4][FPL];
#pragma unroll
    for (int rep = 0; rep < 4; rep++) {
        const float* hp = &hout[(size_t)(n0 + rep) * FW + fl * FPL];
#pragma unroll
        for (int k = 0; k < FPL; k++) hpre[rep][k] = hp[k];
    }
    int2 rec[4];
#pragma unroll
    for (int rep = 0; rep < 4; rep++) rec[rep] = recs[start[rep] + lane];  // pad-safe

    float cs_loc[FPL];
#pragma unroll
    for (int k = 0; k < FPL; k++) cs_loc[k] = 0.f;
    float ss_loc = 0.f;

#pragma unroll
    for (int rep = 0; rep < 4; rep++) {
        float acc[FPL];
#pragma unroll
        for (int k = 0; k < FPL; k++) acc[k] = 0.f;
        const int lim = (total[rep] > 64) ? 64 : total[rep];   // wave-uniform
        const int iters = (lim + 3) >> 2;                      // wave-uniform
#pragma unroll 2
        for (int it = 0; it < iters; it++) {
            const int j4 = it * 4 + q;                         // <= 63 always
            int rwr = __shfl(rec[rep].x, j4);
            int scb = __shfl(rec[rep].y, j4);
            const bool ok = j4 < lim;
            const int rw = ok ? rwr : 0;
            const float sc = ok ? __builtin_bit_cast(float, scb) : 0.f;
            if (FW == 128) {
                uint4 raw = *(const uint4*)&ytab[(size_t)rw * FW + fl * 8];
                acc[0] += sc * bflo(raw.x); acc[1] += sc * bfhi(raw.x);
                acc[2] += sc * bflo(raw.y); acc[3] += sc * bfhi(raw.y);
                acc[4] += sc * bflo(raw.z); acc[5] += sc * bfhi(raw.z);
                acc[6] += sc * bflo(raw.w); acc[7] += sc * bfhi(raw.w);
            } else {
                uint2 raw = *(const uint2*)&ytab[(size_t)rw * FW + fl * 4];
                acc[0] += sc * bflo(raw.x); acc[1] += sc * bfhi(raw.x);
                acc[2] += sc * bflo(raw.y); acc[3] += sc * bfhi(raw.y);
            }
        }
        if (total[rep] > 64) {            // rare fallback (no shfl -> safe)
            for (int j = 64 + q; j < total[rep]; j += 4) {
                int2 r2 = recs[start[rep] + j];
                float sc = __builtin_bit_cast(float, r2.y);
                if (FW == 128) {
                    uint4 raw = *(const uint4*)&ytab[(size_t)r2.x * FW + fl * 8];
                    acc[0] += sc * bflo(raw.x); acc[1] += sc * bfhi(raw.x);
                    acc[2] += sc * bflo(raw.y); acc[3] += sc * bfhi(raw.y);
                    acc[4] += sc * bflo(raw.z); acc[5] += sc * bfhi(raw.z);
                    acc[6] += sc * bflo(raw.w); acc[7] += sc * bfhi(raw.w);
                } else {
                    uint2 raw = *(const uint2*)&ytab[(size_t)r2.x * FW + fl * 4];
                    acc[0] += sc * bflo(raw.x); acc[1] += sc * bfhi(raw.x);
                    acc[2] += sc * bflo(raw.y); acc[3] += sc * bfhi(raw.y);
                }
            }
        }
#pragma unroll
        for (int k = 0; k < FPL; k++) {
            acc[k] += __shfl_xor(acc[k], 32);
            acc[k] += __shfl_xor(acc[k], 16);
        }
        if (q == 0) {
            float o[FPL];
#pragma unroll
            for (int k = 0; k < FPL; k++) {
                o[k] = hpre[rep][k] + acc[k];
                if (RELU) o[k] = fmaxf(o[k], 0.f);
                cs_loc[k] += o[k];
                ss_loc += o[k] * o[k];
            }
            float* hp = &hout[(size_t)(n0 + rep) * FW + fl * FPL];
#pragma unroll
            for (int k = 0; k < FPL; k += 4)
                *(float4*)&hp[k] = *(float4*)&o[k];
        }
    }

    // block-level stats reduce -> replicated global accumulators
    if (q == 0) {
#pragma unroll
        for (int k = 0; k < FPL; k++) sred[wave][fl][k] = cs_loc[k];
        sred[wave][fl][FPL] = ss_loc;
    }
    __syncthreads();
    const int repl = blockIdx.x & 31;
    if (tid < FW) {
        int k = tid & (FPL - 1), f2 = tid / FPL;
        float sv = sred[0][f2][k] + sred[1][f2][k] + sred[2][f2][k] + sred[3][f2][k];
        atomicAdd(&csrep[repl * FW + f2 * FPL + k], sv);
    }
    if (tid < 16) {
        float ssv = sred[0][tid][FPL] + sred[1][tid][FPL]
                  + sred[2][tid][FPL] + sred[3][tid][FPL];
#pragma unroll
        for (int mof = 8; mof > 0; mof >>= 1) ssv += __shfl_xor(ssv, mof);
        if (tid == 0) atomicAdd(&ssrep[repl], ssv);
    }
}

// ---------------------------------------------------------------------------
template <int F>
__global__ void finalize_rep(const float* __restrict__ csrep,
                             const float* __restrict__ ssrep,
                             float* __restrict__ mu_inv) {
    __shared__ float sred[128];
    const int f = threadIdx.x;            // F threads
    float s = 0.f;
    for (int r = 0; r < 32; r++) s += csrep[r * F + f];
    float mu = s / (float)NN;
    mu_inv[f] = mu;
    sred[f] = mu * mu;
    __syncthreads();
    for (int h = F / 2; h > 0; h >>= 1) {
        if (f < h) sred[f] += sred[f + h];
        __syncthreads();
    }
    if (f == 0) {
        float ss = 0.f;
        for (int r = 0; r < 32; r++) ss += ssrep[r];
        float var = ss / (float)NN - sred[0];
        mu_inv[F] = rsqrtf(1e-5f + var);
    }
}

// final L1 normalize (in-place on d_out), float4-vectorized
template <int F>
__global__ void normalize_kernel(const float* __restrict__ x,
                                 const float* __restrict__ mu_inv,
                                 float* __restrict__ out, int total4) {
    int i = blockIdx.x * blockDim.x + threadIdx.x;
    if (i < total4) {
        int base = i * 4;
        int f = base & (F - 1);
        float4 v = *(const float4*)&x[base];
        float4 m = *(const float4*)&mu_inv[f];
        float s = mu_inv[F];
        float4 o = {(v.x - m.x) * s, (v.y - m.y) * s, (v.z - m.z) * s, (v.w - m.w) * s};
        *(float4*)&out[base] = o;
    }
}

// ---------------------------------------------------------------------------
extern "C" void kernel_launch(void* const* d_in, const int* in_sizes, int n_in,
                              void* d_out, int out_size, void* d_ws, size_t ws_size,
                              hipStream_t stream) {
    const float* xa    = (const float*)d_in[0];
    const float* xp    = (const float*)d_in[1];
    const int*   ei    = (const int*)d_in[2];
    const int*   et    = (const int*)d_in[3];
    const float* paw   = (const float*)d_in[4];
    const float* pab   = (const float*)d_in[5];
    const float* ppw   = (const float*)d_in[6];
    const float* ppb   = (const float*)d_in[7];
    const float* comp0 = (const float*)d_in[8];
    const float* basis0= (const float*)d_in[9];
    const float* root0 = (const float*)d_in[10];
    const float* comp1 = (const float*)d_in[11];
    const float* basis1= (const float*)d_in[12];
    const float* root1 = (const float*)d_in[13];
    float* out = (float*)d_out;

    char* ws = (char*)d_ws;
    size_t o = 0;
    auto alloc = [&](size_t b) { size_t p = o; o += (b + 255) & ~(size_t)255; return p; };
    ushort* x0b    = (ushort*)(ws + alloc((size_t)NN * HID * 2));        // 25.6 MB
    ushort* ytab   = (ushort*)(ws + alloc((size_t)NREL * NN * 128 * 2)); // 128 MB
    int2*   desc   = (int2*)(ws + alloc((size_t)NSEG * 8));              // 4 MB
    int2*   recs   = (int2*)(ws + alloc((size_t)(NE + 64) * 8));         // 8 MB
    int*    rank   = (int*)(ws + alloc((size_t)NE * 4));                 // 4 MB (NOT aliased)
    ushort* wbT0a  = (ushort*)(ws + alloc(384 * 128 * 2));
    ushort* wbT0b  = (ushort*)(ws + alloc(384 * 128 * 2));
    ushort* wbT1   = (ushort*)(ws + alloc(384 * 128 * 2));
    ushort* wpa    = (ushort*)(ws + alloc(128 * 256 * 2));
    ushort* wpp    = (ushort*)(ws + alloc(128 * 256 * 2));
    float*  statscr= (float*)(ws + alloc(6400 * 4));
    float*  mu0    = (float*)(ws + alloc(129 * 4));
    float*  mu1    = (float*)(ws + alloc(65 * 4));
    float* cs0rep = statscr;              // 32 x 128
    float* ss0rep = statscr + 4096;       // 32
    float* cs1rep = statscr + 4128;       // 32 x 64
    float* ss1rep = statscr + 6176;       // 32

    // index-build scratch aliased into ytab (cnt/offs/bsums dead after scan3_desc,
    // which completes before the first ytab write in gemm0_scatter)
    char* ybase = (char*)ytab;
    int* cnt    = (int*)(ybase);
    int* offs   = (int*)(ybase + (size_t)NSEG * 4);
    int* bsums  = (int*)(ybase + (size_t)NSEG * 8);
    int* bsums2 = (int*)(ybase + (size_t)NSEG * 8 + 4096);

    float* h0 = out + (size_t)NN * OUTF;   // [NN][128] f32 (x_latent slice)
    float* h1 = out;                       // [NN][64]  f32

    // prep (zeros + all weight builds), then proj FUSED with hist
    prep_kernel<<<2812, 256, 0, stream>>>(comp0, basis0, root0, comp1, basis1, root1,
                                          paw, ppw, wbT0a, wbT0b, wbT1, wpa, wpp,
                                          cnt, statscr, (int*)(recs + NE));
    proj_hist<<<1250 + (NE + 255) / 256, 256, 0, stream>>>(xa, xp, wpa, wpp, pab, ppb,
                                                           x0b, ei, et, cnt, rank);

    // segment index
    const int nb = (NSEG + 2047) / 2048;
    scan1<<<nb, 256, 0, stream>>>(cnt, offs, bsums, NSEG);
    scan2<<<1, 256, 0, stream>>>(bsums, bsums2, nb);
    scan3_desc<<<(NSEG + 255) / 256, 256, 0, stream>>>(offs, bsums2, cnt, desc, NSEG);

    // layer 0: GEMM (both halves) FUSED with scatter, then agg+stats, finalize
    gemm0_scatter<<<1250 + (NE + 255) / 256, 256, 0, stream>>>(
        x0b, wbT0a, wbT0b, ytab, h0, ei, et, rank, desc, recs);
    agg_kernel<128, true><<<NN / 16, 256, 0, stream>>>(ytab, recs, desc, h0, cs0rep, ss0rep);
    finalize_rep<128><<<1, 128, 0, stream>>>(cs0rep, ss0rep, mu0);

    // layer 1: GEMM with fused PairNorm-0 (writes x_latent in place), agg+stats
    ytab_gemm1<<<625, 256, 0, stream>>>(h0, mu0, wbT1, ytab, h1);
    agg_kernel<64, false><<<NN / 16, 256, 0, stream>>>(ytab, recs, desc, h1, cs1rep, ss1rep);
    finalize_rep<64><<<1, 64, 0, stream>>>(cs1rep, ss1rep, mu1);
    normalize_kernel<OUTF><<<(NN * OUTF / 4 + 255) / 256, 256, 0, stream>>>(h1, mu1, out,
                                                                            NN * OUTF / 4);
}